// Round 5
// baseline (608.053 us; speedup 1.0000x reference)
//
#include <hip/hip_runtime.h>

// DecoderStack: B=4,T=1024,D=1024,H=16,DK=DV=64,FF=4096
// Softmax over QUERY axis: l_s = sum_t exp(S) via store-free l-pass (EPI=4),
// 1/l_s folded into V (vscale), then fused attn_pv_k recomputes E per tile in
// LDS and multiplies by V — E never touches HBM.
// sub_norm(o) = o - mean - std (ddof=1).
// R5 gemm8_k: faithful m201 port. 2 K-tiles per loop iteration (even->buf0,
// odd->buf1, compile-time buffers), 8 phases/iter. Phase p =
// [reads-for-THIS-phase (12/4/8/0); stage ONE half-tile; (vmcnt at ph4/ph8);
//  bar; setprio(1); 16 MFMA; setprio(0); bar].
// vmcnt(6) ONLY at phases 4 and 8 (3 half-tiles in flight), never 0 in loop.
// R3/R4's reads-inside-MFMA-window experiment regressed 26% — reverted.

typedef unsigned short u16;
typedef __bf16 bf16x8 __attribute__((ext_vector_type(8)));
typedef float f32x4 __attribute__((ext_vector_type(4)));

__device__ __forceinline__ u16 f2bf(float f) {
    unsigned int u = __float_as_uint(f);
    u += 0x7fffu + ((u >> 16) & 1u);   // RNE; inputs are finite
    return (u16)(u >> 16);
}
__device__ __forceinline__ float bf2f(u16 b) {
    return __uint_as_float(((unsigned int)b) << 16);
}

typedef __attribute__((address_space(1))) const void* as1cv;
typedef __attribute__((address_space(3))) void* as3v;
__device__ __forceinline__ void gl_lds16(const void* g, void* l) {
    __builtin_amdgcn_global_load_lds((as1cv)g, (as3v)l, 16, 0, 0);
}

// ---------------- converts / packs ----------------

__global__ __launch_bounds__(256) void convert_f2b_k(const float* __restrict__ in, u16* __restrict__ out) {
    long i = (long)blockIdx.x * 256 + threadIdx.x;
    float4 v = reinterpret_cast<const float4*>(in)[i];
    ushort4 o;
    o.x = f2bf(v.x); o.y = f2bf(v.y); o.z = f2bf(v.z); o.w = f2bf(v.w);
    reinterpret_cast<ushort4*>(out)[i] = o;
}

// out[p][r][q] = in[p][q][r] (fp32->bf16), LDS-tiled. grid (R/64, Q/64, P)
__global__ __launch_bounds__(256) void pack_perm_t(const float* __restrict__ in, u16* __restrict__ out,
                                                   int Q, int R) {
    __shared__ float tile[64][65];
    int p = blockIdx.z;
    int r0 = blockIdx.x * 64, q0 = blockIdx.y * 64;
    int tx = threadIdx.x & 63, ty = threadIdx.x >> 6;
    const float* inp = in + ((long)p * Q + q0) * R + r0;
    #pragma unroll
    for (int i = 0; i < 64; i += 4)
        tile[ty + i][tx] = inp[(long)(ty + i) * R + tx];
    __syncthreads();
    u16* outp = out + ((long)p * R + r0) * Q + q0;
    #pragma unroll
    for (int i = 0; i < 64; i += 4)
        outp[(long)(ty + i) * Q + tx] = f2bf(tile[tx][ty + i]);
}

// 64x64 tiled bf16 transpose: out[c][r] = in[r][c], batched over z
__global__ __launch_bounds__(256) void transpose_k(const u16* __restrict__ in, long ld_in, long z_in,
                                                   u16* __restrict__ out, long ld_out, long z_out) {
    __shared__ u16 tile[64][66];
    const u16* inz = in + (long)blockIdx.z * z_in;
    u16* outz = out + (long)blockIdx.z * z_out;
    int r0 = blockIdx.y * 64;
    int c0 = blockIdx.x * 64;
    int tx = threadIdx.x & 63, ty = threadIdx.x >> 6;
    #pragma unroll
    for (int i = 0; i < 64; i += 4)
        tile[ty + i][tx] = inz[(long)(r0 + ty + i) * ld_in + c0 + tx];
    __syncthreads();
    #pragma unroll
    for (int i = 0; i < 64; i += 4)
        outz[(long)(c0 + ty + i) * ld_out + r0 + tx] = tile[tx][ty + i];
}

// ---------------- legacy GEMM (kept for l-pass EPI=4 and small Wo split-K) ----------------
template<int BM, int BN, int BK, int WM, int WN, int OUT_BF16, int EPI, int SWZ, int KS>
__global__ __launch_bounds__(256) void gemm_k(
    const u16* __restrict__ A, long lda, long a_zin, long a_zout,
    const u16* __restrict__ B, long ldb, long b_zin, long b_zout,
    void* __restrict__ Cv, long ldc, long c_zin, long c_zout,
    int zin, int K, float alpha, const float* __restrict__ bias,
    float* __restrict__ csum)
{
    static_assert(BK == 64, "staging assumes BK=64");
    constexpr int WTM = BM / WM;
    constexpr int WTN = BN / WN;
    constexpr int TM = WTM / 16;
    constexpr int TN = WTN / 16;
    __shared__ __align__(16) u16 smem[(BM + BN) * BK];
    u16* As = smem;
    u16* Bs = smem + BM * BK;

    int bx, by, z;
    if (SWZ == 4) {
        int L = blockIdx.x;
        if (KS > 1) { z = L >> 9; L &= 511; } else { z = 0; }
        by = (L & 7) * 4 + ((L >> 3) & 3);
        bx = L >> 5;
    } else {
        bx = blockIdx.x; by = blockIdx.y; z = blockIdx.z;
    }
    int zi = z % zin, zo = z / zin;
    A += (long)zi * a_zin + (long)zo * a_zout;
    B += (long)zi * b_zin + (long)zo * b_zout;
    long coff = (long)zi * c_zin + (long)zo * c_zout;

    int tid = threadIdx.x;
    int lane = tid & 63;
    int wave = tid >> 6;
    int wm = wave / WN, wn = wave % WN;
    long bm0 = (long)by * BM, bn0 = (long)bx * BN;

    f32x4 acc[TM][TN];
    #pragma unroll
    for (int i = 0; i < TM; ++i)
        #pragma unroll
        for (int j = 0; j < TN; ++j) {
            acc[i][j][0] = 0.f; acc[i][j][1] = 0.f;
            acc[i][j][2] = 0.f; acc[i][j][3] = 0.f;
        }

    int r16 = lane & 15;
    int quad = lane >> 4;
    int l8 = lane >> 3;                    // stripe row
    int gsw = ((lane & 7) ^ l8) * 8;       // swizzled global col (elements)

    constexpr int ASTR = BM / 8;
    constexpr int BSTR = BN / 8;

    for (int k0 = 0; k0 < K; k0 += BK) {
        #pragma unroll
        for (int s = wave; s < ASTR; s += 4)
            gl_lds16(&A[(bm0 + s * 8 + l8) * lda + k0 + gsw], &As[s * 512]);
        #pragma unroll
        for (int s = wave; s < BSTR; s += 4)
            gl_lds16(&B[(bn0 + s * 8 + l8) * ldb + k0 + gsw], &Bs[s * 512]);
        __syncthreads();
        #pragma unroll
        for (int kk = 0; kk < BK; kk += 32) {
            int cb = (kk >> 3) + quad;
            bf16x8 av[TM], bv[TN];
            #pragma unroll
            for (int i = 0; i < TM; ++i) {
                int r = wm * WTM + i * 16 + r16;
                av[i] = *reinterpret_cast<const bf16x8*>(&As[r * 64 + ((cb ^ (r & 7)) * 8)]);
            }
            #pragma unroll
            for (int j = 0; j < TN; ++j) {
                int r = wn * WTN + j * 16 + r16;
                bv[j] = *reinterpret_cast<const bf16x8*>(&Bs[r * 64 + ((cb ^ (r & 7)) * 8)]);
            }
            #pragma unroll
            for (int i = 0; i < TM; ++i)
                #pragma unroll
                for (int j = 0; j < TN; ++j)
                    acc[i][j] = __builtin_amdgcn_mfma_f32_16x16x32_bf16(av[i], bv[j], acc[i][j], 0, 0, 0);
        }
        __syncthreads();
    }

    int rb = quad * 4;

    if (EPI == 4) {
        // exp + column sums only; no C store. csum layout [z][1024].
        float csl[TN];
        #pragma unroll
        for (int j = 0; j < TN; ++j) csl[j] = 0.f;
        #pragma unroll
        for (int i = 0; i < TM; ++i)
            #pragma unroll
            for (int j = 0; j < TN; ++j)
                #pragma unroll
                for (int r = 0; r < 4; ++r)
                    csl[j] += __expf(acc[i][j][r] * alpha);
        #pragma unroll
        for (int j = 0; j < TN; ++j) {
            float cs = csl[j];
            cs += __shfl_xor(cs, 16, 64);
            cs += __shfl_xor(cs, 32, 64);
            if (quad == 0) {
                long col = bn0 + wn * WTN + j * 16 + r16;
                atomicAdd(&csum[((long)zo * zin + zi) * 1024 + col], cs);
            }
        }
        return;
    }

    // ---- LDS-staged store epilogue ----
    constexpr int EB = OUT_BF16 ? 2 : 4;
    constexpr int CH = 16 / EB;
    constexpr int STRIDE = BN + CH;
    constexpr int LDSB = (BM + BN) * BK * 2;
    constexpr int EPASS = (BM * STRIDE * EB > LDSB) ? 2 : 1;
    constexpr int RPP = BM / EPASS;
    static_assert(RPP * STRIDE * EB <= LDSB, "epilogue tile overflows LDS");
    static_assert(EPASS == 1 || (WM == 2 && WTM == RPP), "pass/wave row alignment");
    constexpr int CPR = BN / CH;
    constexpr int NCH = RPP * CPR / 256;
    static_assert(RPP * CPR % 256 == 0, "store mapping");

    float* Ef = reinterpret_cast<float*>(smem);
    char* Cb = reinterpret_cast<char*>(Cv);

    for (int pass = 0; pass < EPASS; ++pass) {
        int p0 = pass * RPP;
        __syncthreads();
        #pragma unroll
        for (int i = 0; i < TM; ++i) {
            #pragma unroll
            for (int j = 0; j < TN; ++j) {
                int lcol = wn * WTN + j * 16 + r16;
                float bsv = (EPI == 1 || EPI == 2) ? bias[bn0 + lcol] : 0.f;
                #pragma unroll
                for (int r = 0; r < 4; ++r) {
                    int lrow = wm * WTM + i * 16 + rb + r;
                    if ((unsigned)(lrow - p0) < (unsigned)RPP) {
                        float v = acc[i][j][r] * alpha;
                        if (EPI == 1) { v += bsv; v = v > 0.f ? v : 0.f; }
                        else if (EPI == 2) { v += bsv; }
                        if (OUT_BF16) smem[(lrow - p0) * STRIDE + lcol] = f2bf(v);
                        else          Ef[(lrow - p0) * STRIDE + lcol] = v;
                    }
                }
            }
        }
        __syncthreads();
        #pragma unroll
        for (int c = 0; c < NCH; ++c) {
            int cid = tid + c * 256;
            int row = cid / CPR, ch = cid - row * CPR;
            int4 v = *reinterpret_cast<const int4*>(
                reinterpret_cast<const char*>(smem) + (row * STRIDE + ch * CH) * EB);
            long gidx = coff + (bm0 + p0 + row) * ldc + bn0 + ch * CH;
            *reinterpret_cast<int4*>(Cb + gidx * EB) = v;
        }
    }
}

// ---------------- 8-phase 256x256 GEMM, m201 schedule ----------------
// C[4096][NT*256] = alpha * A[4096][K] x B[NT*256][K]^T (+bias/relu), KS-way split-K.
// 512 thr / 8 waves (2M x 4N); per-wave C = 2 ih-blocks(64 rows) x 2 jh-blocks(32 cols).
// LDS 128KB: buf0 (even tile) = A 32KB + B 32KB; buf1 (odd tile) same. Stripe-XOR
// swizzle via pre-swizzled global source (gl_lds linear dest) + swizzled ds_read.
// Iteration = 2 K-tiles (t0 even in buf0, t1=t0+1 in buf1), 8 phases.
// Phase p = [reads for THIS phase's MFMA; stage ONE half-tile; bar; prio1;
//            16 MFMA (one C-quadrant x K=64); prio0; bar].
// Reads/phase (per tile): ph1 av0+bv0 [12], ph2 bv1 [4], ph3 av1 [8], ph4 [0].
// Stages: ph1 A1(t1); ph2 A0(t0+2); ph3 B0(t0+2); ph4 B1(t0+2) + vmcnt(6);
//         ph5 A1(t0+2); ph6 A0(t1+2); ph7 B0(t1+2); ph8 B1(t1+2) + vmcnt(6).
// vmcnt(6) = 3 half-tiles (2 loads/thread each) in flight; NEVER 0 in main loop.
// Coverage (vmcnt+following-barrier guarantees all waves' older loads landed):
//   each read target is >=4 half-tiles older than the governing vmcnt's newest-3.
// WAR: every stage overwrites a region whose last read is >=1 barrier earlier.
// Prologue: 7 half-tiles (tile0 full + tile1 minus A1), vmcnt(6), bar.
// Tail (last iteration): skip all t+2/t+3 stages; keep ph1's A1(t1); ph4 vmcnt(0).

__device__ __forceinline__ void bar_raw() {
    asm volatile("" ::: "memory");
    __builtin_amdgcn_s_barrier();
    asm volatile("" ::: "memory");
}

template<int N> __device__ __forceinline__ void vmw() {
    if constexpr (N == 6) asm volatile("s_waitcnt vmcnt(6)" ::: "memory");
    else if constexpr (N == 0) asm volatile("s_waitcnt vmcnt(0)" ::: "memory");
}

// stage one half-tile (16 stripes of 8 rows x 64 cols) = 2 gl_lds per thread
__device__ __forceinline__ void stage_half(const u16* __restrict__ base, long ld, int kt,
                                           u16* __restrict__ lds, int half, int wave) {
    const u16* src = base + (long)kt * 64;
    #pragma unroll
    for (int u = 0; u < 2; ++u) {
        int s = half * 16 + u * 8 + wave;
        gl_lds16(src + (long)(s * 8) * ld, lds + s * 512);
    }
}

template<int IH>
__device__ __forceinline__ void read_a8(bf16x8 (&av)[4][2], const u16* __restrict__ As,
                                        int wm, int r16, int quad) {
    #pragma unroll
    for (int ii = 0; ii < 4; ++ii) {
        int r = IH * 128 + wm * 64 + ii * 16 + r16;
        #pragma unroll
        for (int kx = 0; kx < 2; ++kx)
            av[ii][kx] = *reinterpret_cast<const bf16x8*>(&As[r * 64 + (((kx * 4 + quad) ^ (r & 7)) * 8)]);
    }
}

template<int JH>
__device__ __forceinline__ void read_b8(bf16x8 (&bv)[2][2], const u16* __restrict__ Bs,
                                        int wn, int r16, int quad) {
    #pragma unroll
    for (int j = 0; j < 2; ++j) {
        int r = JH * 128 + wn * 32 + j * 16 + r16;
        #pragma unroll
        for (int kx = 0; kx < 2; ++kx)
            bv[j][kx] = *reinterpret_cast<const bf16x8*>(&Bs[r * 64 + (((kx * 4 + quad) ^ (r & 7)) * 8)]);
    }
}

template<int IH, int JH>
__device__ __forceinline__ void mfma_q(f32x4 (&acc)[2][4][2][2],
                                       const bf16x8 (&av)[4][2], const bf16x8 (&bv)[2][2]) {
    #pragma unroll
    for (int kx = 0; kx < 2; ++kx)
        #pragma unroll
        for (int ii = 0; ii < 4; ++ii)
            #pragma unroll
            for (int j = 0; j < 2; ++j)
                acc[IH][ii][JH][j] = __builtin_amdgcn_mfma_f32_16x16x32_bf16(
                    av[ii][kx], bv[j][kx], acc[IH][ii][JH][j], 0, 0, 0);
}

// One iteration = tiles t0 (buf0) and t0+1 (buf1). LAST=1: no future stages.
template<int LAST>
__device__ __forceinline__ void iter8(
    int t0, f32x4 (&acc)[2][4][2][2],
    bf16x8 (&avA)[4][2], bf16x8 (&avB)[4][2],
    bf16x8 (&bvA)[2][2], bf16x8 (&bvB)[2][2],
    u16* __restrict__ smem, const u16* __restrict__ Ab, long lda,
    const u16* __restrict__ Bb, long ldb, int wave, int wm, int wn, int r16, int quad)
{
    u16* As0 = smem;              // even-tile A (32KB)
    u16* Bs0 = smem + 16384;      // even-tile B
    u16* As1 = smem + 32768;      // odd-tile A
    u16* Bs1 = smem + 49152;      // odd-tile B
    // ---- ph1 (t0, quad 0,0): reads av0(t0)+bv0(t0); stage A1(t0+1)
    read_a8<0>(avA, As0, wm, r16, quad);
    read_b8<0>(bvA, Bs0, wn, r16, quad);
    stage_half(Ab, lda, t0 + 1, As1, 1, wave);
    bar_raw();
    __builtin_amdgcn_s_setprio(1);
    mfma_q<0, 0>(acc, avA, bvA);
    __builtin_amdgcn_s_setprio(0);
    bar_raw();
    // ---- ph2 (t0, quad 0,1): read bv1(t0); stage A0(t0+2)
    read_b8<1>(bvB, Bs0, wn, r16, quad);
    if (!LAST) stage_half(Ab, lda, t0 + 2, As0, 0, wave);
    bar_raw();
    __builtin_amdgcn_s_setprio(1);
    mfma_q<0, 1>(acc, avA, bvB);
    __builtin_amdgcn_s_setprio(0);
    bar_raw();
    // ---- ph3 (t0, quad 1,0): read av1(t0); stage B0(t0+2)
    read_a8<1>(avB, As0, wm, r16, quad);
    if (!LAST) stage_half(Bb, ldb, t0 + 2, Bs0, 0, wave);
    bar_raw();
    __builtin_amdgcn_s_setprio(1);
    mfma_q<1, 0>(acc, avB, bvA);
    __builtin_amdgcn_s_setprio(0);
    bar_raw();
    // ---- ph4 (t0, quad 1,1): stage B1(t0+2); vmcnt
    if (!LAST) { stage_half(Bb, ldb, t0 + 2, Bs0, 1, wave); vmw<6>(); }
    else       { vmw<0>(); }
    bar_raw();
    __builtin_amdgcn_s_setprio(1);
    mfma_q<1, 1>(acc, avB, bvB);
    __builtin_amdgcn_s_setprio(0);
    bar_raw();
    // ---- ph5 (t1, quad 0,0): reads av0(t1)+bv0(t1); stage A1(t0+2)
    read_a8<0>(avA, As1, wm, r16, quad);
    read_b8<0>(bvA, Bs1, wn, r16, quad);
    if (!LAST) stage_half(Ab, lda, t0 + 2, As0, 1, wave);
    bar_raw();
    __builtin_amdgcn_s_setprio(1);
    mfma_q<0, 0>(acc, avA, bvA);
    __builtin_amdgcn_s_setprio(0);
    bar_raw();
    // ---- ph6 (t1, quad 0,1): read bv1(t1); stage A0(t1+2)
    read_b8<1>(bvB, Bs1, wn, r16, quad);
    if (!LAST) stage_half(Ab, lda, t0 + 3, As1, 0, wave);
    bar_raw();
    __builtin_amdgcn_s_setprio(1);
    mfma_q<0, 1>(acc, avA, bvB);
    __builtin_amdgcn_s_setprio(0);
    bar_raw();
    // ---- ph7 (t1, quad 1,0): read av1(t1); stage B0(t1+2)
    read_a8<1>(avB, As1, wm, r16, quad);
    if (!LAST) stage_half(Bb, ldb, t0 + 3, Bs1, 0, wave);
    bar_raw();
    __builtin_amdgcn_s_setprio(1);
    mfma_q<1, 0>(acc, avB, bvA);
    __builtin_amdgcn_s_setprio(0);
    bar_raw();
    // ---- ph8 (t1, quad 1,1): stage B1(t1+2); vmcnt
    if (!LAST) { stage_half(Bb, ldb, t0 + 3, Bs1, 1, wave); vmw<6>(); }
    bar_raw();
    __builtin_amdgcn_s_setprio(1);
    mfma_q<1, 1>(acc, avB, bvB);
    __builtin_amdgcn_s_setprio(0);
    bar_raw();
}

// grid = 16*NT*KS blocks of 512. EPI: 0 none, 1 bias+relu. KS>1: z picks K-chunk,
// output slab z: z<2 -> Cv + (z&1)*czs, z>=2 -> Cv2 + (z&1)*czs (fp32).
// Requires T = K/64 even and >= 4 (all uses: K=1024 -> T=16).
template<int NT, int KS, int EPI, int OUT_BF16>
__global__ __launch_bounds__(512, 2) void gemm8_k(
    const u16* __restrict__ A, long lda,
    const u16* __restrict__ B, long ldb,
    void* __restrict__ Cv, void* __restrict__ Cv2, long ldc,
    int K, float alpha, const float* __restrict__ bias, long czs)
{
    __shared__ __align__(16) u16 smem[65536];   // 128 KiB

    int L = blockIdx.x;
    int z = 0;
    if (KS > 1) { z = L / (16 * NT); L -= z * 16 * NT; }
    int by = (L & 7) * 2 + ((L >> 3) & 1);      // XCD-contiguous M-rows
    int bx = L >> 4;
    if (KS > 1) { A += (long)z * K; B += (long)z * K; }

    int tid = threadIdx.x;
    int lane = tid & 63, wave = tid >> 6;
    int wm = wave >> 2, wn = wave & 3;
    int r16 = lane & 15, quad = lane >> 4, l8 = lane >> 3;
    int gsw = ((lane & 7) ^ l8) * 8;
    long bm0 = (long)by * 256, bn0 = (long)bx * 256;
    const u16* Ab = A + (bm0 + l8) * lda + gsw;
    const u16* Bb = B + (bn0 + l8) * ldb + gsw;

    f32x4 acc[2][4][2][2];
    #pragma unroll
    for (int a0 = 0; a0 < 2; ++a0)
        #pragma unroll
        for (int a1 = 0; a1 < 4; ++a1)
            #pragma unroll
            for (int a2 = 0; a2 < 2; ++a2)
                #pragma unroll
                for (int a3 = 0; a3 < 2; ++a3) {
                    acc[a0][a1][a2][a3][0] = 0.f; acc[a0][a1][a2][a3][1] = 0.f;
                    acc[a0][a1][a2][a3][2] = 0.f; acc[a0][a1][a2][a3][3] = 0.f;
                }
    bf16x8 avA[4][2], avB[4][2];
    bf16x8 bvA[2][2], bvB[2][2];

    int T = K >> 6;   // even, >= 4

    // prologue: tile0 full + tile1 minus A1 = 7 half-tiles (14 loads)
    stage_half(Ab, lda, 0, smem,         0, wave);   // A0(0)
    stage_half(Bb, ldb, 0, smem + 16384, 0, wave);   // B0(0)
    stage_half(Bb, ldb, 0, smem + 16384, 1, wave);   // B1(0)
    stage_half(Ab, lda, 0, smem,         1, wave);   // A1(0)
    stage_half(Ab, lda, 1, smem + 32768, 0, wave);   // A0(1)
    stage_half(Bb, ldb, 1, smem + 49152, 0, wave);   // B0(1)
    stage_half(Bb, ldb, 1, smem + 49152, 1, wave);   // B1(1)
    vmw<6>();           // 14 issued -> oldest 4 half-tiles (tile0 complete) landed
    bar_raw();

    int ITER = T >> 1;
    for (int i = 0; i < ITER - 1; ++i)
        iter8<0>(2 * i, acc, avA, avB, bvA, bvB, smem, Ab, lda, Bb, ldb, wave, wm, wn, r16, quad);
    iter8<1>(T - 2, acc, avA, avB, bvA, bvB, smem, Ab, lda, Bb, ldb, wave, wm, wn, r16, quad);

    // ---- epilogue: stage to LDS (row-XOR-swizzled), coalesced int4 stores
    constexpr int EB = OUT_BF16 ? 2 : 4;
    constexpr int EPASS = OUT_BF16 ? 1 : 2;   // f32 = 2 passes of 128 rows (ih=pass)
    char* Cb = reinterpret_cast<char*>((KS > 1 && z >= 2) ? Cv2 : Cv);
    if (KS > 1) Cb += (long)(z & 1) * czs * EB;
    float bsv[2][2];
    if (EPI == 1) {
        #pragma unroll
        for (int jh = 0; jh < 2; ++jh)
            #pragma unroll
            for (int j = 0; j < 2; ++j)
                bsv[jh][j] = bias[bn0 + jh * 128 + wn * 32 + j * 16 + r16];
    }
    u16* sm16 = smem;
    float* smf = reinterpret_cast<float*>(smem);
    #pragma unroll
    for (int pass = 0; pass < EPASS; ++pass) {
        bar_raw();
        #pragma unroll
        for (int ih = 0; ih < 2; ++ih) {
            if (EPASS == 2 && ih != pass) continue;
            #pragma unroll
            for (int ii = 0; ii < 4; ++ii)
                #pragma unroll
                for (int jh = 0; jh < 2; ++jh)
                    #pragma unroll
                    for (int j = 0; j < 2; ++j)
                        #pragma unroll
                        for (int r = 0; r < 4; ++r) {
                            int lrow = (EPASS == 2 ? 0 : ih * 128) + wm * 64 + ii * 16 + quad * 4 + r;
                            int lcol = jh * 128 + wn * 32 + j * 16 + r16;
                            float v = acc[ih][ii][jh][j][r] * alpha;
                            if (EPI == 1) { v += bsv[jh][j]; v = v > 0.f ? v : 0.f; }
                            int scol = lcol ^ ((lrow & 7) * 8);
                            if (OUT_BF16) sm16[lrow * 256 + scol] = f2bf(v);
                            else          smf[lrow * 256 + scol] = v;
                        }
        }
        bar_raw();
        constexpr int CH = 16 / EB;
        constexpr int CPR = 256 / CH;
        constexpr int NCH = (OUT_BF16 ? 256 : 128) * CPR / 512;
        #pragma unroll
        for (int c = 0; c < NCH; ++c) {
            int cid = tid + c * 512;
            int row = cid / CPR, ch = cid - row * CPR;
            int col = (ch * CH) ^ ((row & 7) * 8);
            int4 v = *reinterpret_cast<const int4*>(
                reinterpret_cast<const char*>(smem) + ((long)row * 256 + col) * EB);
            long grow = bm0 + pass * 128 + row;
            *reinterpret_cast<int4*>(Cb + (grow * ldc + bn0 + ch * CH) * EB) = v;
        }
    }
}

// ---------------- fused attention PV: recompute E per tile, x scaled V ----------------
// Grid 512 blocks: L -> xcd=L&7: head=(L&7)*2+((L>>3)&1), tb=(L>>4)&7, b=L>>7.
// Per block: out[128 t][64 v] = sum_s exp(0.125*Q K^T) * Vt_scaled.
__global__ __launch_bounds__(256) void attn_pv_k(
    const u16* __restrict__ Qg, long ldq, long qbz,
    const u16* __restrict__ Kg, long ldk, long kbz,
    const u16* __restrict__ Vg,            // [b][1024 hv][1024 s], pre-scaled by 1/l
    u16* __restrict__ outg)                // part: [b][1024 t][1024 (h*64+v)]
{
    __shared__ __align__(16) u16 Qs[128 * 64];
    __shared__ __align__(16) u16 Ks[64 * 64];
    __shared__ __align__(16) u16 Vs[64 * 64];
    __shared__ __align__(16) u16 Es[128 * 64];

    int L = blockIdx.x;
    int h  = (L & 7) * 2 + ((L >> 3) & 1);
    int tb = (L >> 4) & 7;
    int b  = L >> 7;

    const u16* Q  = Qg + (long)b * qbz + h * 64;
    const u16* Kp = Kg + (long)b * kbz + h * 64;
    const u16* Vp = Vg + (long)b * 1048576 + (long)h * 65536;
    u16* outp = outg + (long)b * 1048576 + (long)tb * 131072 + h * 64;

    int tid = threadIdx.x, lane = tid & 63, wave = tid >> 6;
    int wm = wave >> 1, wn = wave & 1;
    int r16 = lane & 15, quad = lane >> 4, l8 = lane >> 3;
    int gsw = ((lane & 7) ^ l8) * 8;
    long t0 = (long)tb * 128;

    #pragma unroll
    for (int s = wave; s < 16; s += 4)
        gl_lds16(&Q[(t0 + s * 8 + l8) * ldq + gsw], &Qs[s * 512]);

    f32x4 acc[4][2];
    #pragma unroll
    for (int i = 0; i < 4; ++i)
        #pragma unroll
        for (int j = 0; j < 2; ++j) {
            acc[i][j][0] = 0.f; acc[i][j][1] = 0.f;
            acc[i][j][2] = 0.f; acc[i][j][3] = 0.f;
        }

    for (int sc = 0; sc < 16; ++sc) {
        #pragma unroll
        for (int s = wave; s < 8; s += 4) {
            gl_lds16(&Kp[(long)(sc * 64 + s * 8 + l8) * ldk + gsw], &Ks[s * 512]);
            gl_lds16(&Vp[(long)(s * 8 + l8) * 1024 + sc * 64 + gsw], &Vs[s * 512]);
        }
        __syncthreads();                       // K/V (and Q on sc==0) staged

        // E-chunk = Q x K^T (128x64, contraction 64)
        f32x4 e[4][2];
        #pragma unroll
        for (int i = 0; i < 4; ++i)
            #pragma unroll
            for (int j = 0; j < 2; ++j) {
                e[i][j][0] = 0.f; e[i][j][1] = 0.f;
                e[i][j][2] = 0.f; e[i][j][3] = 0.f;
            }
        #pragma unroll
        for (int kk = 0; kk < 64; kk += 32) {
            int cb = (kk >> 3) + quad;
            bf16x8 av[4], bv[2];
            #pragma unroll
            for (int i = 0; i < 4; ++i) {
                int r = wm * 64 + i * 16 + r16;
                av[i] = *reinterpret_cast<const bf16x8*>(&Qs[r * 64 + ((cb ^ (r & 7)) * 8)]);
            }
            #pragma unroll
            for (int j = 0; j < 2; ++j) {
                int r = wn * 32 + j * 16 + r16;
                bv[j] = *reinterpret_cast<const bf16x8*>(&Ks[r * 64 + ((cb ^ (r & 7)) * 8)]);
            }
            #pragma unroll
            for (int i = 0; i < 4; ++i)
                #pragma unroll
                for (int j = 0; j < 2; ++j)
                    e[i][j] = __builtin_amdgcn_mfma_f32_16x16x32_bf16(av[i], bv[j], e[i][j], 0, 0, 0);
        }
        // exp + write to Es (C-frag: row=quad*4+r, col=r16; XOR-swizzled rows)
        #pragma unroll
        for (int i = 0; i < 4; ++i)
            #pragma unroll
            for (int j = 0; j < 2; ++j) {
                int lcol = wn * 32 + j * 16 + r16;
                #pragma unroll
                for (int r = 0; r < 4; ++r) {
                    int lrow = wm * 64 + i * 16 + quad * 4 + r;
                    float v = __expf(e[i][j][r] * 0.125f);
                    Es[lrow * 64 + (((lcol >> 3) ^ (lrow & 7)) * 8) + (lcol & 7)] = f2bf(v);
                }
            }
        __syncthreads();                       // Es ready

        // acc += E-chunk x Vs^T (contraction over s-chunk)
        #pragma unroll
        for (int kk = 0; kk < 64; kk += 32) {
            int cb = (kk >> 3) + quad;
            bf16x8 av[4], bv[2];
            #pragma unroll
            for (int i = 0; i < 4; ++i) {
                int r = wm * 64 + i * 16 + r16;
                av[i] = *reinterpret_cast<const bf16x8*>(&Es[r * 64 + ((cb ^ (r & 7)) * 8)]);
            }
            #pragma unroll
            for (int j = 0; j < 2; ++j) {
                int r = wn * 32 + j * 16 + r16;
                bv[j] = *reinterpret_cast<const bf16x8*>(&Vs[r * 64 + ((cb ^ (r & 7)) * 8)]);
            }
            #pragma unroll
            for (int i = 0; i < 4; ++i)
                #pragma unroll
                for (int j = 0; j < 2; ++j)
                    acc[i][j] = __builtin_amdgcn_mfma_f32_16x16x32_bf16(av[i], bv[j], acc[i][j], 0, 0, 0);
        }
        __syncthreads();                       // PV done; next stage may overwrite K/V
    }

    #pragma unroll
    for (int i = 0; i < 4; ++i)
        #pragma unroll
        for (int j = 0; j < 2; ++j) {
            int lcol = wn * 32 + j * 16 + r16;
            #pragma unroll
            for (int r = 0; r < 4; ++r) {
                int lrow = wm * 64 + i * 16 + quad * 4 + r;
                outp[(long)lrow * 1024 + lcol] = f2bf(acc[i][j][r]);
            }
        }
}

// ---------------- Vt *= 1/l over all 4 batches: csum [4][16][1024] ----------------
__global__ __launch_bounds__(256) void vscale_k(u16* __restrict__ Vt, const float* __restrict__ csum) {
    long idx = (long)blockIdx.x * 256 + threadIdx.x;   // grid 2048
    int slab = (int)(idx >> 17);
    int rem = (int)(idx & 131071);
    int hv = rem >> 7;
    int s8 = (rem & 127) * 8;
    const float* cs = csum + slab * 16384 + (hv >> 6) * 1024 + s8;
    u16* pv = Vt + (long)slab * 1048576 + (long)hv * 1024 + s8;
    ushort4 a = *reinterpret_cast<ushort4*>(pv);
    ushort4 b = *reinterpret_cast<ushort4*>(pv + 4);
    a.x = f2bf(bf2f(a.x) / cs[0]); a.y = f2bf(bf2f(a.y) / cs[1]);
    a.z = f2bf(bf2f(a.z) / cs[2]); a.w = f2bf(bf2f(a.w) / cs[3]);
    b.x = f2bf(bf2f(b.x) / cs[4]); b.y = f2bf(bf2f(b.y) / cs[5]);
    b.z = f2bf(bf2f(b.z) / cs[6]); b.w = f2bf(bf2f(b.w) / cs[7]);
    *reinterpret_cast<ushort4*>(pv) = a;
    *reinterpret_cast<ushort4*>(pv + 4) = b;
}

// ---------------- out = (sum of NP partial slabs + resid [+bias]) - mean - std ----------------
// Slabs 0,1 from parts; slabs 2,3 (NP=4) from parts2.
template<int NP, int BIAS>
__global__ __launch_bounds__(256) void addsn_k(const float* __restrict__ parts,
                                               const float* __restrict__ parts2,
                                               long pstride,
                                               const float* __restrict__ resid,
                                               const float* __restrict__ bias,
                                               float* __restrict__ out) {
    __shared__ float sm[8];
    long row = blockIdx.x;
    int tid = threadIdx.x;
    float4 x = reinterpret_cast<const float4*>(resid + row * 1024)[tid];
    #pragma unroll
    for (int p = 0; p < NP; ++p) {
        const float* src = (p < 2) ? (parts + p * pstride) : (parts2 + (p - 2) * pstride);
        float4 a = reinterpret_cast<const float4*>(src + row * 1024)[tid];
        x.x += a.x; x.y += a.y; x.z += a.z; x.w += a.w;
    }
    if (BIAS) {
        float4 bb = reinterpret_cast<const float4*>(bias)[tid];
        x.x += bb.x; x.y += bb.y; x.z += bb.z; x.w += bb.w;
    }
    float s = x.x + x.y + x.z + x.w;
    for (int o = 32; o > 0; o >>= 1) s += __shfl_down(s, o, 64);
    int lane = tid & 63, w = tid >> 6;
    if (lane == 0) sm[w] = s;
    __syncthreads();
    float mean = (sm[0] + sm[1] + sm[2] + sm[3]) * (1.f / 1024.f);
    float d0 = x.x - mean, d1 = x.y - mean, d2 = x.z - mean, d3 = x.w - mean;
    float q = d0 * d0 + d1 * d1 + d2 * d2 + d3 * d3;
    for (int o = 32; o > 0; o >>= 1) q += __shfl_down(q, o, 64);
    if (lane == 0) sm[w + 4] = q;
    __syncthreads();
    float sd = sqrtf((sm[4] + sm[5] + sm[6] + sm[7]) * (1.f / 1023.f));
    float4 ov;
    ov.x = d0 - sd; ov.y = d1 - sd; ov.z = d2 - sd; ov.w = d3 - sd;
    reinterpret_cast<float4*>(out + row * 1024)[tid] = ov;
}

// ---------------- launcher ----------------

extern "C" void kernel_launch(void* const* d_in, const int* in_sizes, int n_in,
                              void* d_out, int out_size, void* d_ws, size_t ws_size,
                              hipStream_t stream) {
    (void)in_sizes; (void)n_in; (void)out_size; (void)ws_size;
    const float* xf   = (const float*)d_in[0];
    const float* yf   = (const float*)d_in[1];
    const float* Wq1  = (const float*)d_in[2];
    const float* Wk1  = (const float*)d_in[3];
    const float* Wv1  = (const float*)d_in[4];
    const float* Wo1  = (const float*)d_in[5];
    const float* Wq2  = (const float*)d_in[6];
    const float* Wk2  = (const float*)d_in[7];
    const float* Wv2  = (const float*)d_in[8];
    const float* Wo2  = (const float*)d_in[9];
    const float* W_in = (const float*)d_in[10];
    const float* b_in = (const float*)d_in[11];
    const float* W_out= (const float*)d_in[12];
    const float* b_out= (const float*)d_in[13];

    // workspace layout (~192 MB)
    char* p = (char*)d_ws;
    auto alloc = [&](size_t bytes) { char* r = p; p += bytes; return r; };
    u16*   yb    = (u16*)alloc(8388608);    // y bf16 (4096x1024)
    u16*   xb    = (u16*)alloc(8388608);    // x bf16
    u16*   W1cat = (u16*)alloc(8388608);    // [Wq1|Wk1|Wv1|Wq2]^T-packed (4096 x 1024)
    u16*   Wkv2t = (u16*)alloc(4194304);    // [Wk2|Wv2] (2048 x 1024)
    u16*   Wo1t  = (u16*)alloc(2097152);
    u16*   Wo2t  = (u16*)alloc(2097152);
    u16*   Winb  = (u16*)alloc(8388608);    // W_in (4096 x 1024) = Bt layout
    u16*   Woutb = (u16*)alloc(8388608);    // W_out (1024 x 4096) = Bt layout
    u16*   QKV   = (u16*)alloc(33554432);   // (4096 x 4096): [Q1|K1|V1|Q2] per (b,t);
                                            // dead after MHA2 -> reused as FFN-out fp32 slabs 2,3
    u16*   KV2   = (u16*)alloc(16777216);   // (4096 x 2048): [K2|V2]
    u16*   Vt    = (u16*)alloc(8388608);    // per b: (1024 hv x 1024 s), scaled by 1/l in place
    u16*   Pb    = (u16*)alloc(33554432);   // FFN hidden (4096x4096 bf16)
    float* csum  = (float*)alloc(262144);   // column sums l [4][16][1024]
    u16*   part  = (u16*)alloc(8388608);    // attn partial (4096 x 1024) bf16
    float* gout  = (float*)alloc(33554432); // fp32 split-K partials, 2 slabs of 16 MB
    float* out1  = (float*)alloc(16777216);

    // ---- converts + weight packs ----
    convert_f2b_k<<<4096, 256, 0, stream>>>(yf, yb);
    convert_f2b_k<<<4096, 256, 0, stream>>>(xf, xb);
    pack_perm_t<<<dim3(1, 16, 16), 256, 0, stream>>>(Wq1, W1cat,           1024, 64);
    pack_perm_t<<<dim3(1, 16, 16), 256, 0, stream>>>(Wk1, W1cat + 1048576, 1024, 64);
    pack_perm_t<<<dim3(1, 16, 16), 256, 0, stream>>>(Wv1, W1cat + 2097152, 1024, 64);
    pack_perm_t<<<dim3(1, 16, 16), 256, 0, stream>>>(Wq2, W1cat + 3145728, 1024, 64);
    pack_perm_t<<<dim3(1, 16, 16), 256, 0, stream>>>(Wk2, Wkv2t,           1024, 64);
    pack_perm_t<<<dim3(1, 16, 16), 256, 0, stream>>>(Wv2, Wkv2t + 1048576, 1024, 64);
    pack_perm_t<<<dim3(16, 16, 1), 256, 0, stream>>>(Wo1, Wo1t,            1024, 1024);
    pack_perm_t<<<dim3(16, 16, 1), 256, 0, stream>>>(Wo2, Wo2t,            1024, 1024);
    convert_f2b_k<<<4096, 256, 0, stream>>>(W_in,  Winb);
    convert_f2b_k<<<4096, 256, 0, stream>>>(W_out, Woutb);

    // attention core: all 4 batches per dispatch.
    auto run_attention = [&](const u16* Q, long ldq, long qbz,
                             const u16* Kp, long ldk, long kbz,
                             const u16* Vp, long ldv, long vbz) {
        transpose_k<<<dim3(16, 16, 4), 256, 0, stream>>>(Vp, ldv, vbz, Vt, 1024L, 1048576L);
        hipMemsetAsync(csum, 0, 262144, stream);
        // l-pass: exp column-sums, no stores. z=(b,h): zi=h (stride 64), zo=b.
        gemm_k<128,128,64,2,2,1,4,0,1><<<dim3(8, 8, 64), 256, 0, stream>>>(
            Q, ldq, 64L, qbz, Kp, ldk, 64L, kbz,
            (void*)Pb, 1024L, 0L, 0L, 16, 64, 0.125f, nullptr, csum);
        vscale_k<<<2048, 256, 0, stream>>>(Vt, csum);
        attn_pv_k<<<512, 256, 0, stream>>>(Q, ldq, qbz, Kp, ldk, kbz, Vt, part);
    };

    // ---- fused projections (8-phase 256^2): QKV1 + Q2 from y (N=4096) ----
    gemm8_k<16,1,0,1><<<256, 512, 0, stream>>>(
        yb, 1024L, W1cat, 1024L, (void*)QKV, nullptr, 4096L, 1024, 1.0f, nullptr, 0L);
    // K2/V2 from x, N=2048
    gemm8_k<8,1,0,1><<<128, 512, 0, stream>>>(
        xb, 1024L, Wkv2t, 1024L, (void*)KV2, nullptr, 2048L, 1024, 1.0f, nullptr, 0L);

    // ---- MHA1 (self-attn on y): Q/K/V at cols 0/1024/2048 of QKV ----
    run_attention(QKV, 4096L, 4194304L, QKV + 1024, 4096L, 4194304L, QKV + 2048, 4096L, 4194304L);
    gemm_k<128,64,64,2,2,0,0,4,2><<<dim3(2 * 512), 256, 0, stream>>>(
        part, 1024L, 0L, 512L, Wo1t, 1024L, 0L, 512L,
        (void*)gout, 1024L, 0L, 4194304L, 1, 512, 1.0f, nullptr, nullptr);
    addsn_k<2,0><<<4096, 256, 0, stream>>>(gout, nullptr, 4194304L, yf, nullptr, out1);

    // ---- MHA2 (q from y at QKV col 3072; k/v from x in KV2) ----
    run_attention(QKV + 3072, 4096L, 4194304L, KV2, 2048L, 2097152L, KV2 + 1024, 2048L, 2097152L);
    gemm_k<128,64,64,2,2,0,0,4,2><<<dim3(2 * 512), 256, 0, stream>>>(
        part, 1024L, 0L, 512L, Wo2t, 1024L, 0L, 512L,
        (void*)gout, 1024L, 0L, 4194304L, 1, 512, 1.0f, nullptr, nullptr);
    addsn_k<2,0><<<4096, 256, 0, stream>>>(gout, nullptr, 4194304L, out1, nullptr, (float*)d_out);

    // ---- FFN on y (hidden in Pb: 4096x4096 bf16), 8-phase GEMMs ----
    gemm8_k<16,1,1,1><<<256, 512, 0, stream>>>(
        yb, 1024L, Winb, 1024L, (void*)Pb, nullptr, 4096L, 1024, 1.0f, b_in, 0L);
    // FFN-out: split-K 4 (full machine); slabs 0,1 -> gout, slabs 2,3 -> dead QKV region
    gemm8_k<4,4,0,0><<<256, 512, 0, stream>>>(
        Pb, 4096L, Woutb, 4096L, (void*)gout, (void*)QKV, 1024L, 1024, 1.0f, nullptr, 4194304L);
    addsn_k<4,1><<<4096, 256, 0, stream>>>(gout, (const float*)QKV, 4194304L,
                                           (const float*)d_out, b_out, (float*)d_out);
}

// Round 6
// 517.732 us; speedup vs baseline: 1.1745x; 1.1745x over previous
//
#include <hip/hip_runtime.h>

// DecoderStack: B=4,T=1024,D=1024,H=16,DK=DV=64,FF=4096
// Softmax over QUERY axis: l_s = sum_t exp(S) via store-free l-pass (EPI=4),
// 1/l_s folded into V (vscale), then fused attn_pv_k recomputes E per tile in
// LDS and multiplies by V — E never touches HBM.
// sub_norm(o) = o - mean - std (ddof=1).
// gemm8_k: REVERTED to R1 (best measured: 42.9 us/dispatch) — 256x256 tile,
// 8 waves, 4-phase-per-K-tile, vmcnt(10), sched_barrier pins + setprio.
// R4 (rolling reads) and R5 (m201 2-tile port) both regressed; surgery stopped.
// R6 NEW: attn_pv_k uses T3-min schedule — K/V double-buffered in LDS,
// next-chunk stage issued BEFORE compute, counted vmcnt(4) (never 0 mid-loop),
// 2 barriers/chunk (mid-chunk barrier dropped: Es rows are wave-local,
// lgkmcnt(0) suffices for the exp-write -> PV-read dependency).

typedef unsigned short u16;
typedef __bf16 bf16x8 __attribute__((ext_vector_type(8)));
typedef float f32x4 __attribute__((ext_vector_type(4)));

__device__ __forceinline__ u16 f2bf(float f) {
    unsigned int u = __float_as_uint(f);
    u += 0x7fffu + ((u >> 16) & 1u);   // RNE; inputs are finite
    return (u16)(u >> 16);
}
__device__ __forceinline__ float bf2f(u16 b) {
    return __uint_as_float(((unsigned int)b) << 16);
}

typedef __attribute__((address_space(1))) const void* as1cv;
typedef __attribute__((address_space(3))) void* as3v;
__device__ __forceinline__ void gl_lds16(const void* g, void* l) {
    __builtin_amdgcn_global_load_lds((as1cv)g, (as3v)l, 16, 0, 0);
}

// ---------------- converts / packs ----------------

__global__ __launch_bounds__(256) void convert_f2b_k(const float* __restrict__ in, u16* __restrict__ out) {
    long i = (long)blockIdx.x * 256 + threadIdx.x;
    float4 v = reinterpret_cast<const float4*>(in)[i];
    ushort4 o;
    o.x = f2bf(v.x); o.y = f2bf(v.y); o.z = f2bf(v.z); o.w = f2bf(v.w);
    reinterpret_cast<ushort4*>(out)[i] = o;
}

// out[p][r][q] = in[p][q][r] (fp32->bf16), LDS-tiled. grid (R/64, Q/64, P)
__global__ __launch_bounds__(256) void pack_perm_t(const float* __restrict__ in, u16* __restrict__ out,
                                                   int Q, int R) {
    __shared__ float tile[64][65];
    int p = blockIdx.z;
    int r0 = blockIdx.x * 64, q0 = blockIdx.y * 64;
    int tx = threadIdx.x & 63, ty = threadIdx.x >> 6;
    const float* inp = in + ((long)p * Q + q0) * R + r0;
    #pragma unroll
    for (int i = 0; i < 64; i += 4)
        tile[ty + i][tx] = inp[(long)(ty + i) * R + tx];
    __syncthreads();
    u16* outp = out + ((long)p * R + r0) * Q + q0;
    #pragma unroll
    for (int i = 0; i < 64; i += 4)
        outp[(long)(ty + i) * Q + tx] = f2bf(tile[tx][ty + i]);
}

// 64x64 tiled bf16 transpose: out[c][r] = in[r][c], batched over z
__global__ __launch_bounds__(256) void transpose_k(const u16* __restrict__ in, long ld_in, long z_in,
                                                   u16* __restrict__ out, long ld_out, long z_out) {
    __shared__ u16 tile[64][66];
    const u16* inz = in + (long)blockIdx.z * z_in;
    u16* outz = out + (long)blockIdx.z * z_out;
    int r0 = blockIdx.y * 64;
    int c0 = blockIdx.x * 64;
    int tx = threadIdx.x & 63, ty = threadIdx.x >> 6;
    #pragma unroll
    for (int i = 0; i < 64; i += 4)
        tile[ty + i][tx] = inz[(long)(r0 + ty + i) * ld_in + c0 + tx];
    __syncthreads();
    #pragma unroll
    for (int i = 0; i < 64; i += 4)
        outz[(long)(c0 + ty + i) * ld_out + r0 + tx] = tile[tx][ty + i];
}

// ---------------- legacy GEMM (kept for l-pass EPI=4 and small Wo split-K) ----------------
template<int BM, int BN, int BK, int WM, int WN, int OUT_BF16, int EPI, int SWZ, int KS>
__global__ __launch_bounds__(256) void gemm_k(
    const u16* __restrict__ A, long lda, long a_zin, long a_zout,
    const u16* __restrict__ B, long ldb, long b_zin, long b_zout,
    void* __restrict__ Cv, long ldc, long c_zin, long c_zout,
    int zin, int K, float alpha, const float* __restrict__ bias,
    float* __restrict__ csum)
{
    static_assert(BK == 64, "staging assumes BK=64");
    constexpr int WTM = BM / WM;
    constexpr int WTN = BN / WN;
    constexpr int TM = WTM / 16;
    constexpr int TN = WTN / 16;
    __shared__ __align__(16) u16 smem[(BM + BN) * BK];
    u16* As = smem;
    u16* Bs = smem + BM * BK;

    int bx, by, z;
    if (SWZ == 4) {
        int L = blockIdx.x;
        if (KS > 1) { z = L >> 9; L &= 511; } else { z = 0; }
        by = (L & 7) * 4 + ((L >> 3) & 3);
        bx = L >> 5;
    } else {
        bx = blockIdx.x; by = blockIdx.y; z = blockIdx.z;
    }
    int zi = z % zin, zo = z / zin;
    A += (long)zi * a_zin + (long)zo * a_zout;
    B += (long)zi * b_zin + (long)zo * b_zout;
    long coff = (long)zi * c_zin + (long)zo * c_zout;

    int tid = threadIdx.x;
    int lane = tid & 63;
    int wave = tid >> 6;
    int wm = wave / WN, wn = wave % WN;
    long bm0 = (long)by * BM, bn0 = (long)bx * BN;

    f32x4 acc[TM][TN];
    #pragma unroll
    for (int i = 0; i < TM; ++i)
        #pragma unroll
        for (int j = 0; j < TN; ++j) {
            acc[i][j][0] = 0.f; acc[i][j][1] = 0.f;
            acc[i][j][2] = 0.f; acc[i][j][3] = 0.f;
        }

    int r16 = lane & 15;
    int quad = lane >> 4;
    int l8 = lane >> 3;                    // stripe row
    int gsw = ((lane & 7) ^ l8) * 8;       // swizzled global col (elements)

    constexpr int ASTR = BM / 8;
    constexpr int BSTR = BN / 8;

    for (int k0 = 0; k0 < K; k0 += BK) {
        #pragma unroll
        for (int s = wave; s < ASTR; s += 4)
            gl_lds16(&A[(bm0 + s * 8 + l8) * lda + k0 + gsw], &As[s * 512]);
        #pragma unroll
        for (int s = wave; s < BSTR; s += 4)
            gl_lds16(&B[(bn0 + s * 8 + l8) * ldb + k0 + gsw], &Bs[s * 512]);
        __syncthreads();
        #pragma unroll
        for (int kk = 0; kk < BK; kk += 32) {
            int cb = (kk >> 3) + quad;
            bf16x8 av[TM], bv[TN];
            #pragma unroll
            for (int i = 0; i < TM; ++i) {
                int r = wm * WTM + i * 16 + r16;
                av[i] = *reinterpret_cast<const bf16x8*>(&As[r * 64 + ((cb ^ (r & 7)) * 8)]);
            }
            #pragma unroll
            for (int j = 0; j < TN; ++j) {
                int r = wn * WTN + j * 16 + r16;
                bv[j] = *reinterpret_cast<const bf16x8*>(&Bs[r * 64 + ((cb ^ (r & 7)) * 8)]);
            }
            #pragma unroll
            for (int i = 0; i < TM; ++i)
                #pragma unroll
                for (int j = 0; j < TN; ++j)
                    acc[i][j] = __builtin_amdgcn_mfma_f32_16x16x32_bf16(av[i], bv[j], acc[i][j], 0, 0, 0);
        }
        __syncthreads();
    }

    int rb = quad * 4;

    if (EPI == 4) {
        // exp + column sums only; no C store. csum layout [z][1024].
        float csl[TN];
        #pragma unroll
        for (int j = 0; j < TN; ++j) csl[j] = 0.f;
        #pragma unroll
        for (int i = 0; i < TM; ++i)
            #pragma unroll
            for (int j = 0; j < TN; ++j)
                #pragma unroll
                for (int r = 0; r < 4; ++r)
                    csl[j] += __expf(acc[i][j][r] * alpha);
        #pragma unroll
        for (int j = 0; j < TN; ++j) {
            float cs = csl[j];
            cs += __shfl_xor(cs, 16, 64);
            cs += __shfl_xor(cs, 32, 64);
            if (quad == 0) {
                long col = bn0 + wn * WTN + j * 16 + r16;
                atomicAdd(&csum[((long)zo * zin + zi) * 1024 + col], cs);
            }
        }
        return;
    }

    // ---- LDS-staged store epilogue ----
    constexpr int EB = OUT_BF16 ? 2 : 4;
    constexpr int CH = 16 / EB;
    constexpr int STRIDE = BN + CH;
    constexpr int LDSB = (BM + BN) * BK * 2;
    constexpr int EPASS = (BM * STRIDE * EB > LDSB) ? 2 : 1;
    constexpr int RPP = BM / EPASS;
    static_assert(RPP * STRIDE * EB <= LDSB, "epilogue tile overflows LDS");
    static_assert(EPASS == 1 || (WM == 2 && WTM == RPP), "pass/wave row alignment");
    constexpr int CPR = BN / CH;
    constexpr int NCH = RPP * CPR / 256;
    static_assert(RPP * CPR % 256 == 0, "store mapping");

    float* Ef = reinterpret_cast<float*>(smem);
    char* Cb = reinterpret_cast<char*>(Cv);

    for (int pass = 0; pass < EPASS; ++pass) {
        int p0 = pass * RPP;
        __syncthreads();
        #pragma unroll
        for (int i = 0; i < TM; ++i) {
            #pragma unroll
            for (int j = 0; j < TN; ++j) {
                int lcol = wn * WTN + j * 16 + r16;
                float bsv = (EPI == 1 || EPI == 2) ? bias[bn0 + lcol] : 0.f;
                #pragma unroll
                for (int r = 0; r < 4; ++r) {
                    int lrow = wm * WTM + i * 16 + rb + r;
                    if ((unsigned)(lrow - p0) < (unsigned)RPP) {
                        float v = acc[i][j][r] * alpha;
                        if (EPI == 1) { v += bsv; v = v > 0.f ? v : 0.f; }
                        else if (EPI == 2) { v += bsv; }
                        if (OUT_BF16) smem[(lrow - p0) * STRIDE + lcol] = f2bf(v);
                        else          Ef[(lrow - p0) * STRIDE + lcol] = v;
                    }
                }
            }
        }
        __syncthreads();
        #pragma unroll
        for (int c = 0; c < NCH; ++c) {
            int cid = tid + c * 256;
            int row = cid / CPR, ch = cid - row * CPR;
            int4 v = *reinterpret_cast<const int4*>(
                reinterpret_cast<const char*>(smem) + (row * STRIDE + ch * CH) * EB);
            long gidx = coff + (bm0 + p0 + row) * ldc + bn0 + ch * CH;
            *reinterpret_cast<int4*>(Cb + gidx * EB) = v;
        }
    }
}

// ---------------- 8-phase 256x256 GEMM (R1 schedule, best measured) ----------------
// Per K-tile t, 4 phases = (ih,jh) quadrants x K=64, 2 raw barriers each:
//   ph1: read av(ih0),bv(jh0) | stage (t+1).A-half1 | vmcnt(10)
//   ph2: read bv(jh1)         | stage (t+2).A-half0 | vmcnt(10)
//   ph3: read av(ih1)         | stage (t+2).B-half0 |
//   ph4:                      | stage (t+2).B-half1 | vmcnt(10)
// 2 loads/thread per half-tile; 5 half-tiles (10 loads) stay in flight.
// Tail tiles T-2/T-1 use derived counts 10/8/4 and 2/0.

__device__ __forceinline__ void bar_raw() {
    asm volatile("" ::: "memory");
    __builtin_amdgcn_s_barrier();
    asm volatile("" ::: "memory");
}

template<int N> __device__ __forceinline__ void vmw() {
    if constexpr (N == 10) asm volatile("s_waitcnt vmcnt(10)" ::: "memory");
    else if constexpr (N == 8) asm volatile("s_waitcnt vmcnt(8)" ::: "memory");
    else if constexpr (N == 4) asm volatile("s_waitcnt vmcnt(4)" ::: "memory");
    else if constexpr (N == 2) asm volatile("s_waitcnt vmcnt(2)" ::: "memory");
    else if constexpr (N == 0) asm volatile("s_waitcnt vmcnt(0)" ::: "memory");
}

// stage one half-tile (16 stripes of 8 rows x 64 cols) = 2 gl_lds per thread
__device__ __forceinline__ void stage_half(const u16* __restrict__ base, long ld, int kt,
                                           u16* __restrict__ lds, int half, int wave) {
    const u16* src = base + (long)kt * 64;
    #pragma unroll
    for (int u = 0; u < 2; ++u) {
        int s = half * 16 + u * 8 + wave;
        gl_lds16(src + (long)(s * 8) * ld, lds + s * 512);
    }
}

template<int IH>
__device__ __forceinline__ void read_a8(bf16x8 (&av)[4][2], const u16* __restrict__ As,
                                        int wm, int r16, int quad) {
    #pragma unroll
    for (int ii = 0; ii < 4; ++ii) {
        int r = IH * 128 + wm * 64 + ii * 16 + r16;
        #pragma unroll
        for (int kx = 0; kx < 2; ++kx)
            av[ii][kx] = *reinterpret_cast<const bf16x8*>(&As[r * 64 + (((kx * 4 + quad) ^ (r & 7)) * 8)]);
    }
}

template<int JH>
__device__ __forceinline__ void read_b8(bf16x8 (&bv)[2][2], const u16* __restrict__ Bs,
                                        int wn, int r16, int quad) {
    #pragma unroll
    for (int j = 0; j < 2; ++j) {
        int r = JH * 128 + wn * 32 + j * 16 + r16;
        #pragma unroll
        for (int kx = 0; kx < 2; ++kx)
            bv[j][kx] = *reinterpret_cast<const bf16x8*>(&Bs[r * 64 + (((kx * 4 + quad) ^ (r & 7)) * 8)]);
    }
}

template<int IH, int JH>
__device__ __forceinline__ void mfma_q(f32x4 (&acc)[2][4][2][2],
                                       const bf16x8 (&av)[4][2], const bf16x8 (&bv)[2][2]) {
    #pragma unroll
    for (int kx = 0; kx < 2; ++kx)
        #pragma unroll
        for (int ii = 0; ii < 4; ++ii)
            #pragma unroll
            for (int j = 0; j < 2; ++j)
                acc[IH][ii][JH][j] = __builtin_amdgcn_mfma_f32_16x16x32_bf16(
                    av[ii][kx], bv[j][kx], acc[IH][ii][JH][j], 0, 0, 0);
}

// MODE 0: steady; 1: t=T-2 (only (t+1).A1 staged); 2: t=T-1 (no staging)
template<int MODE>
__device__ __forceinline__ void tile_iter(
    int t, f32x4 (&acc)[2][4][2][2], bf16x8 (&av)[4][2], bf16x8 (&bvh)[2][2][2],
    u16* __restrict__ smem, const u16* __restrict__ Ab, long lda,
    const u16* __restrict__ Bb, long ldb, int wave, int wm, int wn, int r16, int quad)
{
    u16* As0 = smem + (t & 1) * 32768;          // buf for tile t (also target of t+2 stages)
    u16* Bs0 = As0 + 16384;
    u16* As1 = smem + ((t + 1) & 1) * 32768;    // buf for tile t+1
    // ---- ph1 (ih0,jh0)
    read_a8<0>(av, As0, wm, r16, quad);
    read_b8<0>(bvh[0], Bs0, wn, r16, quad);
    if (MODE < 2) stage_half(Ab, lda, t + 1, As1, 1, wave);
    vmw<MODE == 0 ? 10 : (MODE == 1 ? 10 : 2)>();
    bar_raw(); __builtin_amdgcn_sched_barrier(0);
    __builtin_amdgcn_s_setprio(1);
    mfma_q<0, 0>(acc, av, bvh[0]);
    __builtin_amdgcn_s_setprio(0);
    __builtin_amdgcn_sched_barrier(0);
    bar_raw();
    // ---- ph2 (ih0,jh1)
    read_b8<1>(bvh[1], Bs0, wn, r16, quad);
    if (MODE == 0) stage_half(Ab, lda, t + 2, As0, 0, wave);
    vmw<MODE == 0 ? 10 : (MODE == 1 ? 8 : 0)>();
    bar_raw(); __builtin_amdgcn_sched_barrier(0);
    __builtin_amdgcn_s_setprio(1);
    mfma_q<0, 1>(acc, av, bvh[1]);
    __builtin_amdgcn_s_setprio(0);
    __builtin_amdgcn_sched_barrier(0);
    bar_raw();
    // ---- ph3 (ih1,jh0)
    read_a8<1>(av, As0, wm, r16, quad);
    if (MODE == 0) stage_half(Bb, ldb, t + 2, Bs0, 0, wave);
    bar_raw(); __builtin_amdgcn_sched_barrier(0);
    __builtin_amdgcn_s_setprio(1);
    mfma_q<1, 0>(acc, av, bvh[0]);
    __builtin_amdgcn_s_setprio(0);
    __builtin_amdgcn_sched_barrier(0);
    bar_raw();
    // ---- ph4 (ih1,jh1)
    if (MODE == 0) stage_half(Bb, ldb, t + 2, Bs0, 1, wave);
    if (MODE < 2) vmw<MODE == 0 ? 10 : 4>();
    bar_raw(); __builtin_amdgcn_sched_barrier(0);
    __builtin_amdgcn_s_setprio(1);
    mfma_q<1, 1>(acc, av, bvh[1]);
    __builtin_amdgcn_s_setprio(0);
    __builtin_amdgcn_sched_barrier(0);
    bar_raw();
}

// grid = 16*NT*KS blocks of 512. EPI: 0 none, 1 bias+relu. KS>1: z picks K-chunk,
// output slab z: z<2 -> Cv + (z&1)*czs, z>=2 -> Cv2 + (z&1)*czs (fp32).
template<int NT, int KS, int EPI, int OUT_BF16>
__global__ __launch_bounds__(512, 2) void gemm8_k(
    const u16* __restrict__ A, long lda,
    const u16* __restrict__ B, long ldb,
    void* __restrict__ Cv, void* __restrict__ Cv2, long ldc,
    int K, float alpha, const float* __restrict__ bias, long czs)
{
    __shared__ __align__(16) u16 smem[65536];   // 128 KiB

    int L = blockIdx.x;
    int z = 0;
    if (KS > 1) { z = L / (16 * NT); L -= z * 16 * NT; }
    int by = (L & 7) * 2 + ((L >> 3) & 1);      // XCD-contiguous M-rows
    int bx = L >> 4;
    if (KS > 1) { A += (long)z * K; B += (long)z * K; }

    int tid = threadIdx.x;
    int lane = tid & 63, wave = tid >> 6;
    int wm = wave >> 2, wn = wave & 3;
    int r16 = lane & 15, quad = lane >> 4, l8 = lane >> 3;
    int gsw = ((lane & 7) ^ l8) * 8;
    long bm0 = (long)by * 256, bn0 = (long)bx * 256;
    const u16* Ab = A + (bm0 + l8) * lda + gsw;
    const u16* Bb = B + (bn0 + l8) * ldb + gsw;

    f32x4 acc[2][4][2][2];
    #pragma unroll
    for (int a0 = 0; a0 < 2; ++a0)
        #pragma unroll
        for (int a1 = 0; a1 < 4; ++a1)
            #pragma unroll
            for (int a2 = 0; a2 < 2; ++a2)
                #pragma unroll
                for (int a3 = 0; a3 < 2; ++a3) {
                    acc[a0][a1][a2][a3][0] = 0.f; acc[a0][a1][a2][a3][1] = 0.f;
                    acc[a0][a1][a2][a3][2] = 0.f; acc[a0][a1][a2][a3][3] = 0.f;
                }
    bf16x8 av[4][2];
    bf16x8 bvh[2][2][2];

    int T = K >> 6;   // >= 3

    // prologue issue stream: [0.A0, 0.B0, 0.B1, 0.A1, 1.A0, 1.B0, 1.B1]
    stage_half(Ab, lda, 0, smem,         0, wave);
    stage_half(Bb, ldb, 0, smem + 16384, 0, wave);
    stage_half(Bb, ldb, 0, smem + 16384, 1, wave);
    stage_half(Ab, lda, 0, smem,         1, wave);
    stage_half(Ab, lda, 1, smem + 32768, 0, wave);
    stage_half(Bb, ldb, 1, smem + 49152, 0, wave);
    stage_half(Bb, ldb, 1, smem + 49152, 1, wave);
    vmw<10>();          // 14 issued -> oldest 4 (0.A0,0.B0) landed
    bar_raw();

    for (int t = 0; t < T - 2; ++t)
        tile_iter<0>(t, acc, av, bvh, smem, Ab, lda, Bb, ldb, wave, wm, wn, r16, quad);
    tile_iter<1>(T - 2, acc, av, bvh, smem, Ab, lda, Bb, ldb, wave, wm, wn, r16, quad);
    tile_iter<2>(T - 1, acc, av, bvh, smem, Ab, lda, Bb, ldb, wave, wm, wn, r16, quad);

    // ---- epilogue: stage to LDS (row-XOR-swizzled), coalesced int4 stores
    constexpr int EB = OUT_BF16 ? 2 : 4;
    constexpr int EPASS = OUT_BF16 ? 1 : 2;   // f32 = 2 passes of 128 rows (ih=pass)
    char* Cb = reinterpret_cast<char*>((KS > 1 && z >= 2) ? Cv2 : Cv);
    if (KS > 1) Cb += (long)(z & 1) * czs * EB;
    float bsv[2][2];
    if (EPI == 1) {
        #pragma unroll
        for (int jh = 0; jh < 2; ++jh)
            #pragma unroll
            for (int j = 0; j < 2; ++j)
                bsv[jh][j] = bias[bn0 + jh * 128 + wn * 32 + j * 16 + r16];
    }
    u16* sm16 = smem;
    float* smf = reinterpret_cast<float*>(smem);
    #pragma unroll
    for (int pass = 0; pass < EPASS; ++pass) {
        bar_raw();
        #pragma unroll
        for (int ih = 0; ih < 2; ++ih) {
            if (EPASS == 2 && ih != pass) continue;
            #pragma unroll
            for (int ii = 0; ii < 4; ++ii)
                #pragma unroll
                for (int jh = 0; jh < 2; ++jh)
                    #pragma unroll
                    for (int j = 0; j < 2; ++j)
                        #pragma unroll
                        for (int r = 0; r < 4; ++r) {
                            int lrow = (EPASS == 2 ? 0 : ih * 128) + wm * 64 + ii * 16 + quad * 4 + r;
                            int lcol = jh * 128 + wn * 32 + j * 16 + r16;
                            float v = acc[ih][ii][jh][j][r] * alpha;
                            if (EPI == 1) { v += bsv[jh][j]; v = v > 0.f ? v : 0.f; }
                            int scol = lcol ^ ((lrow & 7) * 8);
                            if (OUT_BF16) sm16[lrow * 256 + scol] = f2bf(v);
                            else          smf[lrow * 256 + scol] = v;
                        }
        }
        bar_raw();
        constexpr int CH = 16 / EB;
        constexpr int CPR = 256 / CH;
        constexpr int NCH = (OUT_BF16 ? 256 : 128) * CPR / 512;
        #pragma unroll
        for (int c = 0; c < NCH; ++c) {
            int cid = tid + c * 512;
            int row = cid / CPR, ch = cid - row * CPR;
            int col = (ch * CH) ^ ((row & 7) * 8);
            int4 v = *reinterpret_cast<const int4*>(
                reinterpret_cast<const char*>(smem) + ((long)row * 256 + col) * EB);
            long grow = bm0 + pass * 128 + row;
            *reinterpret_cast<int4*>(Cb + (grow * ldc + bn0 + ch * CH) * EB) = v;
        }
    }
}

// ---------------- fused attention PV: recompute E per tile, x scaled V ----------------
// Grid 512 blocks: L -> xcd=L&7: head=(L&7)*2+((L>>3)&1), tb=(L>>4)&7, b=L>>7.
// Per block: out[128 t][64 v] = sum_s exp(0.125*Q K^T) * Vt_scaled.
// R6: K/V double-buffered; stage(c+1) issued BEFORE chunk c compute; counted
// vmcnt(4) (= stage(c+1)'s 4 loads/thread in flight) + barrier; mid-chunk
// barrier removed — Es rows are wave-local (write rows wm*64+i*16+quad*4+r,
// read rows wm*64+i*16+r16, same wm), so lgkmcnt(0) orders write->read.
// End-of-chunk barrier retained (cross-wave WAR: stage(c+2) overwrites rows
// of buf[cur] read by other waves). Prologue: Q (4 loads) + K/V(0) (4 loads);
// chunk0's vmcnt(4) covers both. Last chunk: vmcnt(0).
__global__ __launch_bounds__(256) void attn_pv_k(
    const u16* __restrict__ Qg, long ldq, long qbz,
    const u16* __restrict__ Kg, long ldk, long kbz,
    const u16* __restrict__ Vg,            // [b][1024 hv][1024 s], pre-scaled by 1/l
    u16* __restrict__ outg)                // part: [b][1024 t][1024 (h*64+v)]
{
    __shared__ __align__(16) u16 Qs[128 * 64];
    __shared__ __align__(16) u16 Ks[2][64 * 64];
    __shared__ __align__(16) u16 Vs[2][64 * 64];
    __shared__ __align__(16) u16 Es[128 * 64];

    int L = blockIdx.x;
    int h  = (L & 7) * 2 + ((L >> 3) & 1);
    int tb = (L >> 4) & 7;
    int b  = L >> 7;

    const u16* Q  = Qg + (long)b * qbz + h * 64;
    const u16* Kp = Kg + (long)b * kbz + h * 64;
    const u16* Vp = Vg + (long)b * 1048576 + (long)h * 65536;
    u16* outp = outg + (long)b * 1048576 + (long)tb * 131072 + h * 64;

    int tid = threadIdx.x, lane = tid & 63, wave = tid >> 6;
    int wm = wave >> 1, wn = wave & 1;
    int r16 = lane & 15, quad = lane >> 4, l8 = lane >> 3;
    int gsw = ((lane & 7) ^ l8) * 8;
    long t0 = (long)tb * 128;

    // prologue: Q (4 loads/thread) + K/V chunk 0 (4 loads/thread)
    #pragma unroll
    for (int s = wave; s < 16; s += 4)
        gl_lds16(&Q[(t0 + s * 8 + l8) * ldq + gsw], &Qs[s * 512]);
    #pragma unroll
    for (int s = wave; s < 8; s += 4) {
        gl_lds16(&Kp[(long)(s * 8 + l8) * ldk + gsw], &Ks[0][s * 512]);
        gl_lds16(&Vp[(long)(s * 8 + l8) * 1024 + gsw], &Vs[0][s * 512]);
    }

    f32x4 acc[4][2];
    #pragma unroll
    for (int i = 0; i < 4; ++i)
        #pragma unroll
        for (int j = 0; j < 2; ++j) {
            acc[i][j][0] = 0.f; acc[i][j][1] = 0.f;
            acc[i][j][2] = 0.f; acc[i][j][3] = 0.f;
        }

    for (int sc = 0; sc < 16; ++sc) {
        const u16* Ksc = Ks[sc & 1];
        const u16* Vsc = Vs[sc & 1];
        // issue next chunk's staging into the other buffer (its previous
        // contents were last read in chunk sc-1, before the barrier we passed)
        if (sc < 15) {
            int nc = sc + 1;
            u16* Kn = Ks[nc & 1];
            u16* Vn = Vs[nc & 1];
            #pragma unroll
            for (int s = wave; s < 8; s += 4) {
                gl_lds16(&Kp[(long)(nc * 64 + s * 8 + l8) * ldk + gsw], &Kn[s * 512]);
                gl_lds16(&Vp[(long)(s * 8 + l8) * 1024 + nc * 64 + gsw], &Vn[s * 512]);
            }
            asm volatile("s_waitcnt vmcnt(4)" ::: "memory");   // chunk sc (and Q) landed
        } else {
            asm volatile("s_waitcnt vmcnt(0)" ::: "memory");   // last chunk landed
        }
        bar_raw();                            // all waves' chunk-sc loads visible

        // E-chunk = Q x K^T (128x64, contraction 64)
        f32x4 e[4][2];
        #pragma unroll
        for (int i = 0; i < 4; ++i)
            #pragma unroll
            for (int j = 0; j < 2; ++j) {
                e[i][j][0] = 0.f; e[i][j][1] = 0.f;
                e[i][j][2] = 0.f; e[i][j][3] = 0.f;
            }
        #pragma unroll
        for (int kk = 0; kk < 64; kk += 32) {
            int cb = (kk >> 3) + quad;
            bf16x8 av[4], bv[2];
            #pragma unroll
            for (int i = 0; i < 4; ++i) {
                int r = wm * 64 + i * 16 + r16;
                av[i] = *reinterpret_cast<const bf16x8*>(&Qs[r * 64 + ((cb ^ (r & 7)) * 8)]);
            }
            #pragma unroll
            for (int j = 0; j < 2; ++j) {
                int r = wn * 32 + j * 16 + r16;
                bv[j] = *reinterpret_cast<const bf16x8*>(&Ksc[r * 64 + ((cb ^ (r & 7)) * 8)]);
            }
            #pragma unroll
            for (int i = 0; i < 4; ++i)
                #pragma unroll
                for (int j = 0; j < 2; ++j)
                    e[i][j] = __builtin_amdgcn_mfma_f32_16x16x32_bf16(av[i], bv[j], e[i][j], 0, 0, 0);
        }
        // exp + write to Es (C-frag: row=quad*4+r, col=r16; XOR-swizzled rows)
        #pragma unroll
        for (int i = 0; i < 4; ++i)
            #pragma unroll
            for (int j = 0; j < 2; ++j) {
                int lcol = wn * 32 + j * 16 + r16;
                #pragma unroll
                for (int r = 0; r < 4; ++r) {
                    int lrow = wm * 64 + i * 16 + quad * 4 + r;
                    float v = __expf(e[i][j][r] * 0.125f);
                    Es[lrow * 64 + (((lcol >> 3) ^ (lrow & 7)) * 8) + (lcol & 7)] = f2bf(v);
                }
            }
        // wave-local Es write->read: order via lgkmcnt (no cross-wave barrier)
        asm volatile("s_waitcnt lgkmcnt(0)" ::: "memory");

        // acc += E-chunk x Vs^T (contraction over s-chunk)
        #pragma unroll
        for (int kk = 0; kk < 64; kk += 32) {
            int cb = (kk >> 3) + quad;
            bf16x8 av[4], bv[2];
            #pragma unroll
            for (int i = 0; i < 4; ++i) {
                int r = wm * 64 + i * 16 + r16;
                av[i] = *reinterpret_cast<const bf16x8*>(&Es[r * 64 + ((cb ^ (r & 7)) * 8)]);
            }
            #pragma unroll
            for (int j = 0; j < 2; ++j) {
                int r = wn * 32 + j * 16 + r16;
                bv[j] = *reinterpret_cast<const bf16x8*>(&Vsc[r * 64 + ((cb ^ (r & 7)) * 8)]);
            }
            #pragma unroll
            for (int i = 0; i < 4; ++i)
                #pragma unroll
                for (int j = 0; j < 2; ++j)
                    acc[i][j] = __builtin_amdgcn_mfma_f32_16x16x32_bf16(av[i], bv[j], acc[i][j], 0, 0, 0);
        }
        bar_raw();                 // all waves done reading buf[sc&1] K/V
    }

    #pragma unroll
    for (int i = 0; i < 4; ++i)
        #pragma unroll
        for (int j = 0; j < 2; ++j) {
            int lcol = wn * 32 + j * 16 + r16;
            #pragma unroll
            for (int r = 0; r < 4; ++r) {
                int lrow = wm * 64 + i * 16 + quad * 4 + r;
                outp[(long)lrow * 1024 + lcol] = f2bf(acc[i][j][r]);
            }
        }
}

// ---------------- Vt *= 1/l over all 4 batches: csum [4][16][1024] ----------------
__global__ __launch_bounds__(256) void vscale_k(u16* __restrict__ Vt, const float* __restrict__ csum) {
    long idx = (long)blockIdx.x * 256 + threadIdx.x;   // grid 2048
    int slab = (int)(idx >> 17);
    int rem = (int)(idx & 131071);
    int hv = rem >> 7;
    int s8 = (rem & 127) * 8;
    const float* cs = csum + slab * 16384 + (hv >> 6) * 1024 + s8;
    u16* pv = Vt + (long)slab * 1048576 + (long)hv * 1024 + s8;
    ushort4 a = *reinterpret_cast<ushort4*>(pv);
    ushort4 b = *reinterpret_cast<ushort4*>(pv + 4);
    a.x = f2bf(bf2f(a.x) / cs[0]); a.y = f2bf(bf2f(a.y) / cs[1]);
    a.z = f2bf(bf2f(a.z) / cs[2]); a.w = f2bf(bf2f(a.w) / cs[3]);
    b.x = f2bf(bf2f(b.x) / cs[4]); b.y = f2bf(bf2f(b.y) / cs[5]);
    b.z = f2bf(bf2f(b.z) / cs[6]); b.w = f2bf(bf2f(b.w) / cs[7]);
    *reinterpret_cast<ushort4*>(pv) = a;
    *reinterpret_cast<ushort4*>(pv + 4) = b;
}

// ---------------- out = (sum of NP partial slabs + resid [+bias]) - mean - std ----------------
// Slabs 0,1 from parts; slabs 2,3 (NP=4) from parts2.
template<int NP, int BIAS>
__global__ __launch_bounds__(256) void addsn_k(const float* __restrict__ parts,
                                               const float* __restrict__ parts2,
                                               long pstride,
                                               const float* __restrict__ resid,
                                               const float* __restrict__ bias,
                                               float* __restrict__ out) {
    __shared__ float sm[8];
    long row = blockIdx.x;
    int tid = threadIdx.x;
    float4 x = reinterpret_cast<const float4*>(resid + row * 1024)[tid];
    #pragma unroll
    for (int p = 0; p < NP; ++p) {
        const float* src = (p < 2) ? (parts + p * pstride) : (parts2 + (p - 2) * pstride);
        float4 a = reinterpret_cast<const float4*>(src + row * 1024)[tid];
        x.x += a.x; x.y += a.y; x.z += a.z; x.w += a.w;
    }
    if (BIAS) {
        float4 bb = reinterpret_cast<const float4*>(bias)[tid];
        x.x += bb.x; x.y += bb.y; x.z += bb.z; x.w += bb.w;
    }
    float s = x.x + x.y + x.z + x.w;
    for (int o = 32; o > 0; o >>= 1) s += __shfl_down(s, o, 64);
    int lane = tid & 63, w = tid >> 6;
    if (lane == 0) sm[w] = s;
    __syncthreads();
    float mean = (sm[0] + sm[1] + sm[2] + sm[3]) * (1.f / 1024.f);
    float d0 = x.x - mean, d1 = x.y - mean, d2 = x.z - mean, d3 = x.w - mean;
    float q = d0 * d0 + d1 * d1 + d2 * d2 + d3 * d3;
    for (int o = 32; o > 0; o >>= 1) q += __shfl_down(q, o, 64);
    if (lane == 0) sm[w + 4] = q;
    __syncthreads();
    float sd = sqrtf((sm[4] + sm[5] + sm[6] + sm[7]) * (1.f / 1023.f));
    float4 ov;
    ov.x = d0 - sd; ov.y = d1 - sd; ov.z = d2 - sd; ov.w = d3 - sd;
    reinterpret_cast<float4*>(out + row * 1024)[tid] = ov;
}

// ---------------- launcher ----------------

extern "C" void kernel_launch(void* const* d_in, const int* in_sizes, int n_in,
                              void* d_out, int out_size, void* d_ws, size_t ws_size,
                              hipStream_t stream) {
    (void)in_sizes; (void)n_in; (void)out_size; (void)ws_size;
    const float* xf   = (const float*)d_in[0];
    const float* yf   = (const float*)d_in[1];
    const float* Wq1  = (const float*)d_in[2];
    const float* Wk1  = (const float*)d_in[3];
    const float* Wv1  = (const float*)d_in[4];
    const float* Wo1  = (const float*)d_in[5];
    const float* Wq2  = (const float*)d_in[6];
    const float* Wk2  = (const float*)d_in[7];
    const float* Wv2  = (const float*)d_in[8];
    const float* Wo2  = (const float*)d_in[9];
    const float* W_in = (const float*)d_in[10];
    const float* b_in = (const float*)d_in[11];
    const float* W_out= (const float*)d_in[12];
    const float* b_out= (const float*)d_in[13];

    // workspace layout (~192 MB)
    char* p = (char*)d_ws;
    auto alloc = [&](size_t bytes) { char* r = p; p += bytes; return r; };
    u16*   yb    = (u16*)alloc(8388608);    // y bf16 (4096x1024)
    u16*   xb    = (u16*)alloc(8388608);    // x bf16
    u16*   W1cat = (u16*)alloc(8388608);    // [Wq1|Wk1|Wv1|Wq2]^T-packed (4096 x 1024)
    u16*   Wkv2t = (u16*)alloc(4194304);    // [Wk2|Wv2] (2048 x 1024)
    u16*   Wo1t  = (u16*)alloc(2097152);
    u16*   Wo2t  = (u16*)alloc(2097152);
    u16*   Winb  = (u16*)alloc(8388608);    // W_in (4096 x 1024) = Bt layout
    u16*   Woutb = (u16*)alloc(8388608);    // W_out (1024 x 4096) = Bt layout
    u16*   QKV   = (u16*)alloc(33554432);   // (4096 x 4096): [Q1|K1|V1|Q2] per (b,t);
                                            // dead after MHA2 -> reused as FFN-out fp32 slabs 2,3
    u16*   KV2   = (u16*)alloc(16777216);   // (4096 x 2048): [K2|V2]
    u16*   Vt    = (u16*)alloc(8388608);    // per b: (1024 hv x 1024 s), scaled by 1/l in place
    u16*   Pb    = (u16*)alloc(33554432);   // FFN hidden (4096x4096 bf16)
    float* csum  = (float*)alloc(262144);   // column sums l [4][16][1024]
    u16*   part  = (u16*)alloc(8388608);    // attn partial (4096 x 1024) bf16
    float* gout  = (float*)alloc(33554432); // fp32 split-K partials, 2 slabs of 16 MB
    float* out1  = (float*)alloc(16777216);

    // ---- converts + weight packs ----
    convert_f2b_k<<<4096, 256, 0, stream>>>(yf, yb);
    convert_f2b_k<<<4096, 256, 0, stream>>>(xf, xb);
    pack_perm_t<<<dim3(1, 16, 16), 256, 0, stream>>>(Wq1, W1cat,           1024, 64);
    pack_perm_t<<<dim3(1, 16, 16), 256, 0, stream>>>(Wk1, W1cat + 1048576, 1024, 64);
    pack_perm_t<<<dim3(1, 16, 16), 256, 0, stream>>>(Wv1, W1cat + 2097152, 1024, 64);
    pack_perm_t<<<dim3(1, 16, 16), 256, 0, stream>>>(Wq2, W1cat + 3145728, 1024, 64);
    pack_perm_t<<<dim3(1, 16, 16), 256, 0, stream>>>(Wk2, Wkv2t,           1024, 64);
    pack_perm_t<<<dim3(1, 16, 16), 256, 0, stream>>>(Wv2, Wkv2t + 1048576, 1024, 64);
    pack_perm_t<<<dim3(16, 16, 1), 256, 0, stream>>>(Wo1, Wo1t,            1024, 1024);
    pack_perm_t<<<dim3(16, 16, 1), 256, 0, stream>>>(Wo2, Wo2t,            1024, 1024);
    convert_f2b_k<<<4096, 256, 0, stream>>>(W_in,  Winb);
    convert_f2b_k<<<4096, 256, 0, stream>>>(W_out, Woutb);

    // attention core: all 4 batches per dispatch.
    auto run_attention = [&](const u16* Q, long ldq, long qbz,
                             const u16* Kp, long ldk, long kbz,
                             const u16* Vp, long ldv, long vbz) {
        transpose_k<<<dim3(16, 16, 4), 256, 0, stream>>>(Vp, ldv, vbz, Vt, 1024L, 1048576L);
        hipMemsetAsync(csum, 0, 262144, stream);
        // l-pass: exp column-sums, no stores. z=(b,h): zi=h (stride 64), zo=b.
        gemm_k<128,128,64,2,2,1,4,0,1><<<dim3(8, 8, 64), 256, 0, stream>>>(
            Q, ldq, 64L, qbz, Kp, ldk, 64L, kbz,
            (void*)Pb, 1024L, 0L, 0L, 16, 64, 0.125f, nullptr, csum);
        vscale_k<<<2048, 256, 0, stream>>>(Vt, csum);
        attn_pv_k<<<512, 256, 0, stream>>>(Q, ldq, qbz, Kp, ldk, kbz, Vt, part);
    };

    // ---- fused projections (8-phase 256^2): QKV1 + Q2 from y (N=4096) ----
    gemm8_k<16,1,0,1><<<256, 512, 0, stream>>>(
        yb, 1024L, W1cat, 1024L, (void*)QKV, nullptr, 4096L, 1024, 1.0f, nullptr, 0L);
    // K2/V2 from x, N=2048
    gemm8_k<8,1,0,1><<<128, 512, 0, stream>>>(
        xb, 1024L, Wkv2t, 1024L, (void*)KV2, nullptr, 2048L, 1024, 1.0f, nullptr, 0L);

    // ---- MHA1 (self-attn on y): Q/K/V at cols 0/1024/2048 of QKV ----
    run_attention(QKV, 4096L, 4194304L, QKV + 1024, 4096L, 4194304L, QKV + 2048, 4096L, 4194304L);
    gemm_k<128,64,64,2,2,0,0,4,2><<<dim3(2 * 512), 256, 0, stream>>>(
        part, 1024L, 0L, 512L, Wo1t, 1024L, 0L, 512L,
        (void*)gout, 1024L, 0L, 4194304L, 1, 512, 1.0f, nullptr, nullptr);
    addsn_k<2,0><<<4096, 256, 0, stream>>>(gout, nullptr, 4194304L, yf, nullptr, out1);

    // ---- MHA2 (q from y at QKV col 3072; k/v from x in KV2) ----
    run_attention(QKV + 3072, 4096L, 4194304L, KV2, 2048L, 2097152L, KV2 + 1024, 2048L, 2097152L);
    gemm_k<128,64,64,2,2,0,0,4,2><<<dim3(2 * 512), 256, 0, stream>>>(
        part, 1024L, 0L, 512L, Wo2t, 1024L, 0L, 512L,
        (void*)gout, 1024L, 0L, 4194304L, 1, 512, 1.0f, nullptr, nullptr);
    addsn_k<2,0><<<4096, 256, 0, stream>>>(gout, nullptr, 4194304L, out1, nullptr, (float*)d_out);

    // ---- FFN on y (hidden in Pb: 4096x4096 bf16), 8-phase GEMMs ----
    gemm8_k<16,1,1,1><<<256, 512, 0, stream>>>(
        yb, 1024L, Winb, 1024L, (void*)Pb, nullptr, 4096L, 1024, 1.0f, b_in, 0L);
    // FFN-out: split-K 4 (full machine); slabs 0,1 -> gout, slabs 2,3 -> dead QKV region
    gemm8_k<4,4,0,0><<<256, 512, 0, stream>>>(
        Pb, 4096L, Woutb, 4096L, (void*)gout, (void*)QKV, 1024L, 1024, 1.0f, nullptr, 4194304L);
    addsn_k<4,1><<<4096, 256, 0, stream>>>(gout, (const float*)QKV, 4194304L,
                                           (const float*)d_out, b_out, (float*)d_out);
}

// Round 7
// 507.983 us; speedup vs baseline: 1.1970x; 1.0192x over previous
//
#include <hip/hip_runtime.h>

// DecoderStack: B=4,T=1024,D=1024,H=16,DK=DV=64,FF=4096
// Softmax over QUERY axis: l_s = sum_t exp(S) via store-free l-pass (EPI=4),
// 1/l_s folded into V (now fused into the V-transpose), then attn_pv_k
// recomputes E per tile in LDS and multiplies by V — E never touches HBM.
// sub_norm(o) = o - mean - std (ddof=1).
// gemm8_k: R1 schedule (best measured 42.9us) — 256x256, 8 waves, 4 phases,
// vmcnt(10), sched_barrier pins + setprio. Schedule frozen (R3-R5 all lost).
// R7: dispatch consolidation — 33 -> 17 dispatches:
//  * mega_pack_k: all 4 converts + 8 weight packs in ONE dispatch (job table)
//  * SPLITN gemm8: QKV1 + FFN-in merged (same A=yb; B=[W1cat|Winb] contiguous;
//    bx<NT/2 -> QKV, bx>=NT/2 -> Pb with bias+relu)
//  * transpose_scale_k: vscale folded into V-transpose (l-pass runs first)
//  * attn_pv_k RACE FIX: mid-chunk barrier restored (Es columns are written
//    by the sibling wave of the same wm band — NOT wave-local; lgkmcnt alone
//    was a timing-luck race). Keeps K/V double-buffer + counted vmcnt(4).

typedef unsigned short u16;
typedef __bf16 bf16x8 __attribute__((ext_vector_type(8)));
typedef float f32x4 __attribute__((ext_vector_type(4)));

__device__ __forceinline__ u16 f2bf(float f) {
    unsigned int u = __float_as_uint(f);
    u += 0x7fffu + ((u >> 16) & 1u);   // RNE; inputs are finite
    return (u16)(u >> 16);
}
__device__ __forceinline__ float bf2f(u16 b) {
    return __uint_as_float(((unsigned int)b) << 16);
}

typedef __attribute__((address_space(1))) const void* as1cv;
typedef __attribute__((address_space(3))) void* as3v;
__device__ __forceinline__ void gl_lds16(const void* g, void* l) {
    __builtin_amdgcn_global_load_lds((as1cv)g, (as3v)l, 16, 0, 0);
}

// ---------------- fused converts + packs: ONE dispatch ----------------
// Blocks 0..16383: float4->bf16x4 converts, job = id>>12:
//   0: yf->yb  1: xf->xb  2: W_in->Winb  3: W_out->Woutb   (4096 blocks each)
// Blocks 16384..18431: pack_perm jobs, p = (id-16384)>>8, local = &255:
//   p 0-5: per-head packs (grid was dim3(1,16,16)): bx=0, by=local&15, bz=local>>4
//     0: Wq1->W1cat  1: Wk1->W1cat+1M  2: Wv1->W1cat+2M  3: Wq2->W1cat+3M
//     4: Wk2->Wkv2t  5: Wv2->Wkv2t+1M
//   p 6-7: Wo1/Wo2 (grid was dim3(16,16,1)): bx=local&15, by=local>>4, bz=0
__global__ __launch_bounds__(256) void mega_pack_k(
    const float* __restrict__ yf, u16* __restrict__ yb,
    const float* __restrict__ xf, u16* __restrict__ xb,
    const float* __restrict__ W_in, u16* __restrict__ Winb,
    const float* __restrict__ W_out, u16* __restrict__ Woutb,
    const float* __restrict__ Wq1, const float* __restrict__ Wk1,
    const float* __restrict__ Wv1, const float* __restrict__ Wq2,
    u16* __restrict__ W1cat,
    const float* __restrict__ Wk2, const float* __restrict__ Wv2,
    u16* __restrict__ Wkv2t,
    const float* __restrict__ Wo1, u16* __restrict__ Wo1t,
    const float* __restrict__ Wo2, u16* __restrict__ Wo2t)
{
    __shared__ float tile[64][65];
    int id = blockIdx.x;
    if (id < 16384) {
        int j = id >> 12, local = id & 4095;
        const float* in; u16* out;
        switch (j) {
            case 0:  in = yf;    out = yb;    break;
            case 1:  in = xf;    out = xb;    break;
            case 2:  in = W_in;  out = Winb;  break;
            default: in = W_out; out = Woutb; break;
        }
        long i = (long)local * 256 + threadIdx.x;
        float4 v = reinterpret_cast<const float4*>(in)[i];
        ushort4 o;
        o.x = f2bf(v.x); o.y = f2bf(v.y); o.z = f2bf(v.z); o.w = f2bf(v.w);
        reinterpret_cast<ushort4*>(out)[i] = o;
        return;
    }
    int t = id - 16384;
    int pj = t >> 8, local = t & 255;
    const float* in; u16* out;
    int Q, R, bx, by, bz;
    if (pj < 6) {
        switch (pj) {
            case 0:  in = Wq1; out = W1cat;           break;
            case 1:  in = Wk1; out = W1cat + 1048576; break;
            case 2:  in = Wv1; out = W1cat + 2097152; break;
            case 3:  in = Wq2; out = W1cat + 3145728; break;
            case 4:  in = Wk2; out = Wkv2t;           break;
            default: in = Wv2; out = Wkv2t + 1048576; break;
        }
        Q = 1024; R = 64; bx = 0; by = local & 15; bz = local >> 4;
    } else {
        in = (pj == 6) ? Wo1 : Wo2; out = (pj == 6) ? Wo1t : Wo2t;
        Q = 1024; R = 1024; bx = local & 15; by = local >> 4; bz = 0;
    }
    // pack_perm body: out[p][r][q] = in[p][q][r] (fp32->bf16), LDS-tiled
    int r0 = bx * 64, q0 = by * 64;
    int tx = threadIdx.x & 63, ty = threadIdx.x >> 6;
    const float* inp = in + ((long)bz * Q + q0) * R + r0;
    #pragma unroll
    for (int i = 0; i < 64; i += 4)
        tile[ty + i][tx] = inp[(long)(ty + i) * R + tx];
    __syncthreads();
    u16* outp = out + ((long)bz * R + r0) * Q + q0;
    #pragma unroll
    for (int i = 0; i < 64; i += 4)
        outp[(long)(ty + i) * Q + tx] = f2bf(tile[tx][ty + i]);
}

// 64x64 tiled bf16 transpose + per-output-column 1/l scale:
// out[c][r] = in[r][c] / csum[z][c>>6][r]. Used for V (V-cols hv, rows s):
// output row = hv, output col = s; scale per s with head = hv>>6.
__global__ __launch_bounds__(256) void transpose_scale_k(
    const u16* __restrict__ in, long ld_in, long z_in,
    u16* __restrict__ out, long ld_out, long z_out,
    const float* __restrict__ csum) {
    __shared__ u16 tile[64][66];
    int z = blockIdx.z;
    const u16* inz = in + (long)z * z_in;
    u16* outz = out + (long)z * z_out;
    int r0 = blockIdx.y * 64;
    int c0 = blockIdx.x * 64;
    int tx = threadIdx.x & 63, ty = threadIdx.x >> 6;
    #pragma unroll
    for (int i = 0; i < 64; i += 4)
        tile[ty + i][tx] = inz[(long)(r0 + ty + i) * ld_in + c0 + tx];
    __syncthreads();
    #pragma unroll
    for (int i = 0; i < 64; i += 4) {
        int orow = c0 + ty + i;
        float f = bf2f(tile[tx][ty + i]) / csum[(long)z * 16384 + (orow >> 6) * 1024 + r0 + tx];
        outz[(long)orow * ld_out + r0 + tx] = f2bf(f);
    }
}

// ---------------- legacy GEMM (l-pass EPI=4 and small Wo split-K) ----------------
template<int BM, int BN, int BK, int WM, int WN, int OUT_BF16, int EPI, int SWZ, int KS>
__global__ __launch_bounds__(256) void gemm_k(
    const u16* __restrict__ A, long lda, long a_zin, long a_zout,
    const u16* __restrict__ B, long ldb, long b_zin, long b_zout,
    void* __restrict__ Cv, long ldc, long c_zin, long c_zout,
    int zin, int K, float alpha, const float* __restrict__ bias,
    float* __restrict__ csum)
{
    static_assert(BK == 64, "staging assumes BK=64");
    constexpr int WTM = BM / WM;
    constexpr int WTN = BN / WN;
    constexpr int TM = WTM / 16;
    constexpr int TN = WTN / 16;
    __shared__ __align__(16) u16 smem[(BM + BN) * BK];
    u16* As = smem;
    u16* Bs = smem + BM * BK;

    int bx, by, z;
    if (SWZ == 4) {
        int L = blockIdx.x;
        if (KS > 1) { z = L >> 9; L &= 511; } else { z = 0; }
        by = (L & 7) * 4 + ((L >> 3) & 3);
        bx = L >> 5;
    } else {
        bx = blockIdx.x; by = blockIdx.y; z = blockIdx.z;
    }
    int zi = z % zin, zo = z / zin;
    A += (long)zi * a_zin + (long)zo * a_zout;
    B += (long)zi * b_zin + (long)zo * b_zout;
    long coff = (long)zi * c_zin + (long)zo * c_zout;

    int tid = threadIdx.x;
    int lane = tid & 63;
    int wave = tid >> 6;
    int wm = wave / WN, wn = wave % WN;
    long bm0 = (long)by * BM, bn0 = (long)bx * BN;

    f32x4 acc[TM][TN];
    #pragma unroll
    for (int i = 0; i < TM; ++i)
        #pragma unroll
        for (int j = 0; j < TN; ++j) {
            acc[i][j][0] = 0.f; acc[i][j][1] = 0.f;
            acc[i][j][2] = 0.f; acc[i][j][3] = 0.f;
        }

    int r16 = lane & 15;
    int quad = lane >> 4;
    int l8 = lane >> 3;                    // stripe row
    int gsw = ((lane & 7) ^ l8) * 8;       // swizzled global col (elements)

    constexpr int ASTR = BM / 8;
    constexpr int BSTR = BN / 8;

    for (int k0 = 0; k0 < K; k0 += BK) {
        #pragma unroll
        for (int s = wave; s < ASTR; s += 4)
            gl_lds16(&A[(bm0 + s * 8 + l8) * lda + k0 + gsw], &As[s * 512]);
        #pragma unroll
        for (int s = wave; s < BSTR; s += 4)
            gl_lds16(&B[(bn0 + s * 8 + l8) * ldb + k0 + gsw], &Bs[s * 512]);
        __syncthreads();
        #pragma unroll
        for (int kk = 0; kk < BK; kk += 32) {
            int cb = (kk >> 3) + quad;
            bf16x8 av[TM], bv[TN];
            #pragma unroll
            for (int i = 0; i < TM; ++i) {
                int r = wm * WTM + i * 16 + r16;
                av[i] = *reinterpret_cast<const bf16x8*>(&As[r * 64 + ((cb ^ (r & 7)) * 8)]);
            }
            #pragma unroll
            for (int j = 0; j < TN; ++j) {
                int r = wn * WTN + j * 16 + r16;
                bv[j] = *reinterpret_cast<const bf16x8*>(&Bs[r * 64 + ((cb ^ (r & 7)) * 8)]);
            }
            #pragma unroll
            for (int i = 0; i < TM; ++i)
                #pragma unroll
                for (int j = 0; j < TN; ++j)
                    acc[i][j] = __builtin_amdgcn_mfma_f32_16x16x32_bf16(av[i], bv[j], acc[i][j], 0, 0, 0);
        }
        __syncthreads();
    }

    int rb = quad * 4;

    if (EPI == 4) {
        // exp + column sums only; no C store. csum layout [z][1024].
        float csl[TN];
        #pragma unroll
        for (int j = 0; j < TN; ++j) csl[j] = 0.f;
        #pragma unroll
        for (int i = 0; i < TM; ++i)
            #pragma unroll
            for (int j = 0; j < TN; ++j)
                #pragma unroll
                for (int r = 0; r < 4; ++r)
                    csl[j] += __expf(acc[i][j][r] * alpha);
        #pragma unroll
        for (int j = 0; j < TN; ++j) {
            float cs = csl[j];
            cs += __shfl_xor(cs, 16, 64);
            cs += __shfl_xor(cs, 32, 64);
            if (quad == 0) {
                long col = bn0 + wn * WTN + j * 16 + r16;
                atomicAdd(&csum[((long)zo * zin + zi) * 1024 + col], cs);
            }
        }
        return;
    }

    // ---- LDS-staged store epilogue ----
    constexpr int EB = OUT_BF16 ? 2 : 4;
    constexpr int CH = 16 / EB;
    constexpr int STRIDE = BN + CH;
    constexpr int LDSB = (BM + BN) * BK * 2;
    constexpr int EPASS = (BM * STRIDE * EB > LDSB) ? 2 : 1;
    constexpr int RPP = BM / EPASS;
    static_assert(RPP * STRIDE * EB <= LDSB, "epilogue tile overflows LDS");
    static_assert(EPASS == 1 || (WM == 2 && WTM == RPP), "pass/wave row alignment");
    constexpr int CPR = BN / CH;
    constexpr int NCH = RPP * CPR / 256;
    static_assert(RPP * CPR % 256 == 0, "store mapping");

    float* Ef = reinterpret_cast<float*>(smem);
    char* Cb = reinterpret_cast<char*>(Cv);

    for (int pass = 0; pass < EPASS; ++pass) {
        int p0 = pass * RPP;
        __syncthreads();
        #pragma unroll
        for (int i = 0; i < TM; ++i) {
            #pragma unroll
            for (int j = 0; j < TN; ++j) {
                int lcol = wn * WTN + j * 16 + r16;
                float bsv = (EPI == 1 || EPI == 2) ? bias[bn0 + lcol] : 0.f;
                #pragma unroll
                for (int r = 0; r < 4; ++r) {
                    int lrow = wm * WTM + i * 16 + rb + r;
                    if ((unsigned)(lrow - p0) < (unsigned)RPP) {
                        float v = acc[i][j][r] * alpha;
                        if (EPI == 1) { v += bsv; v = v > 0.f ? v : 0.f; }
                        else if (EPI == 2) { v += bsv; }
                        if (OUT_BF16) smem[(lrow - p0) * STRIDE + lcol] = f2bf(v);
                        else          Ef[(lrow - p0) * STRIDE + lcol] = v;
                    }
                }
            }
        }
        __syncthreads();
        #pragma unroll
        for (int c = 0; c < NCH; ++c) {
            int cid = tid + c * 256;
            int row = cid / CPR, ch = cid - row * CPR;
            int4 v = *reinterpret_cast<const int4*>(
                reinterpret_cast<const char*>(smem) + (row * STRIDE + ch * CH) * EB);
            long gidx = coff + (bm0 + p0 + row) * ldc + bn0 + ch * CH;
            *reinterpret_cast<int4*>(Cb + gidx * EB) = v;
        }
    }
}

// ---------------- 8-phase 256x256 GEMM (R1 schedule, frozen) ----------------
// Per K-tile t, 4 phases = (ih,jh) quadrants x K=64, 2 raw barriers each:
//   ph1: read av(ih0),bv(jh0) | stage (t+1).A-half1 | vmcnt(10)
//   ph2: read bv(jh1)         | stage (t+2).A-half0 | vmcnt(10)
//   ph3: read av(ih1)         | stage (t+2).B-half0 |
//   ph4:                      | stage (t+2).B-half1 | vmcnt(10)
// 2 loads/thread per half-tile; 5 half-tiles (10 loads) stay in flight.
// Tail tiles T-2/T-1 use derived counts 10/8/4 and 2/0.
// SPLITN=1: first NT/2 bx-tiles -> Cv (no epi); second NT/2 -> Cv2 with
// bias+relu, column base rebased by NT/2*256 (QKV1 + FFN-in fused dispatch).

__device__ __forceinline__ void bar_raw() {
    asm volatile("" ::: "memory");
    __builtin_amdgcn_s_barrier();
    asm volatile("" ::: "memory");
}

template<int N> __device__ __forceinline__ void vmw() {
    if constexpr (N == 10) asm volatile("s_waitcnt vmcnt(10)" ::: "memory");
    else if constexpr (N == 8) asm volatile("s_waitcnt vmcnt(8)" ::: "memory");
    else if constexpr (N == 4) asm volatile("s_waitcnt vmcnt(4)" ::: "memory");
    else if constexpr (N == 2) asm volatile("s_waitcnt vmcnt(2)" ::: "memory");
    else if constexpr (N == 0) asm volatile("s_waitcnt vmcnt(0)" ::: "memory");
}

// stage one half-tile (16 stripes of 8 rows x 64 cols) = 2 gl_lds per thread
__device__ __forceinline__ void stage_half(const u16* __restrict__ base, long ld, int kt,
                                           u16* __restrict__ lds, int half, int wave) {
    const u16* src = base + (long)kt * 64;
    #pragma unroll
    for (int u = 0; u < 2; ++u) {
        int s = half * 16 + u * 8 + wave;
        gl_lds16(src + (long)(s * 8) * ld, lds + s * 512);
    }
}

template<int IH>
__device__ __forceinline__ void read_a8(bf16x8 (&av)[4][2], const u16* __restrict__ As,
                                        int wm, int r16, int quad) {
    #pragma unroll
    for (int ii = 0; ii < 4; ++ii) {
        int r = IH * 128 + wm * 64 + ii * 16 + r16;
        #pragma unroll
        for (int kx = 0; kx < 2; ++kx)
            av[ii][kx] = *reinterpret_cast<const bf16x8*>(&As[r * 64 + (((kx * 4 + quad) ^ (r & 7)) * 8)]);
    }
}

template<int JH>
__device__ __forceinline__ void read_b8(bf16x8 (&bv)[2][2], const u16* __restrict__ Bs,
                                        int wn, int r16, int quad) {
    #pragma unroll
    for (int j = 0; j < 2; ++j) {
        int r = JH * 128 + wn * 32 + j * 16 + r16;
        #pragma unroll
        for (int kx = 0; kx < 2; ++kx)
            bv[j][kx] = *reinterpret_cast<const bf16x8*>(&Bs[r * 64 + (((kx * 4 + quad) ^ (r & 7)) * 8)]);
    }
}

template<int IH, int JH>
__device__ __forceinline__ void mfma_q(f32x4 (&acc)[2][4][2][2],
                                       const bf16x8 (&av)[4][2], const bf16x8 (&bv)[2][2]) {
    #pragma unroll
    for (int kx = 0; kx < 2; ++kx)
        #pragma unroll
        for (int ii = 0; ii < 4; ++ii)
            #pragma unroll
            for (int j = 0; j < 2; ++j)
                acc[IH][ii][JH][j] = __builtin_amdgcn_mfma_f32_16x16x32_bf16(
                    av[ii][kx], bv[j][kx], acc[IH][ii][JH][j], 0, 0, 0);
}

// MODE 0: steady; 1: t=T-2 (only (t+1).A1 staged); 2: t=T-1 (no staging)
template<int MODE>
__device__ __forceinline__ void tile_iter(
    int t, f32x4 (&acc)[2][4][2][2], bf16x8 (&av)[4][2], bf16x8 (&bvh)[2][2][2],
    u16* __restrict__ smem, const u16* __restrict__ Ab, long lda,
    const u16* __restrict__ Bb, long ldb, int wave, int wm, int wn, int r16, int quad)
{
    u16* As0 = smem + (t & 1) * 32768;          // buf for tile t (also target of t+2 stages)
    u16* Bs0 = As0 + 16384;
    u16* As1 = smem + ((t + 1) & 1) * 32768;    // buf for tile t+1
    // ---- ph1 (ih0,jh0)
    read_a8<0>(av, As0, wm, r16, quad);
    read_b8<0>(bvh[0], Bs0, wn, r16, quad);
    if (MODE < 2) stage_half(Ab, lda, t + 1, As1, 1, wave);
    vmw<MODE == 0 ? 10 : (MODE == 1 ? 10 : 2)>();
    bar_raw(); __builtin_amdgcn_sched_barrier(0);
    __builtin_amdgcn_s_setprio(1);
    mfma_q<0, 0>(acc, av, bvh[0]);
    __builtin_amdgcn_s_setprio(0);
    __builtin_amdgcn_sched_barrier(0);
    bar_raw();
    // ---- ph2 (ih0,jh1)
    read_b8<1>(bvh[1], Bs0, wn, r16, quad);
    if (MODE == 0) stage_half(Ab, lda, t + 2, As0, 0, wave);
    vmw<MODE == 0 ? 10 : (MODE == 1 ? 8 : 0)>();
    bar_raw(); __builtin_amdgcn_sched_barrier(0);
    __builtin_amdgcn_s_setprio(1);
    mfma_q<0, 1>(acc, av, bvh[1]);
    __builtin_amdgcn_s_setprio(0);
    __builtin_amdgcn_sched_barrier(0);
    bar_raw();
    // ---- ph3 (ih1,jh0)
    read_a8<1>(av, As0, wm, r16, quad);
    if (MODE == 0) stage_half(Bb, ldb, t + 2, Bs0, 0, wave);
    bar_raw(); __builtin_amdgcn_sched_barrier(0);
    __builtin_amdgcn_s_setprio(1);
    mfma_q<1, 0>(acc, av, bvh[0]);
    __builtin_amdgcn_s_setprio(0);
    __builtin_amdgcn_sched_barrier(0);
    bar_raw();
    // ---- ph4 (ih1,jh1)
    if (MODE == 0) stage_half(Bb, ldb, t + 2, Bs0, 1, wave);
    if (MODE < 2) vmw<MODE == 0 ? 10 : 4>();
    bar_raw(); __builtin_amdgcn_sched_barrier(0);
    __builtin_amdgcn_s_setprio(1);
    mfma_q<1, 1>(acc, av, bvh[1]);
    __builtin_amdgcn_s_setprio(0);
    __builtin_amdgcn_sched_barrier(0);
    bar_raw();
}

// grid = 16*NT*KS blocks of 512. EPI: 0 none, 1 bias+relu. KS>1: z picks K-chunk,
// output slab z: z<2 -> Cv + (z&1)*czs, z>=2 -> Cv2 + (z&1)*czs (fp32).
// SPLITN=1 (KS must be 1): bx>=NT/2 -> Cv2, bias+relu, columns rebased.
template<int NT, int KS, int EPI, int OUT_BF16, int SPLITN>
__global__ __launch_bounds__(512, 2) void gemm8_k(
    const u16* __restrict__ A, long lda,
    const u16* __restrict__ B, long ldb,
    void* __restrict__ Cv, void* __restrict__ Cv2, long ldc,
    int K, float alpha, const float* __restrict__ bias, long czs)
{
    __shared__ __align__(16) u16 smem[65536];   // 128 KiB

    int L = blockIdx.x;
    int z = 0;
    if (KS > 1) { z = L / (16 * NT); L -= z * 16 * NT; }
    int by = (L & 7) * 2 + ((L >> 3) & 1);      // XCD-contiguous M-rows
    int bx = L >> 4;
    if (KS > 1) { A += (long)z * K; B += (long)z * K; }

    int tid = threadIdx.x;
    int lane = tid & 63, wave = tid >> 6;
    int wm = wave >> 2, wn = wave & 3;
    int r16 = lane & 15, quad = lane >> 4, l8 = lane >> 3;
    int gsw = ((lane & 7) ^ l8) * 8;
    long bm0 = (long)by * 256, bn0 = (long)bx * 256;
    const u16* Ab = A + (bm0 + l8) * lda + gsw;
    const u16* Bb = B + (bn0 + l8) * ldb + gsw;

    f32x4 acc[2][4][2][2];
    #pragma unroll
    for (int a0 = 0; a0 < 2; ++a0)
        #pragma unroll
        for (int a1 = 0; a1 < 4; ++a1)
            #pragma unroll
            for (int a2 = 0; a2 < 2; ++a2)
                #pragma unroll
                for (int a3 = 0; a3 < 2; ++a3) {
                    acc[a0][a1][a2][a3][0] = 0.f; acc[a0][a1][a2][a3][1] = 0.f;
                    acc[a0][a1][a2][a3][2] = 0.f; acc[a0][a1][a2][a3][3] = 0.f;
                }
    bf16x8 av[4][2];
    bf16x8 bvh[2][2][2];

    int T = K >> 6;   // >= 3

    // prologue issue stream: [0.A0, 0.B0, 0.B1, 0.A1, 1.A0, 1.B0, 1.B1]
    stage_half(Ab, lda, 0, smem,         0, wave);
    stage_half(Bb, ldb, 0, smem + 16384, 0, wave);
    stage_half(Bb, ldb, 0, smem + 16384, 1, wave);
    stage_half(Ab, lda, 0, smem,         1, wave);
    stage_half(Ab, lda, 1, smem + 32768, 0, wave);
    stage_half(Bb, ldb, 1, smem + 49152, 0, wave);
    stage_half(Bb, ldb, 1, smem + 49152, 1, wave);
    vmw<10>();          // 14 issued -> oldest 4 (0.A0,0.B0) landed
    bar_raw();

    for (int t = 0; t < T - 2; ++t)
        tile_iter<0>(t, acc, av, bvh, smem, Ab, lda, Bb, ldb, wave, wm, wn, r16, quad);
    tile_iter<1>(T - 2, acc, av, bvh, smem, Ab, lda, Bb, ldb, wave, wm, wn, r16, quad);
    tile_iter<2>(T - 1, acc, av, bvh, smem, Ab, lda, Bb, ldb, wave, wm, wn, r16, quad);

    // ---- epilogue: stage to LDS (row-XOR-swizzled), coalesced int4 stores
    constexpr int EB = OUT_BF16 ? 2 : 4;
    constexpr int EPASS = OUT_BF16 ? 1 : 2;   // f32 = 2 passes of 128 rows (ih=pass)
    bool sec = SPLITN && (bx >= NT / 2);
    char* Cb;
    long bnc = bn0;
    if (SPLITN) {
        Cb = reinterpret_cast<char*>(sec ? Cv2 : Cv);
        if (sec) bnc = bn0 - (long)(NT / 2) * 256;
    } else {
        Cb = reinterpret_cast<char*>((KS > 1 && z >= 2) ? Cv2 : Cv);
        if (KS > 1) Cb += (long)(z & 1) * czs * EB;
    }
    bool do_bias = (EPI == 1) || sec;
    float bsv[2][2];
    if (do_bias) {
        #pragma unroll
        for (int jh = 0; jh < 2; ++jh)
            #pragma unroll
            for (int j = 0; j < 2; ++j)
                bsv[jh][j] = bias[bnc + jh * 128 + wn * 32 + j * 16 + r16];
    }
    u16* sm16 = smem;
    float* smf = reinterpret_cast<float*>(smem);
    #pragma unroll
    for (int pass = 0; pass < EPASS; ++pass) {
        bar_raw();
        #pragma unroll
        for (int ih = 0; ih < 2; ++ih) {
            if (EPASS == 2 && ih != pass) continue;
            #pragma unroll
            for (int ii = 0; ii < 4; ++ii)
                #pragma unroll
                for (int jh = 0; jh < 2; ++jh)
                    #pragma unroll
                    for (int j = 0; j < 2; ++j)
                        #pragma unroll
                        for (int r = 0; r < 4; ++r) {
                            int lrow = (EPASS == 2 ? 0 : ih * 128) + wm * 64 + ii * 16 + quad * 4 + r;
                            int lcol = jh * 128 + wn * 32 + j * 16 + r16;
                            float v = acc[ih][ii][jh][j][r] * alpha;
                            if (do_bias) { v += bsv[jh][j]; v = v > 0.f ? v : 0.f; }
                            int scol = lcol ^ ((lrow & 7) * 8);
                            if (OUT_BF16) sm16[lrow * 256 + scol] = f2bf(v);
                            else          smf[lrow * 256 + scol] = v;
                        }
        }
        bar_raw();
        constexpr int CH = 16 / EB;
        constexpr int CPR = 256 / CH;
        constexpr int NCH = (OUT_BF16 ? 256 : 128) * CPR / 512;
        #pragma unroll
        for (int c = 0; c < NCH; ++c) {
            int cid = tid + c * 512;
            int row = cid / CPR, ch = cid - row * CPR;
            int col = (ch * CH) ^ ((row & 7) * 8);
            int4 v = *reinterpret_cast<const int4*>(
                reinterpret_cast<const char*>(smem) + ((long)row * 256 + col) * EB);
            long grow = bm0 + pass * 128 + row;
            *reinterpret_cast<int4*>(Cb + (grow * ldc + bnc + ch * CH) * EB) = v;
        }
    }
}

// ---------------- fused attention PV: recompute E per tile, x scaled V ----------------
// Grid 512 blocks: L -> xcd=L&7: head=(L&7)*2+((L>>3)&1), tb=(L>>4)&7, b=L>>7.
// Per block: out[128 t][64 v] = sum_s exp(0.125*Q K^T) * Vt_scaled.
// K/V double-buffered; stage(c+1) issued BEFORE chunk c compute; counted
// vmcnt(4) + barrier. Mid-chunk barrier RESTORED (R7): Es rows in a wm band
// are written by BOTH waves of that band (each wn-half), and PV reads full
// rows — cross-wave dependency needs lgkmcnt(0) + s_barrier, not lgkmcnt alone.
__global__ __launch_bounds__(256) void attn_pv_k(
    const u16* __restrict__ Qg, long ldq, long qbz,
    const u16* __restrict__ Kg, long ldk, long kbz,
    const u16* __restrict__ Vg,            // [b][1024 hv][1024 s], pre-scaled by 1/l
    u16* __restrict__ outg)                // part: [b][1024 t][1024 (h*64+v)]
{
    __shared__ __align__(16) u16 Qs[128 * 64];
    __shared__ __align__(16) u16 Ks[2][64 * 64];
    __shared__ __align__(16) u16 Vs[2][64 * 64];
    __shared__ __align__(16) u16 Es[128 * 64];

    int L = blockIdx.x;
    int h  = (L & 7) * 2 + ((L >> 3) & 1);
    int tb = (L >> 4) & 7;
    int b  = L >> 7;

    const u16* Q  = Qg + (long)b * qbz + h * 64;
    const u16* Kp = Kg + (long)b * kbz + h * 64;
    const u16* Vp = Vg + (long)b * 1048576 + (long)h * 65536;
    u16* outp = outg + (long)b * 1048576 + (long)tb * 131072 + h * 64;

    int tid = threadIdx.x, lane = tid & 63, wave = tid >> 6;
    int wm = wave >> 1, wn = wave & 1;
    int r16 = lane & 15, quad = lane >> 4, l8 = lane >> 3;
    int gsw = ((lane & 7) ^ l8) * 8;
    long t0 = (long)tb * 128;

    // prologue: Q (4 loads/thread) + K/V chunk 0 (4 loads/thread)
    #pragma unroll
    for (int s = wave; s < 16; s += 4)
        gl_lds16(&Q[(t0 + s * 8 + l8) * ldq + gsw], &Qs[s * 512]);
    #pragma unroll
    for (int s = wave; s < 8; s += 4) {
        gl_lds16(&Kp[(long)(s * 8 + l8) * ldk + gsw], &Ks[0][s * 512]);
        gl_lds16(&Vp[(long)(s * 8 + l8) * 1024 + gsw], &Vs[0][s * 512]);
    }

    f32x4 acc[4][2];
    #pragma unroll
    for (int i = 0; i < 4; ++i)
        #pragma unroll
        for (int j = 0; j < 2; ++j) {
            acc[i][j][0] = 0.f; acc[i][j][1] = 0.f;
            acc[i][j][2] = 0.f; acc[i][j][3] = 0.f;
        }

    for (int sc = 0; sc < 16; ++sc) {
        const u16* Ksc = Ks[sc & 1];
        const u16* Vsc = Vs[sc & 1];
        // issue next chunk's staging into the other buffer (last read in
        // chunk sc-1, protected by that chunk's trailing barrier)
        if (sc < 15) {
            int nc = sc + 1;
            u16* Kn = Ks[nc & 1];
            u16* Vn = Vs[nc & 1];
            #pragma unroll
            for (int s = wave; s < 8; s += 4) {
                gl_lds16(&Kp[(long)(nc * 64 + s * 8 + l8) * ldk + gsw], &Kn[s * 512]);
                gl_lds16(&Vp[(long)(s * 8 + l8) * 1024 + nc * 64 + gsw], &Vn[s * 512]);
            }
            asm volatile("s_waitcnt vmcnt(4)" ::: "memory");   // chunk sc (and Q) landed
        } else {
            asm volatile("s_waitcnt vmcnt(0)" ::: "memory");   // last chunk landed
        }
        bar_raw();                            // all waves' chunk-sc loads visible

        // E-chunk = Q x K^T (128x64, contraction 64)
        f32x4 e[4][2];
        #pragma unroll
        for (int i = 0; i < 4; ++i)
            #pragma unroll
            for (int j = 0; j < 2; ++j) {
                e[i][j][0] = 0.f; e[i][j][1] = 0.f;
                e[i][j][2] = 0.f; e[i][j][3] = 0.f;
            }
        #pragma unroll
        for (int kk = 0; kk < 64; kk += 32) {
            int cb = (kk >> 3) + quad;
            bf16x8 av[4], bv[2];
            #pragma unroll
            for (int i = 0; i < 4; ++i) {
                int r = wm * 64 + i * 16 + r16;
                av[i] = *reinterpret_cast<const bf16x8*>(&Qs[r * 64 + ((cb ^ (r & 7)) * 8)]);
            }
            #pragma unroll
            for (int j = 0; j < 2; ++j) {
                int r = wn * 32 + j * 16 + r16;
                bv[j] = *reinterpret_cast<const bf16x8*>(&Ksc[r * 64 + ((cb ^ (r & 7)) * 8)]);
            }
            #pragma unroll
            for (int i = 0; i < 4; ++i)
                #pragma unroll
                for (int j = 0; j < 2; ++j)
                    e[i][j] = __builtin_amdgcn_mfma_f32_16x16x32_bf16(av[i], bv[j], e[i][j], 0, 0, 0);
        }
        // exp + write to Es (C-frag: row=quad*4+r, col=r16; XOR-swizzled rows)
        #pragma unroll
        for (int i = 0; i < 4; ++i)
            #pragma unroll
            for (int j = 0; j < 2; ++j) {
                int lcol = wn * 32 + j * 16 + r16;
                #pragma unroll
                for (int r = 0; r < 4; ++r) {
                    int lrow = wm * 64 + i * 16 + quad * 4 + r;
                    float v = __expf(e[i][j][r] * 0.125f);
                    Es[lrow * 64 + (((lcol >> 3) ^ (lrow & 7)) * 8) + (lcol & 7)] = f2bf(v);
                }
            }
        // Es rows are filled by BOTH waves of the wm band (one per wn half);
        // PV reads full rows -> cross-wave: drain LDS writes, then barrier.
        asm volatile("s_waitcnt lgkmcnt(0)" ::: "memory");
        bar_raw();

        // acc += E-chunk x Vs^T (contraction over s-chunk)
        #pragma unroll
        for (int kk = 0; kk < 64; kk += 32) {
            int cb = (kk >> 3) + quad;
            bf16x8 av[4], bv[2];
            #pragma unroll
            for (int i = 0; i < 4; ++i) {
                int r = wm * 64 + i * 16 + r16;
                av[i] = *reinterpret_cast<const bf16x8*>(&Es[r * 64 + ((cb ^ (r & 7)) * 8)]);
            }
            #pragma unroll
            for (int j = 0; j < 2; ++j) {
                int r = wn * 32 + j * 16 + r16;
                bv[j] = *reinterpret_cast<const bf16x8*>(&Vsc[r * 64 + ((cb ^ (r & 7)) * 8)]);
            }
            #pragma unroll
            for (int i = 0; i < 4; ++i)
                #pragma unroll
                for (int j = 0; j < 2; ++j)
                    acc[i][j] = __builtin_amdgcn_mfma_f32_16x16x32_bf16(av[i], bv[j], acc[i][j], 0, 0, 0);
        }
        bar_raw();                 // all waves done reading buf[sc&1] K/V + Es
    }

    #pragma unroll
    for (int i = 0; i < 4; ++i)
        #pragma unroll
        for (int j = 0; j < 2; ++j) {
            int lcol = wn * 32 + j * 16 + r16;
            #pragma unroll
            for (int r = 0; r < 4; ++r) {
                int lrow = wm * 64 + i * 16 + quad * 4 + r;
                outp[(long)lrow * 1024 + lcol] = f2bf(acc[i][j][r]);
            }
        }
}

// ---------------- out = (sum of NP partial slabs + resid [+bias]) - mean - std ----------------
// Slabs 0,1 from parts; slabs 2,3 (NP=4) from parts2.
template<int NP, int BIAS>
__global__ __launch_bounds__(256) void addsn_k(const float* __restrict__ parts,
                                               const float* __restrict__ parts2,
                                               long pstride,
                                               const float* __restrict__ resid,
                                               const float* __restrict__ bias,
                                               float* __restrict__ out) {
    __shared__ float sm[8];
    long row = blockIdx.x;
    int tid = threadIdx.x;
    float4 x = reinterpret_cast<const float4*>(resid + row * 1024)[tid];
    #pragma unroll
    for (int p = 0; p < NP; ++p) {
        const float* src = (p < 2) ? (parts + p * pstride) : (parts2 + (p - 2) * pstride);
        float4 a = reinterpret_cast<const float4*>(src + row * 1024)[tid];
        x.x += a.x; x.y += a.y; x.z += a.z; x.w += a.w;
    }
    if (BIAS) {
        float4 bb = reinterpret_cast<const float4*>(bias)[tid];
        x.x += bb.x; x.y += bb.y; x.z += bb.z; x.w += bb.w;
    }
    float s = x.x + x.y + x.z + x.w;
    for (int o = 32; o > 0; o >>= 1) s += __shfl_down(s, o, 64);
    int lane = tid & 63, w = tid >> 6;
    if (lane == 0) sm[w] = s;
    __syncthreads();
    float mean = (sm[0] + sm[1] + sm[2] + sm[3]) * (1.f / 1024.f);
    float d0 = x.x - mean, d1 = x.y - mean, d2 = x.z - mean, d3 = x.w - mean;
    float q = d0 * d0 + d1 * d1 + d2 * d2 + d3 * d3;
    for (int o = 32; o > 0; o >>= 1) q += __shfl_down(q, o, 64);
    if (lane == 0) sm[w + 4] = q;
    __syncthreads();
    float sd = sqrtf((sm[4] + sm[5] + sm[6] + sm[7]) * (1.f / 1023.f));
    float4 ov;
    ov.x = d0 - sd; ov.y = d1 - sd; ov.z = d2 - sd; ov.w = d3 - sd;
    reinterpret_cast<float4*>(out + row * 1024)[tid] = ov;
}

// ---------------- launcher ----------------

extern "C" void kernel_launch(void* const* d_in, const int* in_sizes, int n_in,
                              void* d_out, int out_size, void* d_ws, size_t ws_size,
                              hipStream_t stream) {
    (void)in_sizes; (void)n_in; (void)out_size; (void)ws_size;
    const float* xf   = (const float*)d_in[0];
    const float* yf   = (const float*)d_in[1];
    const float* Wq1  = (const float*)d_in[2];
    const float* Wk1  = (const float*)d_in[3];
    const float* Wv1  = (const float*)d_in[4];
    const float* Wo1  = (const float*)d_in[5];
    const float* Wq2  = (const float*)d_in[6];
    const float* Wk2  = (const float*)d_in[7];
    const float* Wv2  = (const float*)d_in[8];
    const float* Wo2  = (const float*)d_in[9];
    const float* W_in = (const float*)d_in[10];
    const float* b_in = (const float*)d_in[11];
    const float* W_out= (const float*)d_in[12];
    const float* b_out= (const float*)d_in[13];

    // workspace layout (~192 MB). NOTE: W1cat and Winb are ADJACENT so the
    // SPLITN gemm8 sees one contiguous B of 8192 x 1024 ([W1cat | Winb]).
    char* p = (char*)d_ws;
    auto alloc = [&](size_t bytes) { char* r = p; p += bytes; return r; };
    u16*   yb    = (u16*)alloc(8388608);    // y bf16 (4096x1024)
    u16*   xb    = (u16*)alloc(8388608);    // x bf16
    u16*   W1cat = (u16*)alloc(8388608);    // [Wq1|Wk1|Wv1|Wq2]^T-packed (4096 x 1024)
    u16*   Winb  = (u16*)alloc(8388608);    // W_in (4096 x 1024), contiguous after W1cat
    u16*   Wkv2t = (u16*)alloc(4194304);    // [Wk2|Wv2] (2048 x 1024)
    u16*   Wo1t  = (u16*)alloc(2097152);
    u16*   Wo2t  = (u16*)alloc(2097152);
    u16*   Woutb = (u16*)alloc(8388608);    // W_out (1024 x 4096) = Bt layout
    u16*   QKV   = (u16*)alloc(33554432);   // (4096 x 4096): [Q1|K1|V1|Q2] per (b,t);
                                            // dead after MHA2 -> reused as FFN-out fp32 slabs 2,3
    u16*   KV2   = (u16*)alloc(16777216);   // (4096 x 2048): [K2|V2]
    u16*   Vt    = (u16*)alloc(8388608);    // per b: (1024 hv x 1024 s), scaled by 1/l at transpose
    u16*   Pb    = (u16*)alloc(33554432);   // FFN hidden (4096x4096 bf16)
    float* csum  = (float*)alloc(262144);   // column sums l [4][16][1024]
    u16*   part  = (u16*)alloc(8388608);    // attn partial (4096 x 1024) bf16
    float* gout  = (float*)alloc(33554432); // fp32 split-K partials, 2 slabs of 16 MB
    float* out1  = (float*)alloc(16777216);

    // ---- ALL converts + weight packs in one dispatch ----
    mega_pack_k<<<18432, 256, 0, stream>>>(
        yf, yb, xf, xb, W_in, Winb, W_out, Woutb,
        Wq1, Wk1, Wv1, Wq2, W1cat, Wk2, Wv2, Wkv2t,
        Wo1, Wo1t, Wo2, Wo2t);

    // attention core: all 4 batches per dispatch. Order: l-pass first, then
    // transpose+scale fused (csum complete by stream order), then PV.
    auto run_attention = [&](const u16* Q, long ldq, long qbz,
                             const u16* Kp, long ldk, long kbz,
                             const u16* Vp, long ldv, long vbz) {
        hipMemsetAsync(csum, 0, 262144, stream);
        // l-pass: exp column-sums, no stores. z=(b,h): zi=h (stride 64), zo=b.
        gemm_k<128,128,64,2,2,1,4,0,1><<<dim3(8, 8, 64), 256, 0, stream>>>(
            Q, ldq, 64L, qbz, Kp, ldk, 64L, kbz,
            (void*)Pb, 1024L, 0L, 0L, 16, 64, 0.125f, nullptr, csum);
        transpose_scale_k<<<dim3(16, 16, 4), 256, 0, stream>>>(
            Vp, ldv, vbz, Vt, 1024L, 1048576L, csum);
        attn_pv_k<<<512, 256, 0, stream>>>(Q, ldq, qbz, Kp, ldk, kbz, Vt, part);
    };

    // ---- fused projections: QKV1+Q2 AND FFN-in in ONE dispatch (A=yb both).
    // B = [W1cat | Winb] (8192 x 1024). bx<16 -> QKV (no epi); bx>=16 -> Pb
    // (bias b_in + relu). Both outputs 4096-wide bf16.
    gemm8_k<32,1,0,1,1><<<512, 512, 0, stream>>>(
        yb, 1024L, W1cat, 1024L, (void*)QKV, (void*)Pb, 4096L, 1024, 1.0f, b_in, 0L);
    // K2/V2 from x, N=2048
    gemm8_k<8,1,0,1,0><<<128, 512, 0, stream>>>(
        xb, 1024L, Wkv2t, 1024L, (void*)KV2, nullptr, 2048L, 1024, 1.0f, nullptr, 0L);

    // ---- MHA1 (self-attn on y): Q/K/V at cols 0/1024/2048 of QKV ----
    run_attention(QKV, 4096L, 4194304L, QKV + 1024, 4096L, 4194304L, QKV + 2048, 4096L, 4194304L);
    gemm_k<128,64,64,2,2,0,0,4,2><<<dim3(2 * 512), 256, 0, stream>>>(
        part, 1024L, 0L, 512L, Wo1t, 1024L, 0L, 512L,
        (void*)gout, 1024L, 0L, 4194304L, 1, 512, 1.0f, nullptr, nullptr);
    addsn_k<2,0><<<4096, 256, 0, stream>>>(gout, nullptr, 4194304L, yf, nullptr, out1);

    // ---- MHA2 (q from y at QKV col 3072; k/v from x in KV2) ----
    run_attention(QKV + 3072, 4096L, 4194304L, KV2, 2048L, 2097152L, KV2 + 1024, 2048L, 2097152L);
    gemm_k<128,64,64,2,2,0,0,4,2><<<dim3(2 * 512), 256, 0, stream>>>(
        part, 1024L, 0L, 512L, Wo2t, 1024L, 0L, 512L,
        (void*)gout, 1024L, 0L, 4194304L, 1, 512, 1.0f, nullptr, nullptr);
    addsn_k<2,0><<<4096, 256, 0, stream>>>(gout, nullptr, 4194304L, out1, nullptr, (float*)d_out);

    // ---- FFN-out (hidden Pb computed up front): split-K 4 (full machine);
    // slabs 0,1 -> gout, slabs 2,3 -> dead QKV region
    gemm8_k<4,4,0,0,0><<<256, 512, 0, stream>>>(
        Pb, 4096L, Woutb, 4096L, (void*)gout, (void*)QKV, 1024L, 1024, 1.0f, nullptr, 4194304L);
    addsn_k<4,1><<<4096, 256, 0, stream>>>(gout, (const float*)QKV, 4194304L,
                                           (const float*)d_out, b_out, (float*)d_out);
}

// Round 8
// 481.719 us; speedup vs baseline: 1.2623x; 1.0545x over previous
//
#include <hip/hip_runtime.h>

// DecoderStack: B=4,T=1024,D=1024,H=16,DK=DV=64,FF=4096
// Softmax over QUERY axis: l_s = sum_t exp(S) via store-free l-pass (EPI=4),
// 1/l_s folded into the V-transpose, then attn_pv_k recomputes E per tile in
// LDS and multiplies by V — E never touches HBM.
// sub_norm(o) = o - mean - std (ddof=1).
// gemm8_k: R1 schedule (best measured 42.9us/tile-wave), frozen.
// R8: pipeline-wide dispatch consolidation, 19 -> 11 dispatches:
//   1 mega_pack (+csum zero)      7 Wo_both   (full-K, both MHAs, 1 dispatch)
//   2 SPLITN gemm8 (QKV+FFN-in)   8 FFN-out   (split-K4 -> QKV + yb-region)
//   3 KV2 gemm8                   9 addsn1 (NP=1)
//   4 lpass_both  (MRG z>=64)    10 addsn2 (NP=1)
//   5 tscale_both (z 0-7)        11 addsn3 (NP=4)
//   6 attnpv_both (L>=512)
// Buffer lifetimes (aliases): Vt[2] = [yb|xb] (dead after KV2 gemm);
// csum[2] = gout head (dead before Wo writes gout); out1 = part (dead after
// Wo); FFN-out slabs 2,3 = [yb..Winb] 32MB (dead after SPLITN/KV2; Vt dead
// after attnpv). Compute cores byte-identical to R7.

typedef unsigned short u16;
typedef __bf16 bf16x8 __attribute__((ext_vector_type(8)));
typedef float f32x4 __attribute__((ext_vector_type(4)));

__device__ __forceinline__ u16 f2bf(float f) {
    unsigned int u = __float_as_uint(f);
    u += 0x7fffu + ((u >> 16) & 1u);   // RNE; inputs are finite
    return (u16)(u >> 16);
}
__device__ __forceinline__ float bf2f(u16 b) {
    return __uint_as_float(((unsigned int)b) << 16);
}

typedef __attribute__((address_space(1))) const void* as1cv;
typedef __attribute__((address_space(3))) void* as3v;
__device__ __forceinline__ void gl_lds16(const void* g, void* l) {
    __builtin_amdgcn_global_load_lds((as1cv)g, (as3v)l, 16, 0, 0);
}

// ---------------- fused converts + packs + csum-zero: ONE dispatch ----------------
// Blocks 0..16383: float4->bf16x4 converts (job = id>>12: yf,xf,W_in,W_out).
// Blocks 16384..18431: pack_perm jobs (8 x 256 blocks).
// Blocks 18432..18559: zero csum[2] (131072 floats).
__global__ __launch_bounds__(256) void mega_pack_k(
    const float* __restrict__ yf, u16* __restrict__ yb,
    const float* __restrict__ xf, u16* __restrict__ xb,
    const float* __restrict__ W_in, u16* __restrict__ Winb,
    const float* __restrict__ W_out, u16* __restrict__ Woutb,
    const float* __restrict__ Wq1, const float* __restrict__ Wk1,
    const float* __restrict__ Wv1, const float* __restrict__ Wq2,
    u16* __restrict__ W1cat,
    const float* __restrict__ Wk2, const float* __restrict__ Wv2,
    u16* __restrict__ Wkv2t,
    const float* __restrict__ Wo1, u16* __restrict__ Wo1t,
    const float* __restrict__ Wo2, u16* __restrict__ Wo2t,
    float* __restrict__ csumz)
{
    __shared__ float tile[64][65];
    int id = blockIdx.x;
    if (id >= 18432) {
        long i = (long)(id - 18432) * 256 + threadIdx.x;
        float4 zz; zz.x = 0.f; zz.y = 0.f; zz.z = 0.f; zz.w = 0.f;
        reinterpret_cast<float4*>(csumz)[i] = zz;
        return;
    }
    if (id < 16384) {
        int j = id >> 12, local = id & 4095;
        const float* in; u16* out;
        switch (j) {
            case 0:  in = yf;    out = yb;    break;
            case 1:  in = xf;    out = xb;    break;
            case 2:  in = W_in;  out = Winb;  break;
            default: in = W_out; out = Woutb; break;
        }
        long i = (long)local * 256 + threadIdx.x;
        float4 v = reinterpret_cast<const float4*>(in)[i];
        ushort4 o;
        o.x = f2bf(v.x); o.y = f2bf(v.y); o.z = f2bf(v.z); o.w = f2bf(v.w);
        reinterpret_cast<ushort4*>(out)[i] = o;
        return;
    }
    int t = id - 16384;
    int pj = t >> 8, local = t & 255;
    const float* in; u16* out;
    int Q, R, bx, by, bz;
    if (pj < 6) {
        switch (pj) {
            case 0:  in = Wq1; out = W1cat;           break;
            case 1:  in = Wk1; out = W1cat + 1048576; break;
            case 2:  in = Wv1; out = W1cat + 2097152; break;
            case 3:  in = Wq2; out = W1cat + 3145728; break;
            case 4:  in = Wk2; out = Wkv2t;           break;
            default: in = Wv2; out = Wkv2t + 1048576; break;
        }
        Q = 1024; R = 64; bx = 0; by = local & 15; bz = local >> 4;
    } else {
        in = (pj == 6) ? Wo1 : Wo2; out = (pj == 6) ? Wo1t : Wo2t;
        Q = 1024; R = 1024; bx = local & 15; by = local >> 4; bz = 0;
    }
    int r0 = bx * 64, q0 = by * 64;
    int tx = threadIdx.x & 63, ty = threadIdx.x >> 6;
    const float* inp = in + ((long)bz * Q + q0) * R + r0;
    #pragma unroll
    for (int i = 0; i < 64; i += 4)
        tile[ty + i][tx] = inp[(long)(ty + i) * R + tx];
    __syncthreads();
    u16* outp = out + ((long)bz * R + r0) * Q + q0;
    #pragma unroll
    for (int i = 0; i < 64; i += 4)
        outp[(long)(ty + i) * Q + tx] = f2bf(tile[tx][ty + i]);
}

// Merged V-transpose + 1/l scale for BOTH MHAs. grid (16,16,8): z<4 -> MHA1
// (in1/ld1/zs1, Vt slab 0, csum half 0), z>=4 -> MHA2. out[c][r]=in[r][c]/l.
__global__ __launch_bounds__(256) void tscale2_k(
    const u16* __restrict__ in1, long ld1, long zs1,
    const u16* __restrict__ in2, long ld2, long zs2,
    u16* __restrict__ Vt, const float* __restrict__ csum) {
    __shared__ u16 tile[64][66];
    int z = blockIdx.z;
    int m = z >> 2, zb = z & 3;
    const u16* in; long ld, zs;
    if (m) { in = in2; ld = ld2; zs = zs2; } else { in = in1; ld = ld1; zs = zs1; }
    const u16* inz = in + (long)zb * zs;
    u16* outz = Vt + (long)m * 4194304 + (long)zb * 1048576;
    const float* cs = csum + m * 65536 + (long)zb * 16384;
    int r0 = blockIdx.y * 64;
    int c0 = blockIdx.x * 64;
    int tx = threadIdx.x & 63, ty = threadIdx.x >> 6;
    #pragma unroll
    for (int i = 0; i < 64; i += 4)
        tile[ty + i][tx] = inz[(long)(r0 + ty + i) * ld + c0 + tx];
    __syncthreads();
    #pragma unroll
    for (int i = 0; i < 64; i += 4) {
        int orow = c0 + ty + i;
        float f = bf2f(tile[tx][ty + i]) / cs[(orow >> 6) * 1024 + r0 + tx];
        outz[(long)orow * 1024 + r0 + tx] = f2bf(f);
    }
}

// ---------------- legacy GEMM (l-pass EPI=4 merged, Wo full-K merged) ----------------
// MRG=1 (SWZ=0 path): blockIdx.z in [0,128); z>=64 switches to the second
// pointer set (A2/lda2/B2/ldb2/b_zout2/csum2) with z &= 63.
template<int BM, int BN, int BK, int WM, int WN, int OUT_BF16, int EPI, int SWZ, int KS, int MRG>
__global__ __launch_bounds__(256) void gemm_k(
    const u16* __restrict__ A, long lda, long a_zin, long a_zout,
    const u16* __restrict__ B, long ldb, long b_zin, long b_zout,
    void* __restrict__ Cv, long ldc, long c_zin, long c_zout,
    int zin, int K, float alpha, const float* __restrict__ bias,
    float* __restrict__ csum,
    const u16* __restrict__ A2, long lda2,
    const u16* __restrict__ B2, long ldb2, long b_zout2,
    float* __restrict__ csum2)
{
    static_assert(BK == 64, "staging assumes BK=64");
    constexpr int WTM = BM / WM;
    constexpr int WTN = BN / WN;
    constexpr int TM = WTM / 16;
    constexpr int TN = WTN / 16;
    __shared__ __align__(16) u16 smem[(BM + BN) * BK];
    u16* As = smem;
    u16* Bs = smem + BM * BK;

    int bx, by, z;
    if (SWZ == 4) {
        int L = blockIdx.x;
        if (KS > 1) { z = L >> 9; L &= 511; } else { z = 0; }
        by = (L & 7) * 4 + ((L >> 3) & 3);
        bx = L >> 5;
    } else {
        bx = blockIdx.x; by = blockIdx.y; z = blockIdx.z;
    }
    if (MRG) {
        int m2 = z >> 6; z &= 63;
        if (m2) { A = A2; lda = lda2; B = B2; ldb = ldb2; b_zout = b_zout2; csum = csum2; }
    }
    int zi = z % zin, zo = z / zin;
    A += (long)zi * a_zin + (long)zo * a_zout;
    B += (long)zi * b_zin + (long)zo * b_zout;
    long coff = (long)zi * c_zin + (long)zo * c_zout;

    int tid = threadIdx.x;
    int lane = tid & 63;
    int wave = tid >> 6;
    int wm = wave / WN, wn = wave % WN;
    long bm0 = (long)by * BM, bn0 = (long)bx * BN;

    f32x4 acc[TM][TN];
    #pragma unroll
    for (int i = 0; i < TM; ++i)
        #pragma unroll
        for (int j = 0; j < TN; ++j) {
            acc[i][j][0] = 0.f; acc[i][j][1] = 0.f;
            acc[i][j][2] = 0.f; acc[i][j][3] = 0.f;
        }

    int r16 = lane & 15;
    int quad = lane >> 4;
    int l8 = lane >> 3;                    // stripe row
    int gsw = ((lane & 7) ^ l8) * 8;       // swizzled global col (elements)

    constexpr int ASTR = BM / 8;
    constexpr int BSTR = BN / 8;

    for (int k0 = 0; k0 < K; k0 += BK) {
        #pragma unroll
        for (int s = wave; s < ASTR; s += 4)
            gl_lds16(&A[(bm0 + s * 8 + l8) * lda + k0 + gsw], &As[s * 512]);
        #pragma unroll
        for (int s = wave; s < BSTR; s += 4)
            gl_lds16(&B[(bn0 + s * 8 + l8) * ldb + k0 + gsw], &Bs[s * 512]);
        __syncthreads();
        #pragma unroll
        for (int kk = 0; kk < BK; kk += 32) {
            int cb = (kk >> 3) + quad;
            bf16x8 av[TM], bv[TN];
            #pragma unroll
            for (int i = 0; i < TM; ++i) {
                int r = wm * WTM + i * 16 + r16;
                av[i] = *reinterpret_cast<const bf16x8*>(&As[r * 64 + ((cb ^ (r & 7)) * 8)]);
            }
            #pragma unroll
            for (int j = 0; j < TN; ++j) {
                int r = wn * WTN + j * 16 + r16;
                bv[j] = *reinterpret_cast<const bf16x8*>(&Bs[r * 64 + ((cb ^ (r & 7)) * 8)]);
            }
            #pragma unroll
            for (int i = 0; i < TM; ++i)
                #pragma unroll
                for (int j = 0; j < TN; ++j)
                    acc[i][j] = __builtin_amdgcn_mfma_f32_16x16x32_bf16(av[i], bv[j], acc[i][j], 0, 0, 0);
        }
        __syncthreads();
    }

    int rb = quad * 4;

    if (EPI == 4) {
        // exp + column sums only; no C store. csum layout [z][1024].
        float csl[TN];
        #pragma unroll
        for (int j = 0; j < TN; ++j) csl[j] = 0.f;
        #pragma unroll
        for (int i = 0; i < TM; ++i)
            #pragma unroll
            for (int j = 0; j < TN; ++j)
                #pragma unroll
                for (int r = 0; r < 4; ++r)
                    csl[j] += __expf(acc[i][j][r] * alpha);
        #pragma unroll
        for (int j = 0; j < TN; ++j) {
            float cs = csl[j];
            cs += __shfl_xor(cs, 16, 64);
            cs += __shfl_xor(cs, 32, 64);
            if (quad == 0) {
                long col = bn0 + wn * WTN + j * 16 + r16;
                atomicAdd(&csum[((long)zo * zin + zi) * 1024 + col], cs);
            }
        }
        return;
    }

    // ---- LDS-staged store epilogue ----
    constexpr int EB = OUT_BF16 ? 2 : 4;
    constexpr int CH = 16 / EB;
    constexpr int STRIDE = BN + CH;
    constexpr int LDSB = (BM + BN) * BK * 2;
    constexpr int EPASS = (BM * STRIDE * EB > LDSB) ? 2 : 1;
    constexpr int RPP = BM / EPASS;
    static_assert(RPP * STRIDE * EB <= LDSB, "epilogue tile overflows LDS");
    static_assert(EPASS == 1 || (WM == 2 && WTM == RPP), "pass/wave row alignment");
    constexpr int CPR = BN / CH;
    constexpr int NCH = RPP * CPR / 256;
    static_assert(RPP * CPR % 256 == 0, "store mapping");

    float* Ef = reinterpret_cast<float*>(smem);
    char* Cb = reinterpret_cast<char*>(Cv);

    for (int pass = 0; pass < EPASS; ++pass) {
        int p0 = pass * RPP;
        __syncthreads();
        #pragma unroll
        for (int i = 0; i < TM; ++i) {
            #pragma unroll
            for (int j = 0; j < TN; ++j) {
                int lcol = wn * WTN + j * 16 + r16;
                float bsv = (EPI == 1 || EPI == 2) ? bias[bn0 + lcol] : 0.f;
                #pragma unroll
                for (int r = 0; r < 4; ++r) {
                    int lrow = wm * WTM + i * 16 + rb + r;
                    if ((unsigned)(lrow - p0) < (unsigned)RPP) {
                        float v = acc[i][j][r] * alpha;
                        if (EPI == 1) { v += bsv; v = v > 0.f ? v : 0.f; }
                        else if (EPI == 2) { v += bsv; }
                        if (OUT_BF16) smem[(lrow - p0) * STRIDE + lcol] = f2bf(v);
                        else          Ef[(lrow - p0) * STRIDE + lcol] = v;
                    }
                }
            }
        }
        __syncthreads();
        #pragma unroll
        for (int c = 0; c < NCH; ++c) {
            int cid = tid + c * 256;
            int row = cid / CPR, ch = cid - row * CPR;
            int4 v = *reinterpret_cast<const int4*>(
                reinterpret_cast<const char*>(smem) + (row * STRIDE + ch * CH) * EB);
            long gidx = coff + (bm0 + p0 + row) * ldc + bn0 + ch * CH;
            *reinterpret_cast<int4*>(Cb + gidx * EB) = v;
        }
    }
}

// ---------------- 8-phase 256x256 GEMM (R1 schedule, frozen) ----------------
// Per K-tile t, 4 phases = (ih,jh) quadrants x K=64, 2 raw barriers each:
//   ph1: read av(ih0),bv(jh0) | stage (t+1).A-half1 | vmcnt(10)
//   ph2: read bv(jh1)         | stage (t+2).A-half0 | vmcnt(10)
//   ph3: read av(ih1)         | stage (t+2).B-half0 |
//   ph4:                      | stage (t+2).B-half1 | vmcnt(10)
// SPLITN=1: first NT/2 bx-tiles -> Cv (no epi); second NT/2 -> Cv2 with
// bias+relu, column base rebased (QKV1 + FFN-in fused dispatch).

__device__ __forceinline__ void bar_raw() {
    asm volatile("" ::: "memory");
    __builtin_amdgcn_s_barrier();
    asm volatile("" ::: "memory");
}

template<int N> __device__ __forceinline__ void vmw() {
    if constexpr (N == 10) asm volatile("s_waitcnt vmcnt(10)" ::: "memory");
    else if constexpr (N == 8) asm volatile("s_waitcnt vmcnt(8)" ::: "memory");
    else if constexpr (N == 4) asm volatile("s_waitcnt vmcnt(4)" ::: "memory");
    else if constexpr (N == 2) asm volatile("s_waitcnt vmcnt(2)" ::: "memory");
    else if constexpr (N == 0) asm volatile("s_waitcnt vmcnt(0)" ::: "memory");
}

// stage one half-tile (16 stripes of 8 rows x 64 cols) = 2 gl_lds per thread
__device__ __forceinline__ void stage_half(const u16* __restrict__ base, long ld, int kt,
                                           u16* __restrict__ lds, int half, int wave) {
    const u16* src = base + (long)kt * 64;
    #pragma unroll
    for (int u = 0; u < 2; ++u) {
        int s = half * 16 + u * 8 + wave;
        gl_lds16(src + (long)(s * 8) * ld, lds + s * 512);
    }
}

template<int IH>
__device__ __forceinline__ void read_a8(bf16x8 (&av)[4][2], const u16* __restrict__ As,
                                        int wm, int r16, int quad) {
    #pragma unroll
    for (int ii = 0; ii < 4; ++ii) {
        int r = IH * 128 + wm * 64 + ii * 16 + r16;
        #pragma unroll
        for (int kx = 0; kx < 2; ++kx)
            av[ii][kx] = *reinterpret_cast<const bf16x8*>(&As[r * 64 + (((kx * 4 + quad) ^ (r & 7)) * 8)]);
    }
}

template<int JH>
__device__ __forceinline__ void read_b8(bf16x8 (&bv)[2][2], const u16* __restrict__ Bs,
                                        int wn, int r16, int quad) {
    #pragma unroll
    for (int j = 0; j < 2; ++j) {
        int r = JH * 128 + wn * 32 + j * 16 + r16;
        #pragma unroll
        for (int kx = 0; kx < 2; ++kx)
            bv[j][kx] = *reinterpret_cast<const bf16x8*>(&Bs[r * 64 + (((kx * 4 + quad) ^ (r & 7)) * 8)]);
    }
}

template<int IH, int JH>
__device__ __forceinline__ void mfma_q(f32x4 (&acc)[2][4][2][2],
                                       const bf16x8 (&av)[4][2], const bf16x8 (&bv)[2][2]) {
    #pragma unroll
    for (int kx = 0; kx < 2; ++kx)
        #pragma unroll
        for (int ii = 0; ii < 4; ++ii)
            #pragma unroll
            for (int j = 0; j < 2; ++j)
                acc[IH][ii][JH][j] = __builtin_amdgcn_mfma_f32_16x16x32_bf16(
                    av[ii][kx], bv[j][kx], acc[IH][ii][JH][j], 0, 0, 0);
}

// MODE 0: steady; 1: t=T-2 (only (t+1).A1 staged); 2: t=T-1 (no staging)
template<int MODE>
__device__ __forceinline__ void tile_iter(
    int t, f32x4 (&acc)[2][4][2][2], bf16x8 (&av)[4][2], bf16x8 (&bvh)[2][2][2],
    u16* __restrict__ smem, const u16* __restrict__ Ab, long lda,
    const u16* __restrict__ Bb, long ldb, int wave, int wm, int wn, int r16, int quad)
{
    u16* As0 = smem + (t & 1) * 32768;          // buf for tile t (also target of t+2 stages)
    u16* Bs0 = As0 + 16384;
    u16* As1 = smem + ((t + 1) & 1) * 32768;    // buf for tile t+1
    // ---- ph1 (ih0,jh0)
    read_a8<0>(av, As0, wm, r16, quad);
    read_b8<0>(bvh[0], Bs0, wn, r16, quad);
    if (MODE < 2) stage_half(Ab, lda, t + 1, As1, 1, wave);
    vmw<MODE == 0 ? 10 : (MODE == 1 ? 10 : 2)>();
    bar_raw(); __builtin_amdgcn_sched_barrier(0);
    __builtin_amdgcn_s_setprio(1);
    mfma_q<0, 0>(acc, av, bvh[0]);
    __builtin_amdgcn_s_setprio(0);
    __builtin_amdgcn_sched_barrier(0);
    bar_raw();
    // ---- ph2 (ih0,jh1)
    read_b8<1>(bvh[1], Bs0, wn, r16, quad);
    if (MODE == 0) stage_half(Ab, lda, t + 2, As0, 0, wave);
    vmw<MODE == 0 ? 10 : (MODE == 1 ? 8 : 0)>();
    bar_raw(); __builtin_amdgcn_sched_barrier(0);
    __builtin_amdgcn_s_setprio(1);
    mfma_q<0, 1>(acc, av, bvh[1]);
    __builtin_amdgcn_s_setprio(0);
    __builtin_amdgcn_sched_barrier(0);
    bar_raw();
    // ---- ph3 (ih1,jh0)
    read_a8<1>(av, As0, wm, r16, quad);
    if (MODE == 0) stage_half(Bb, ldb, t + 2, Bs0, 0, wave);
    bar_raw(); __builtin_amdgcn_sched_barrier(0);
    __builtin_amdgcn_s_setprio(1);
    mfma_q<1, 0>(acc, av, bvh[0]);
    __builtin_amdgcn_s_setprio(0);
    __builtin_amdgcn_sched_barrier(0);
    bar_raw();
    // ---- ph4 (ih1,jh1)
    if (MODE == 0) stage_half(Bb, ldb, t + 2, Bs0, 1, wave);
    if (MODE < 2) vmw<MODE == 0 ? 10 : 4>();
    bar_raw(); __builtin_amdgcn_sched_barrier(0);
    __builtin_amdgcn_s_setprio(1);
    mfma_q<1, 1>(acc, av, bvh[1]);
    __builtin_amdgcn_s_setprio(0);
    __builtin_amdgcn_sched_barrier(0);
    bar_raw();
}

// grid = 16*NT*KS blocks of 512. EPI: 0 none, 1 bias+relu. KS>1: z picks K-chunk,
// output slab z: z<2 -> Cv + (z&1)*czs, z>=2 -> Cv2 + (z&1)*czs (fp32).
// SPLITN=1 (KS must be 1): bx>=NT/2 -> Cv2, bias+relu, columns rebased.
template<int NT, int KS, int EPI, int OUT_BF16, int SPLITN>
__global__ __launch_bounds__(512, 2) void gemm8_k(
    const u16* __restrict__ A, long lda,
    const u16* __restrict__ B, long ldb,
    void* __restrict__ Cv, void* __restrict__ Cv2, long ldc,
    int K, float alpha, const float* __restrict__ bias, long czs)
{
    __shared__ __align__(16) u16 smem[65536];   // 128 KiB

    int L = blockIdx.x;
    int z = 0;
    if (KS > 1) { z = L / (16 * NT); L -= z * 16 * NT; }
    int by = (L & 7) * 2 + ((L >> 3) & 1);      // XCD-contiguous M-rows
    int bx = L >> 4;
    if (KS > 1) { A += (long)z * K; B += (long)z * K; }

    int tid = threadIdx.x;
    int lane = tid & 63, wave = tid >> 6;
    int wm = wave >> 2, wn = wave & 3;
    int r16 = lane & 15, quad = lane >> 4, l8 = lane >> 3;
    int gsw = ((lane & 7) ^ l8) * 8;
    long bm0 = (long)by * 256, bn0 = (long)bx * 256;
    const u16* Ab = A + (bm0 + l8) * lda + gsw;
    const u16* Bb = B + (bn0 + l8) * ldb + gsw;

    f32x4 acc[2][4][2][2];
    #pragma unroll
    for (int a0 = 0; a0 < 2; ++a0)
        #pragma unroll
        for (int a1 = 0; a1 < 4; ++a1)
            #pragma unroll
            for (int a2 = 0; a2 < 2; ++a2)
                #pragma unroll
                for (int a3 = 0; a3 < 2; ++a3) {
                    acc[a0][a1][a2][a3][0] = 0.f; acc[a0][a1][a2][a3][1] = 0.f;
                    acc[a0][a1][a2][a3][2] = 0.f; acc[a0][a1][a2][a3][3] = 0.f;
                }
    bf16x8 av[4][2];
    bf16x8 bvh[2][2][2];

    int T = K >> 6;   // >= 3

    // prologue issue stream: [0.A0, 0.B0, 0.B1, 0.A1, 1.A0, 1.B0, 1.B1]
    stage_half(Ab, lda, 0, smem,         0, wave);
    stage_half(Bb, ldb, 0, smem + 16384, 0, wave);
    stage_half(Bb, ldb, 0, smem + 16384, 1, wave);
    stage_half(Ab, lda, 0, smem,         1, wave);
    stage_half(Ab, lda, 1, smem + 32768, 0, wave);
    stage_half(Bb, ldb, 1, smem + 49152, 0, wave);
    stage_half(Bb, ldb, 1, smem + 49152, 1, wave);
    vmw<10>();          // 14 issued -> oldest 4 (0.A0,0.B0) landed
    bar_raw();

    for (int t = 0; t < T - 2; ++t)
        tile_iter<0>(t, acc, av, bvh, smem, Ab, lda, Bb, ldb, wave, wm, wn, r16, quad);
    tile_iter<1>(T - 2, acc, av, bvh, smem, Ab, lda, Bb, ldb, wave, wm, wn, r16, quad);
    tile_iter<2>(T - 1, acc, av, bvh, smem, Ab, lda, Bb, ldb, wave, wm, wn, r16, quad);

    // ---- epilogue: stage to LDS (row-XOR-swizzled), coalesced int4 stores
    constexpr int EB = OUT_BF16 ? 2 : 4;
    constexpr int EPASS = OUT_BF16 ? 1 : 2;   // f32 = 2 passes of 128 rows (ih=pass)
    bool sec = SPLITN && (bx >= NT / 2);
    char* Cb;
    long bnc = bn0;
    if (SPLITN) {
        Cb = reinterpret_cast<char*>(sec ? Cv2 : Cv);
        if (sec) bnc = bn0 - (long)(NT / 2) * 256;
    } else {
        Cb = reinterpret_cast<char*>((KS > 1 && z >= 2) ? Cv2 : Cv);
        if (KS > 1) Cb += (long)(z & 1) * czs * EB;
    }
    bool do_bias = (EPI == 1) || sec;
    float bsv[2][2];
    if (do_bias) {
        #pragma unroll
        for (int jh = 0; jh < 2; ++jh)
            #pragma unroll
            for (int j = 0; j < 2; ++j)
                bsv[jh][j] = bias[bnc + jh * 128 + wn * 32 + j * 16 + r16];
    }
    u16* sm16 = smem;
    float* smf = reinterpret_cast<float*>(smem);
    #pragma unroll
    for (int pass = 0; pass < EPASS; ++pass) {
        bar_raw();
        #pragma unroll
        for (int ih = 0; ih < 2; ++ih) {
            if (EPASS == 2 && ih != pass) continue;
            #pragma unroll
            for (int ii = 0; ii < 4; ++ii)
                #pragma unroll
                for (int jh = 0; jh < 2; ++jh)
                    #pragma unroll
                    for (int j = 0; j < 2; ++j)
                        #pragma unroll
                        for (int r = 0; r < 4; ++r) {
                            int lrow = (EPASS == 2 ? 0 : ih * 128) + wm * 64 + ii * 16 + quad * 4 + r;
                            int lcol = jh * 128 + wn * 32 + j * 16 + r16;
                            float v = acc[ih][ii][jh][j][r] * alpha;
                            if (do_bias) { v += bsv[jh][j]; v = v > 0.f ? v : 0.f; }
                            int scol = lcol ^ ((lrow & 7) * 8);
                            if (OUT_BF16) sm16[lrow * 256 + scol] = f2bf(v);
                            else          smf[lrow * 256 + scol] = v;
                        }
        }
        bar_raw();
        constexpr int CH = 16 / EB;
        constexpr int CPR = 256 / CH;
        constexpr int NCH = (OUT_BF16 ? 256 : 128) * CPR / 512;
        #pragma unroll
        for (int c = 0; c < NCH; ++c) {
            int cid = tid + c * 512;
            int row = cid / CPR, ch = cid - row * CPR;
            int col = (ch * CH) ^ ((row & 7) * 8);
            int4 v = *reinterpret_cast<const int4*>(
                reinterpret_cast<const char*>(smem) + ((long)row * 256 + col) * EB);
            long grow = bm0 + pass * 128 + row;
            *reinterpret_cast<int4*>(Cb + (grow * ldc + bnc + ch * CH) * EB) = v;
        }
    }
}

// ---------------- fused attention PV (both MHAs in one dispatch) ----------------
// MRG=1: grid 1024; L>=512 switches to second pointer set (MHA2).
// Per block: out[128 t][64 v] = sum_s exp(0.125*Q K^T) * Vt_scaled.
// K/V double-buffered; stage(c+1) issued BEFORE chunk c compute; counted
// vmcnt(4) + barrier; mid-chunk lgkmcnt(0)+barrier (Es rows filled by both
// waves of the wm band).
template<int MRG>
__global__ __launch_bounds__(256) void attn_pv_k(
    const u16* __restrict__ Qg, long ldq, long qbz,
    const u16* __restrict__ Kg, long ldk, long kbz,
    const u16* __restrict__ Vg, u16* __restrict__ outg,
    const u16* __restrict__ Qg2,
    const u16* __restrict__ Kg2, long ldk2, long kbz2,
    const u16* __restrict__ Vg2, u16* __restrict__ outg2)
{
    __shared__ __align__(16) u16 Qs[128 * 64];
    __shared__ __align__(16) u16 Ks[2][64 * 64];
    __shared__ __align__(16) u16 Vs[2][64 * 64];
    __shared__ __align__(16) u16 Es[128 * 64];

    int L = blockIdx.x;
    if (MRG) {
        int m = L >> 9; L &= 511;
        if (m) { Qg = Qg2; Kg = Kg2; ldk = ldk2; kbz = kbz2; Vg = Vg2; outg = outg2; }
    }
    int h  = (L & 7) * 2 + ((L >> 3) & 1);
    int tb = (L >> 4) & 7;
    int b  = L >> 7;

    const u16* Q  = Qg + (long)b * qbz + h * 64;
    const u16* Kp = Kg + (long)b * kbz + h * 64;
    const u16* Vp = Vg + (long)b * 1048576 + (long)h * 65536;
    u16* outp = outg + (long)b * 1048576 + (long)tb * 131072 + h * 64;

    int tid = threadIdx.x, lane = tid & 63, wave = tid >> 6;
    int wm = wave >> 1, wn = wave & 1;
    int r16 = lane & 15, quad = lane >> 4, l8 = lane >> 3;
    int gsw = ((lane & 7) ^ l8) * 8;
    long t0 = (long)tb * 128;

    // prologue: Q (4 loads/thread) + K/V chunk 0 (4 loads/thread)
    #pragma unroll
    for (int s = wave; s < 16; s += 4)
        gl_lds16(&Q[(t0 + s * 8 + l8) * ldq + gsw], &Qs[s * 512]);
    #pragma unroll
    for (int s = wave; s < 8; s += 4) {
        gl_lds16(&Kp[(long)(s * 8 + l8) * ldk + gsw], &Ks[0][s * 512]);
        gl_lds16(&Vp[(long)(s * 8 + l8) * 1024 + gsw], &Vs[0][s * 512]);
    }

    f32x4 acc[4][2];
    #pragma unroll
    for (int i = 0; i < 4; ++i)
        #pragma unroll
        for (int j = 0; j < 2; ++j) {
            acc[i][j][0] = 0.f; acc[i][j][1] = 0.f;
            acc[i][j][2] = 0.f; acc[i][j][3] = 0.f;
        }

    for (int sc = 0; sc < 16; ++sc) {
        const u16* Ksc = Ks[sc & 1];
        const u16* Vsc = Vs[sc & 1];
        if (sc < 15) {
            int nc = sc + 1;
            u16* Kn = Ks[nc & 1];
            u16* Vn = Vs[nc & 1];
            #pragma unroll
            for (int s = wave; s < 8; s += 4) {
                gl_lds16(&Kp[(long)(nc * 64 + s * 8 + l8) * ldk + gsw], &Kn[s * 512]);
                gl_lds16(&Vp[(long)(s * 8 + l8) * 1024 + nc * 64 + gsw], &Vn[s * 512]);
            }
            asm volatile("s_waitcnt vmcnt(4)" ::: "memory");   // chunk sc (and Q) landed
        } else {
            asm volatile("s_waitcnt vmcnt(0)" ::: "memory");   // last chunk landed
        }
        bar_raw();                            // all waves' chunk-sc loads visible

        // E-chunk = Q x K^T (128x64, contraction 64)
        f32x4 e[4][2];
        #pragma unroll
        for (int i = 0; i < 4; ++i)
            #pragma unroll
            for (int j = 0; j < 2; ++j) {
                e[i][j][0] = 0.f; e[i][j][1] = 0.f;
                e[i][j][2] = 0.f; e[i][j][3] = 0.f;
            }
        #pragma unroll
        for (int kk = 0; kk < 64; kk += 32) {
            int cb = (kk >> 3) + quad;
            bf16x8 av[4], bv[2];
            #pragma unroll
            for (int i = 0; i < 4; ++i) {
                int r = wm * 64 + i * 16 + r16;
                av[i] = *reinterpret_cast<const bf16x8*>(&Qs[r * 64 + ((cb ^ (r & 7)) * 8)]);
            }
            #pragma unroll
            for (int j = 0; j < 2; ++j) {
                int r = wn * 32 + j * 16 + r16;
                bv[j] = *reinterpret_cast<const bf16x8*>(&Ksc[r * 64 + ((cb ^ (r & 7)) * 8)]);
            }
            #pragma unroll
            for (int i = 0; i < 4; ++i)
                #pragma unroll
                for (int j = 0; j < 2; ++j)
                    e[i][j] = __builtin_amdgcn_mfma_f32_16x16x32_bf16(av[i], bv[j], e[i][j], 0, 0, 0);
        }
        // exp + write to Es (C-frag: row=quad*4+r, col=r16; XOR-swizzled rows)
        #pragma unroll
        for (int i = 0; i < 4; ++i)
            #pragma unroll
            for (int j = 0; j < 2; ++j) {
                int lcol = wn * 32 + j * 16 + r16;
                #pragma unroll
                for (int r = 0; r < 4; ++r) {
                    int lrow = wm * 64 + i * 16 + quad * 4 + r;
                    float v = __expf(e[i][j][r] * 0.125f);
                    Es[lrow * 64 + (((lcol >> 3) ^ (lrow & 7)) * 8) + (lcol & 7)] = f2bf(v);
                }
            }
        asm volatile("s_waitcnt lgkmcnt(0)" ::: "memory");
        bar_raw();

        // acc += E-chunk x Vs^T (contraction over s-chunk)
        #pragma unroll
        for (int kk = 0; kk < 64; kk += 32) {
            int cb = (kk >> 3) + quad;
            bf16x8 av[4], bv[2];
            #pragma unroll
            for (int i = 0; i < 4; ++i) {
                int r = wm * 64 + i * 16 + r16;
                av[i] = *reinterpret_cast<const bf16x8*>(&Es[r * 64 + ((cb ^ (r & 7)) * 8)]);
            }
            #pragma unroll
            for (int j = 0; j < 2; ++j) {
                int r = wn * 32 + j * 16 + r16;
                bv[j] = *reinterpret_cast<const bf16x8*>(&Vsc[r * 64 + ((cb ^ (r & 7)) * 8)]);
            }
            #pragma unroll
            for (int i = 0; i < 4; ++i)
                #pragma unroll
                for (int j = 0; j < 2; ++j)
                    acc[i][j] = __builtin_amdgcn_mfma_f32_16x16x32_bf16(av[i], bv[j], acc[i][j], 0, 0, 0);
        }
        bar_raw();                 // all waves done reading buf[sc&1] K/V + Es
    }

    #pragma unroll
    for (int i = 0; i < 4; ++i)
        #pragma unroll
        for (int j = 0; j < 2; ++j) {
            int lcol = wn * 32 + j * 16 + r16;
            #pragma unroll
            for (int r = 0; r < 4; ++r) {
                int lrow = wm * 64 + i * 16 + quad * 4 + r;
                outp[(long)lrow * 1024 + lcol] = f2bf(acc[i][j][r]);
            }
        }
}

// ---------------- out = (sum of NP partial slabs + resid [+bias]) - mean - std ----------------
// Slabs 0,1 from parts; slabs 2,3 (NP=4) from parts2. NP=1: single slab.
template<int NP, int BIAS>
__global__ __launch_bounds__(256) void addsn_k(const float* __restrict__ parts,
                                               const float* __restrict__ parts2,
                                               long pstride,
                                               const float* __restrict__ resid,
                                               const float* __restrict__ bias,
                                               float* __restrict__ out) {
    __shared__ float sm[8];
    long row = blockIdx.x;
    int tid = threadIdx.x;
    float4 x = reinterpret_cast<const float4*>(resid + row * 1024)[tid];
    #pragma unroll
    for (int p = 0; p < NP; ++p) {
        const float* src = (p < 2) ? (parts + p * pstride) : (parts2 + (p - 2) * pstride);
        float4 a = reinterpret_cast<const float4*>(src + row * 1024)[tid];
        x.x += a.x; x.y += a.y; x.z += a.z; x.w += a.w;
    }
    if (BIAS) {
        float4 bb = reinterpret_cast<const float4*>(bias)[tid];
        x.x += bb.x; x.y += bb.y; x.z += bb.z; x.w += bb.w;
    }
    float s = x.x + x.y + x.z + x.w;
    for (int o = 32; o > 0; o >>= 1) s += __shfl_down(s, o, 64);
    int lane = tid & 63, w = tid >> 6;
    if (lane == 0) sm[w] = s;
    __syncthreads();
    float mean = (sm[0] + sm[1] + sm[2] + sm[3]) * (1.f / 1024.f);
    float d0 = x.x - mean, d1 = x.y - mean, d2 = x.z - mean, d3 = x.w - mean;
    float q = d0 * d0 + d1 * d1 + d2 * d2 + d3 * d3;
    for (int o = 32; o > 0; o >>= 1) q += __shfl_down(q, o, 64);
    if (lane == 0) sm[w + 4] = q;
    __syncthreads();
    float sd = sqrtf((sm[4] + sm[5] + sm[6] + sm[7]) * (1.f / 1023.f));
    float4 ov;
    ov.x = d0 - sd; ov.y = d1 - sd; ov.z = d2 - sd; ov.w = d3 - sd;
    reinterpret_cast<float4*>(out + row * 1024)[tid] = ov;
}

// ---------------- launcher ----------------

extern "C" void kernel_launch(void* const* d_in, const int* in_sizes, int n_in,
                              void* d_out, int out_size, void* d_ws, size_t ws_size,
                              hipStream_t stream) {
    (void)in_sizes; (void)n_in; (void)out_size; (void)ws_size;
    const float* xf   = (const float*)d_in[0];
    const float* yf   = (const float*)d_in[1];
    const float* Wq1  = (const float*)d_in[2];
    const float* Wk1  = (const float*)d_in[3];
    const float* Wv1  = (const float*)d_in[4];
    const float* Wo1  = (const float*)d_in[5];
    const float* Wq2  = (const float*)d_in[6];
    const float* Wk2  = (const float*)d_in[7];
    const float* Wv2  = (const float*)d_in[8];
    const float* Wo2  = (const float*)d_in[9];
    const float* W_in = (const float*)d_in[10];
    const float* b_in = (const float*)d_in[11];
    const float* W_out= (const float*)d_in[12];
    const float* b_out= (const float*)d_in[13];

    // workspace layout (176 MB with aliases; lifetimes in header comment)
    char* p = (char*)d_ws;
    auto alloc = [&](size_t bytes) { char* r = p; p += bytes; return r; };
    u16*   yb    = (u16*)alloc(8388608);    // dead after SPLITN
    u16*   xb    = (u16*)alloc(8388608);    // dead after KV2 gemm
    u16*   W1cat = (u16*)alloc(8388608);    // dead after SPLITN
    u16*   Winb  = (u16*)alloc(8388608);    // dead after SPLITN (contiguous with W1cat)
    u16*   Wkv2t = (u16*)alloc(4194304);
    u16*   Wo1t  = (u16*)alloc(2097152);
    u16*   Wo2t  = (u16*)alloc(2097152);    // contiguous after Wo1t (b_zout=1048576)
    u16*   Woutb = (u16*)alloc(8388608);
    u16*   QKV   = (u16*)alloc(33554432);   // [Q1|K1|V1|Q2]; FFN-out fp32 slabs 0,1 after attn
    u16*   KV2   = (u16*)alloc(16777216);   // [K2|V2]
    u16*   Pb    = (u16*)alloc(33554432);   // FFN hidden
    u16*   part  = (u16*)alloc(16777216);   // attn partials [2 mha][4096][1024] bf16
    float* gout  = (float*)alloc(33554432); // Wo fp32 outputs, 2 slabs of 16 MB
    // aliases:
    u16*   Vt    = yb;                      // [2 mha][1024 hv][1024 s] (16 MB over yb+xb)
    float* csum  = gout;                    // [2 mha][4][16][1024] (512 KB, dead before Wo)
    float* out1  = (float*)part;            // addsn1 output (part dead after Wo)
    float* ffnC2 = (float*)yb;              // FFN-out slabs 2,3 (32 MB over yb..Winb)

    // 1. all converts + weight packs + csum zero
    mega_pack_k<<<18560, 256, 0, stream>>>(
        yf, yb, xf, xb, W_in, Winb, W_out, Woutb,
        Wq1, Wk1, Wv1, Wq2, W1cat, Wk2, Wv2, Wkv2t,
        Wo1, Wo1t, Wo2, Wo2t, csum);

    // 2. QKV1+Q2 AND FFN-in in one dispatch (A=yb; B=[W1cat|Winb] contiguous)
    gemm8_k<32,1,0,1,1><<<512, 512, 0, stream>>>(
        yb, 1024L, W1cat, 1024L, (void*)QKV, (void*)Pb, 4096L, 1024, 1.0f, b_in, 0L);
    // 3. K2/V2 from x, N=2048
    gemm8_k<8,1,0,1,0><<<128, 512, 0, stream>>>(
        xb, 1024L, Wkv2t, 1024L, (void*)KV2, nullptr, 2048L, 1024, 1.0f, nullptr, 0L);

    // 4. l-pass BOTH MHAs: grid (8,8,128); z<64 MHA1 (Q1 x K1), z>=64 MHA2
    //    (Q2 x K2). zin=16: zi=h (stride 64), zo=b.
    gemm_k<128,128,64,2,2,1,4,0,1,1><<<dim3(8, 8, 128), 256, 0, stream>>>(
        QKV, 4096L, 64L, 4194304L,            // A1 = Q1
        QKV + 1024, 4096L, 64L, 4194304L,     // B1 = K1
        (void*)Pb, 1024L, 0L, 0L, 16, 64, 0.125f, nullptr, csum,
        QKV + 3072, 4096L,                    // A2 = Q2
        KV2, 2048L, 2097152L,                 // B2 = K2
        csum + 65536);

    // 5. V-transpose + 1/l scale, both MHAs (Vt slabs 0,1 = dead yb/xb region)
    tscale2_k<<<dim3(16, 16, 8), 256, 0, stream>>>(
        QKV + 2048, 4096L, 4194304L,          // V1
        KV2 + 1024, 2048L, 2097152L,          // V2
        Vt, csum);

    // 6. attention PV, both MHAs (part slabs 0,1)
    attn_pv_k<1><<<1024, 256, 0, stream>>>(
        QKV, 4096L, 4194304L, QKV + 1024, 4096L, 4194304L, Vt, part,
        QKV + 3072, KV2, 2048L, 2097152L, Vt + 4194304, part + 4194304);

    // 7. Wo both MHAs, full-K (KS=2 only for z=mha decode): grid 2*512.
    //    z: A += z*4194304 (part slab), B += z*1048576 (Wo1t->Wo2t),
    //    C += z*4194304 floats (gout slab). K=1024 full contraction.
    gemm_k<128,64,64,2,2,0,0,4,2,0><<<1024, 256, 0, stream>>>(
        part, 1024L, 0L, 4194304L, Wo1t, 1024L, 0L, 1048576L,
        (void*)gout, 1024L, 0L, 4194304L, 1, 1024, 1.0f, nullptr, nullptr,
        nullptr, 0L, nullptr, 0L, 0L, nullptr);

    // 8. FFN-out: split-K 4; slabs 0,1 -> QKV (dead), slabs 2,3 -> yb region
    //    (dead; Vt dead after step 6). gout holds live Wo results - untouched.
    gemm8_k<4,4,0,0,0><<<256, 512, 0, stream>>>(
        Pb, 4096L, Woutb, 4096L, (void*)QKV, (void*)ffnC2, 1024L, 1024, 1.0f, nullptr, 4194304L);

    // 9-11. sub_norm chain
    addsn_k<1,0><<<4096, 256, 0, stream>>>(gout, nullptr, 0L, yf, nullptr, out1);
    addsn_k<1,0><<<4096, 256, 0, stream>>>(gout + 4194304, nullptr, 0L, out1, nullptr, (float*)d_out);
    addsn_k<4,1><<<4096, 256, 0, stream>>>((const float*)QKV, ffnC2, 4194304L,
                                           (const float*)d_out, b_out, (float*)d_out);
}

// Round 9
// 470.694 us; speedup vs baseline: 1.2918x; 1.0234x over previous
//
#include <hip/hip_runtime.h>

// DecoderStack: B=4,T=1024,D=1024,H=16,DK=DV=64,FF=4096
// Softmax over QUERY axis: l_s = sum_t exp(S) via store-free l-pass (EPI=4),
// 1/l_s folded into the V-transpose, then attn_pv_k recomputes E per tile in
// LDS and multiplies by V — E never touches HBM.
// sub_norm(o) = o - mean - std (ddof=1).
// gemm8_k: R1 schedule (best measured), frozen.
// R9 (9 dispatches):
//   1 mega_pack (+csum zero)        6 Wo_both   (full-K, both MHAs)
//   2 SPLITN gemm8 (QKV+FFN-in)     7 FFN-out   (split-K4 -> QKV + yb-region)
//   3 KV2 legacy gemm_k 128^2 tiles 8 addsn_fuse (all 3 sub_norms, 1 kernel)
//   4 lpass_both  (MRG z>=64)
//   5 tscale_both; 6' attnpv_both
// R9 changes vs R8: (a) KV2 moved from gemm8 grid-128 (half machine idle,
// ~43us) to legacy 128^2 gemm_k grid (16,32)=512 blocks (~27us predicted);
// (b) three addsn dispatches fused into one per-row chain kernel (sm[8]
// reuse race-free: slot readers complete before the overwriting barrier).

typedef unsigned short u16;
typedef __bf16 bf16x8 __attribute__((ext_vector_type(8)));
typedef float f32x4 __attribute__((ext_vector_type(4)));

__device__ __forceinline__ u16 f2bf(float f) {
    unsigned int u = __float_as_uint(f);
    u += 0x7fffu + ((u >> 16) & 1u);   // RNE; inputs are finite
    return (u16)(u >> 16);
}
__device__ __forceinline__ float bf2f(u16 b) {
    return __uint_as_float(((unsigned int)b) << 16);
}

typedef __attribute__((address_space(1))) const void* as1cv;
typedef __attribute__((address_space(3))) void* as3v;
__device__ __forceinline__ void gl_lds16(const void* g, void* l) {
    __builtin_amdgcn_global_load_lds((as1cv)g, (as3v)l, 16, 0, 0);
}

// ---------------- fused converts + packs + csum-zero: ONE dispatch ----------------
// Blocks 0..16383: float4->bf16x4 converts (job = id>>12: yf,xf,W_in,W_out).
// Blocks 16384..18431: pack_perm jobs (8 x 256 blocks).
// Blocks 18432..18559: zero csum[2] (131072 floats).
__global__ __launch_bounds__(256) void mega_pack_k(
    const float* __restrict__ yf, u16* __restrict__ yb,
    const float* __restrict__ xf, u16* __restrict__ xb,
    const float* __restrict__ W_in, u16* __restrict__ Winb,
    const float* __restrict__ W_out, u16* __restrict__ Woutb,
    const float* __restrict__ Wq1, const float* __restrict__ Wk1,
    const float* __restrict__ Wv1, const float* __restrict__ Wq2,
    u16* __restrict__ W1cat,
    const float* __restrict__ Wk2, const float* __restrict__ Wv2,
    u16* __restrict__ Wkv2t,
    const float* __restrict__ Wo1, u16* __restrict__ Wo1t,
    const float* __restrict__ Wo2, u16* __restrict__ Wo2t,
    float* __restrict__ csumz)
{
    __shared__ float tile[64][65];
    int id = blockIdx.x;
    if (id >= 18432) {
        long i = (long)(id - 18432) * 256 + threadIdx.x;
        float4 zz; zz.x = 0.f; zz.y = 0.f; zz.z = 0.f; zz.w = 0.f;
        reinterpret_cast<float4*>(csumz)[i] = zz;
        return;
    }
    if (id < 16384) {
        int j = id >> 12, local = id & 4095;
        const float* in; u16* out;
        switch (j) {
            case 0:  in = yf;    out = yb;    break;
            case 1:  in = xf;    out = xb;    break;
            case 2:  in = W_in;  out = Winb;  break;
            default: in = W_out; out = Woutb; break;
        }
        long i = (long)local * 256 + threadIdx.x;
        float4 v = reinterpret_cast<const float4*>(in)[i];
        ushort4 o;
        o.x = f2bf(v.x); o.y = f2bf(v.y); o.z = f2bf(v.z); o.w = f2bf(v.w);
        reinterpret_cast<ushort4*>(out)[i] = o;
        return;
    }
    int t = id - 16384;
    int pj = t >> 8, local = t & 255;
    const float* in; u16* out;
    int Q, R, bx, by, bz;
    if (pj < 6) {
        switch (pj) {
            case 0:  in = Wq1; out = W1cat;           break;
            case 1:  in = Wk1; out = W1cat + 1048576; break;
            case 2:  in = Wv1; out = W1cat + 2097152; break;
            case 3:  in = Wq2; out = W1cat + 3145728; break;
            case 4:  in = Wk2; out = Wkv2t;           break;
            default: in = Wv2; out = Wkv2t + 1048576; break;
        }
        Q = 1024; R = 64; bx = 0; by = local & 15; bz = local >> 4;
    } else {
        in = (pj == 6) ? Wo1 : Wo2; out = (pj == 6) ? Wo1t : Wo2t;
        Q = 1024; R = 1024; bx = local & 15; by = local >> 4; bz = 0;
    }
    int r0 = bx * 64, q0 = by * 64;
    int tx = threadIdx.x & 63, ty = threadIdx.x >> 6;
    const float* inp = in + ((long)bz * Q + q0) * R + r0;
    #pragma unroll
    for (int i = 0; i < 64; i += 4)
        tile[ty + i][tx] = inp[(long)(ty + i) * R + tx];
    __syncthreads();
    u16* outp = out + ((long)bz * R + r0) * Q + q0;
    #pragma unroll
    for (int i = 0; i < 64; i += 4)
        outp[(long)(ty + i) * Q + tx] = f2bf(tile[tx][ty + i]);
}

// Merged V-transpose + 1/l scale for BOTH MHAs. grid (16,16,8): z<4 -> MHA1
// (in1/ld1/zs1, Vt slab 0, csum half 0), z>=4 -> MHA2. out[c][r]=in[r][c]/l.
__global__ __launch_bounds__(256) void tscale2_k(
    const u16* __restrict__ in1, long ld1, long zs1,
    const u16* __restrict__ in2, long ld2, long zs2,
    u16* __restrict__ Vt, const float* __restrict__ csum) {
    __shared__ u16 tile[64][66];
    int z = blockIdx.z;
    int m = z >> 2, zb = z & 3;
    const u16* in; long ld, zs;
    if (m) { in = in2; ld = ld2; zs = zs2; } else { in = in1; ld = ld1; zs = zs1; }
    const u16* inz = in + (long)zb * zs;
    u16* outz = Vt + (long)m * 4194304 + (long)zb * 1048576;
    const float* cs = csum + m * 65536 + (long)zb * 16384;
    int r0 = blockIdx.y * 64;
    int c0 = blockIdx.x * 64;
    int tx = threadIdx.x & 63, ty = threadIdx.x >> 6;
    #pragma unroll
    for (int i = 0; i < 64; i += 4)
        tile[ty + i][tx] = inz[(long)(r0 + ty + i) * ld + c0 + tx];
    __syncthreads();
    #pragma unroll
    for (int i = 0; i < 64; i += 4) {
        int orow = c0 + ty + i;
        float f = bf2f(tile[tx][ty + i]) / cs[(orow >> 6) * 1024 + r0 + tx];
        outz[(long)orow * 1024 + r0 + tx] = f2bf(f);
    }
}

// ---------------- legacy GEMM (l-pass merged, Wo full-K merged, KV2 128^2) ----------------
// MRG=1 (SWZ=0 path): blockIdx.z in [0,128); z>=64 switches to the second
// pointer set (A2/lda2/B2/ldb2/b_zout2/csum2) with z &= 63.
template<int BM, int BN, int BK, int WM, int WN, int OUT_BF16, int EPI, int SWZ, int KS, int MRG>
__global__ __launch_bounds__(256) void gemm_k(
    const u16* __restrict__ A, long lda, long a_zin, long a_zout,
    const u16* __restrict__ B, long ldb, long b_zin, long b_zout,
    void* __restrict__ Cv, long ldc, long c_zin, long c_zout,
    int zin, int K, float alpha, const float* __restrict__ bias,
    float* __restrict__ csum,
    const u16* __restrict__ A2, long lda2,
    const u16* __restrict__ B2, long ldb2, long b_zout2,
    float* __restrict__ csum2)
{
    static_assert(BK == 64, "staging assumes BK=64");
    constexpr int WTM = BM / WM;
    constexpr int WTN = BN / WN;
    constexpr int TM = WTM / 16;
    constexpr int TN = WTN / 16;
    __shared__ __align__(16) u16 smem[(BM + BN) * BK];
    u16* As = smem;
    u16* Bs = smem + BM * BK;

    int bx, by, z;
    if (SWZ == 4) {
        int L = blockIdx.x;
        if (KS > 1) { z = L >> 9; L &= 511; } else { z = 0; }
        by = (L & 7) * 4 + ((L >> 3) & 3);
        bx = L >> 5;
    } else {
        bx = blockIdx.x; by = blockIdx.y; z = blockIdx.z;
    }
    if (MRG) {
        int m2 = z >> 6; z &= 63;
        if (m2) { A = A2; lda = lda2; B = B2; ldb = ldb2; b_zout = b_zout2; csum = csum2; }
    }
    int zi = z % zin, zo = z / zin;
    A += (long)zi * a_zin + (long)zo * a_zout;
    B += (long)zi * b_zin + (long)zo * b_zout;
    long coff = (long)zi * c_zin + (long)zo * c_zout;

    int tid = threadIdx.x;
    int lane = tid & 63;
    int wave = tid >> 6;
    int wm = wave / WN, wn = wave % WN;
    long bm0 = (long)by * BM, bn0 = (long)bx * BN;

    f32x4 acc[TM][TN];
    #pragma unroll
    for (int i = 0; i < TM; ++i)
        #pragma unroll
        for (int j = 0; j < TN; ++j) {
            acc[i][j][0] = 0.f; acc[i][j][1] = 0.f;
            acc[i][j][2] = 0.f; acc[i][j][3] = 0.f;
        }

    int r16 = lane & 15;
    int quad = lane >> 4;
    int l8 = lane >> 3;                    // stripe row
    int gsw = ((lane & 7) ^ l8) * 8;       // swizzled global col (elements)

    constexpr int ASTR = BM / 8;
    constexpr int BSTR = BN / 8;

    for (int k0 = 0; k0 < K; k0 += BK) {
        #pragma unroll
        for (int s = wave; s < ASTR; s += 4)
            gl_lds16(&A[(bm0 + s * 8 + l8) * lda + k0 + gsw], &As[s * 512]);
        #pragma unroll
        for (int s = wave; s < BSTR; s += 4)
            gl_lds16(&B[(bn0 + s * 8 + l8) * ldb + k0 + gsw], &Bs[s * 512]);
        __syncthreads();
        #pragma unroll
        for (int kk = 0; kk < BK; kk += 32) {
            int cb = (kk >> 3) + quad;
            bf16x8 av[TM], bv[TN];
            #pragma unroll
            for (int i = 0; i < TM; ++i) {
                int r = wm * WTM + i * 16 + r16;
                av[i] = *reinterpret_cast<const bf16x8*>(&As[r * 64 + ((cb ^ (r & 7)) * 8)]);
            }
            #pragma unroll
            for (int j = 0; j < TN; ++j) {
                int r = wn * WTN + j * 16 + r16;
                bv[j] = *reinterpret_cast<const bf16x8*>(&Bs[r * 64 + ((cb ^ (r & 7)) * 8)]);
            }
            #pragma unroll
            for (int i = 0; i < TM; ++i)
                #pragma unroll
                for (int j = 0; j < TN; ++j)
                    acc[i][j] = __builtin_amdgcn_mfma_f32_16x16x32_bf16(av[i], bv[j], acc[i][j], 0, 0, 0);
        }
        __syncthreads();
    }

    int rb = quad * 4;

    if (EPI == 4) {
        // exp + column sums only; no C store. csum layout [z][1024].
        float csl[TN];
        #pragma unroll
        for (int j = 0; j < TN; ++j) csl[j] = 0.f;
        #pragma unroll
        for (int i = 0; i < TM; ++i)
            #pragma unroll
            for (int j = 0; j < TN; ++j)
                #pragma unroll
                for (int r = 0; r < 4; ++r)
                    csl[j] += __expf(acc[i][j][r] * alpha);
        #pragma unroll
        for (int j = 0; j < TN; ++j) {
            float cs = csl[j];
            cs += __shfl_xor(cs, 16, 64);
            cs += __shfl_xor(cs, 32, 64);
            if (quad == 0) {
                long col = bn0 + wn * WTN + j * 16 + r16;
                atomicAdd(&csum[((long)zo * zin + zi) * 1024 + col], cs);
            }
        }
        return;
    }

    // ---- LDS-staged store epilogue ----
    constexpr int EB = OUT_BF16 ? 2 : 4;
    constexpr int CH = 16 / EB;
    constexpr int STRIDE = BN + CH;
    constexpr int LDSB = (BM + BN) * BK * 2;
    constexpr int EPASS = (BM * STRIDE * EB > LDSB) ? 2 : 1;
    constexpr int RPP = BM / EPASS;
    static_assert(RPP * STRIDE * EB <= LDSB, "epilogue tile overflows LDS");
    static_assert(EPASS == 1 || (WM == 2 && WTM == RPP), "pass/wave row alignment");
    constexpr int CPR = BN / CH;
    constexpr int NCH = RPP * CPR / 256;
    static_assert(RPP * CPR % 256 == 0, "store mapping");

    float* Ef = reinterpret_cast<float*>(smem);
    char* Cb = reinterpret_cast<char*>(Cv);

    for (int pass = 0; pass < EPASS; ++pass) {
        int p0 = pass * RPP;
        __syncthreads();
        #pragma unroll
        for (int i = 0; i < TM; ++i) {
            #pragma unroll
            for (int j = 0; j < TN; ++j) {
                int lcol = wn * WTN + j * 16 + r16;
                float bsv = (EPI == 1 || EPI == 2) ? bias[bn0 + lcol] : 0.f;
                #pragma unroll
                for (int r = 0; r < 4; ++r) {
                    int lrow = wm * WTM + i * 16 + rb + r;
                    if ((unsigned)(lrow - p0) < (unsigned)RPP) {
                        float v = acc[i][j][r] * alpha;
                        if (EPI == 1) { v += bsv; v = v > 0.f ? v : 0.f; }
                        else if (EPI == 2) { v += bsv; }
                        if (OUT_BF16) smem[(lrow - p0) * STRIDE + lcol] = f2bf(v);
                        else          Ef[(lrow - p0) * STRIDE + lcol] = v;
                    }
                }
            }
        }
        __syncthreads();
        #pragma unroll
        for (int c = 0; c < NCH; ++c) {
            int cid = tid + c * 256;
            int row = cid / CPR, ch = cid - row * CPR;
            int4 v = *reinterpret_cast<const int4*>(
                reinterpret_cast<const char*>(smem) + (row * STRIDE + ch * CH) * EB);
            long gidx = coff + (bm0 + p0 + row) * ldc + bn0 + ch * CH;
            *reinterpret_cast<int4*>(Cb + gidx * EB) = v;
        }
    }
}

// ---------------- 8-phase 256x256 GEMM (R1 schedule, frozen) ----------------
// Per K-tile t, 4 phases = (ih,jh) quadrants x K=64, 2 raw barriers each:
//   ph1: read av(ih0),bv(jh0) | stage (t+1).A-half1 | vmcnt(10)
//   ph2: read bv(jh1)         | stage (t+2).A-half0 | vmcnt(10)
//   ph3: read av(ih1)         | stage (t+2).B-half0 |
//   ph4:                      | stage (t+2).B-half1 | vmcnt(10)
// SPLITN=1: first NT/2 bx-tiles -> Cv (no epi); second NT/2 -> Cv2 with
// bias+relu, column base rebased (QKV1 + FFN-in fused dispatch).

__device__ __forceinline__ void bar_raw() {
    asm volatile("" ::: "memory");
    __builtin_amdgcn_s_barrier();
    asm volatile("" ::: "memory");
}

template<int N> __device__ __forceinline__ void vmw() {
    if constexpr (N == 10) asm volatile("s_waitcnt vmcnt(10)" ::: "memory");
    else if constexpr (N == 8) asm volatile("s_waitcnt vmcnt(8)" ::: "memory");
    else if constexpr (N == 4) asm volatile("s_waitcnt vmcnt(4)" ::: "memory");
    else if constexpr (N == 2) asm volatile("s_waitcnt vmcnt(2)" ::: "memory");
    else if constexpr (N == 0) asm volatile("s_waitcnt vmcnt(0)" ::: "memory");
}

// stage one half-tile (16 stripes of 8 rows x 64 cols) = 2 gl_lds per thread
__device__ __forceinline__ void stage_half(const u16* __restrict__ base, long ld, int kt,
                                           u16* __restrict__ lds, int half, int wave) {
    const u16* src = base + (long)kt * 64;
    #pragma unroll
    for (int u = 0; u < 2; ++u) {
        int s = half * 16 + u * 8 + wave;
        gl_lds16(src + (long)(s * 8) * ld, lds + s * 512);
    }
}

template<int IH>
__device__ __forceinline__ void read_a8(bf16x8 (&av)[4][2], const u16* __restrict__ As,
                                        int wm, int r16, int quad) {
    #pragma unroll
    for (int ii = 0; ii < 4; ++ii) {
        int r = IH * 128 + wm * 64 + ii * 16 + r16;
        #pragma unroll
        for (int kx = 0; kx < 2; ++kx)
            av[ii][kx] = *reinterpret_cast<const bf16x8*>(&As[r * 64 + (((kx * 4 + quad) ^ (r & 7)) * 8)]);
    }
}

template<int JH>
__device__ __forceinline__ void read_b8(bf16x8 (&bv)[2][2], const u16* __restrict__ Bs,
                                        int wn, int r16, int quad) {
    #pragma unroll
    for (int j = 0; j < 2; ++j) {
        int r = JH * 128 + wn * 32 + j * 16 + r16;
        #pragma unroll
        for (int kx = 0; kx < 2; ++kx)
            bv[j][kx] = *reinterpret_cast<const bf16x8*>(&Bs[r * 64 + (((kx * 4 + quad) ^ (r & 7)) * 8)]);
    }
}

template<int IH, int JH>
__device__ __forceinline__ void mfma_q(f32x4 (&acc)[2][4][2][2],
                                       const bf16x8 (&av)[4][2], const bf16x8 (&bv)[2][2]) {
    #pragma unroll
    for (int kx = 0; kx < 2; ++kx)
        #pragma unroll
        for (int ii = 0; ii < 4; ++ii)
            #pragma unroll
            for (int j = 0; j < 2; ++j)
                acc[IH][ii][JH][j] = __builtin_amdgcn_mfma_f32_16x16x32_bf16(
                    av[ii][kx], bv[j][kx], acc[IH][ii][JH][j], 0, 0, 0);
}

// MODE 0: steady; 1: t=T-2 (only (t+1).A1 staged); 2: t=T-1 (no staging)
template<int MODE>
__device__ __forceinline__ void tile_iter(
    int t, f32x4 (&acc)[2][4][2][2], bf16x8 (&av)[4][2], bf16x8 (&bvh)[2][2][2],
    u16* __restrict__ smem, const u16* __restrict__ Ab, long lda,
    const u16* __restrict__ Bb, long ldb, int wave, int wm, int wn, int r16, int quad)
{
    u16* As0 = smem + (t & 1) * 32768;          // buf for tile t (also target of t+2 stages)
    u16* Bs0 = As0 + 16384;
    u16* As1 = smem + ((t + 1) & 1) * 32768;    // buf for tile t+1
    // ---- ph1 (ih0,jh0)
    read_a8<0>(av, As0, wm, r16, quad);
    read_b8<0>(bvh[0], Bs0, wn, r16, quad);
    if (MODE < 2) stage_half(Ab, lda, t + 1, As1, 1, wave);
    vmw<MODE == 0 ? 10 : (MODE == 1 ? 10 : 2)>();
    bar_raw(); __builtin_amdgcn_sched_barrier(0);
    __builtin_amdgcn_s_setprio(1);
    mfma_q<0, 0>(acc, av, bvh[0]);
    __builtin_amdgcn_s_setprio(0);
    __builtin_amdgcn_sched_barrier(0);
    bar_raw();
    // ---- ph2 (ih0,jh1)
    read_b8<1>(bvh[1], Bs0, wn, r16, quad);
    if (MODE == 0) stage_half(Ab, lda, t + 2, As0, 0, wave);
    vmw<MODE == 0 ? 10 : (MODE == 1 ? 8 : 0)>();
    bar_raw(); __builtin_amdgcn_sched_barrier(0);
    __builtin_amdgcn_s_setprio(1);
    mfma_q<0, 1>(acc, av, bvh[1]);
    __builtin_amdgcn_s_setprio(0);
    __builtin_amdgcn_sched_barrier(0);
    bar_raw();
    // ---- ph3 (ih1,jh0)
    read_a8<1>(av, As0, wm, r16, quad);
    if (MODE == 0) stage_half(Bb, ldb, t + 2, Bs0, 0, wave);
    bar_raw(); __builtin_amdgcn_sched_barrier(0);
    __builtin_amdgcn_s_setprio(1);
    mfma_q<1, 0>(acc, av, bvh[0]);
    __builtin_amdgcn_s_setprio(0);
    __builtin_amdgcn_sched_barrier(0);
    bar_raw();
    // ---- ph4 (ih1,jh1)
    if (MODE == 0) stage_half(Bb, ldb, t + 2, Bs0, 1, wave);
    if (MODE < 2) vmw<MODE == 0 ? 10 : 4>();
    bar_raw(); __builtin_amdgcn_sched_barrier(0);
    __builtin_amdgcn_s_setprio(1);
    mfma_q<1, 1>(acc, av, bvh[1]);
    __builtin_amdgcn_s_setprio(0);
    __builtin_amdgcn_sched_barrier(0);
    bar_raw();
}

// grid = 16*NT*KS blocks of 512. EPI: 0 none, 1 bias+relu. KS>1: z picks K-chunk,
// output slab z: z<2 -> Cv + (z&1)*czs, z>=2 -> Cv2 + (z&1)*czs (fp32).
// SPLITN=1 (KS must be 1): bx>=NT/2 -> Cv2, bias+relu, columns rebased.
template<int NT, int KS, int EPI, int OUT_BF16, int SPLITN>
__global__ __launch_bounds__(512, 2) void gemm8_k(
    const u16* __restrict__ A, long lda,
    const u16* __restrict__ B, long ldb,
    void* __restrict__ Cv, void* __restrict__ Cv2, long ldc,
    int K, float alpha, const float* __restrict__ bias, long czs)
{
    __shared__ __align__(16) u16 smem[65536];   // 128 KiB

    int L = blockIdx.x;
    int z = 0;
    if (KS > 1) { z = L / (16 * NT); L -= z * 16 * NT; }
    int by = (L & 7) * 2 + ((L >> 3) & 1);      // XCD-contiguous M-rows
    int bx = L >> 4;
    if (KS > 1) { A += (long)z * K; B += (long)z * K; }

    int tid = threadIdx.x;
    int lane = tid & 63, wave = tid >> 6;
    int wm = wave >> 2, wn = wave & 3;
    int r16 = lane & 15, quad = lane >> 4, l8 = lane >> 3;
    int gsw = ((lane & 7) ^ l8) * 8;
    long bm0 = (long)by * 256, bn0 = (long)bx * 256;
    const u16* Ab = A + (bm0 + l8) * lda + gsw;
    const u16* Bb = B + (bn0 + l8) * ldb + gsw;

    f32x4 acc[2][4][2][2];
    #pragma unroll
    for (int a0 = 0; a0 < 2; ++a0)
        #pragma unroll
        for (int a1 = 0; a1 < 4; ++a1)
            #pragma unroll
            for (int a2 = 0; a2 < 2; ++a2)
                #pragma unroll
                for (int a3 = 0; a3 < 2; ++a3) {
                    acc[a0][a1][a2][a3][0] = 0.f; acc[a0][a1][a2][a3][1] = 0.f;
                    acc[a0][a1][a2][a3][2] = 0.f; acc[a0][a1][a2][a3][3] = 0.f;
                }
    bf16x8 av[4][2];
    bf16x8 bvh[2][2][2];

    int T = K >> 6;   // >= 3

    // prologue issue stream: [0.A0, 0.B0, 0.B1, 0.A1, 1.A0, 1.B0, 1.B1]
    stage_half(Ab, lda, 0, smem,         0, wave);
    stage_half(Bb, ldb, 0, smem + 16384, 0, wave);
    stage_half(Bb, ldb, 0, smem + 16384, 1, wave);
    stage_half(Ab, lda, 0, smem,         1, wave);
    stage_half(Ab, lda, 1, smem + 32768, 0, wave);
    stage_half(Bb, ldb, 1, smem + 49152, 0, wave);
    stage_half(Bb, ldb, 1, smem + 49152, 1, wave);
    vmw<10>();          // 14 issued -> oldest 4 (0.A0,0.B0) landed
    bar_raw();

    for (int t = 0; t < T - 2; ++t)
        tile_iter<0>(t, acc, av, bvh, smem, Ab, lda, Bb, ldb, wave, wm, wn, r16, quad);
    tile_iter<1>(T - 2, acc, av, bvh, smem, Ab, lda, Bb, ldb, wave, wm, wn, r16, quad);
    tile_iter<2>(T - 1, acc, av, bvh, smem, Ab, lda, Bb, ldb, wave, wm, wn, r16, quad);

    // ---- epilogue: stage to LDS (row-XOR-swizzled), coalesced int4 stores
    constexpr int EB = OUT_BF16 ? 2 : 4;
    constexpr int EPASS = OUT_BF16 ? 1 : 2;   // f32 = 2 passes of 128 rows (ih=pass)
    bool sec = SPLITN && (bx >= NT / 2);
    char* Cb;
    long bnc = bn0;
    if (SPLITN) {
        Cb = reinterpret_cast<char*>(sec ? Cv2 : Cv);
        if (sec) bnc = bn0 - (long)(NT / 2) * 256;
    } else {
        Cb = reinterpret_cast<char*>((KS > 1 && z >= 2) ? Cv2 : Cv);
        if (KS > 1) Cb += (long)(z & 1) * czs * EB;
    }
    bool do_bias = (EPI == 1) || sec;
    float bsv[2][2];
    if (do_bias) {
        #pragma unroll
        for (int jh = 0; jh < 2; ++jh)
            #pragma unroll
            for (int j = 0; j < 2; ++j)
                bsv[jh][j] = bias[bnc + jh * 128 + wn * 32 + j * 16 + r16];
    }
    u16* sm16 = smem;
    float* smf = reinterpret_cast<float*>(smem);
    #pragma unroll
    for (int pass = 0; pass < EPASS; ++pass) {
        bar_raw();
        #pragma unroll
        for (int ih = 0; ih < 2; ++ih) {
            if (EPASS == 2 && ih != pass) continue;
            #pragma unroll
            for (int ii = 0; ii < 4; ++ii)
                #pragma unroll
                for (int jh = 0; jh < 2; ++jh)
                    #pragma unroll
                    for (int j = 0; j < 2; ++j)
                        #pragma unroll
                        for (int r = 0; r < 4; ++r) {
                            int lrow = (EPASS == 2 ? 0 : ih * 128) + wm * 64 + ii * 16 + quad * 4 + r;
                            int lcol = jh * 128 + wn * 32 + j * 16 + r16;
                            float v = acc[ih][ii][jh][j][r] * alpha;
                            if (do_bias) { v += bsv[jh][j]; v = v > 0.f ? v : 0.f; }
                            int scol = lcol ^ ((lrow & 7) * 8);
                            if (OUT_BF16) sm16[lrow * 256 + scol] = f2bf(v);
                            else          smf[lrow * 256 + scol] = v;
                        }
        }
        bar_raw();
        constexpr int CH = 16 / EB;
        constexpr int CPR = 256 / CH;
        constexpr int NCH = (OUT_BF16 ? 256 : 128) * CPR / 512;
        #pragma unroll
        for (int c = 0; c < NCH; ++c) {
            int cid = tid + c * 512;
            int row = cid / CPR, ch = cid - row * CPR;
            int col = (ch * CH) ^ ((row & 7) * 8);
            int4 v = *reinterpret_cast<const int4*>(
                reinterpret_cast<const char*>(smem) + ((long)row * 256 + col) * EB);
            long grow = bm0 + pass * 128 + row;
            *reinterpret_cast<int4*>(Cb + (grow * ldc + bnc + ch * CH) * EB) = v;
        }
    }
}

// ---------------- fused attention PV (both MHAs in one dispatch) ----------------
// MRG=1: grid 1024; L>=512 switches to second pointer set (MHA2).
// Per block: out[128 t][64 v] = sum_s exp(0.125*Q K^T) * Vt_scaled.
// K/V double-buffered; stage(c+1) issued BEFORE chunk c compute; counted
// vmcnt(4) + barrier; mid-chunk lgkmcnt(0)+barrier (Es rows filled by both
// waves of the wm band).
template<int MRG>
__global__ __launch_bounds__(256) void attn_pv_k(
    const u16* __restrict__ Qg, long ldq, long qbz,
    const u16* __restrict__ Kg, long ldk, long kbz,
    const u16* __restrict__ Vg, u16* __restrict__ outg,
    const u16* __restrict__ Qg2,
    const u16* __restrict__ Kg2, long ldk2, long kbz2,
    const u16* __restrict__ Vg2, u16* __restrict__ outg2)
{
    __shared__ __align__(16) u16 Qs[128 * 64];
    __shared__ __align__(16) u16 Ks[2][64 * 64];
    __shared__ __align__(16) u16 Vs[2][64 * 64];
    __shared__ __align__(16) u16 Es[128 * 64];

    int L = blockIdx.x;
    if (MRG) {
        int m = L >> 9; L &= 511;
        if (m) { Qg = Qg2; Kg = Kg2; ldk = ldk2; kbz = kbz2; Vg = Vg2; outg = outg2; }
    }
    int h  = (L & 7) * 2 + ((L >> 3) & 1);
    int tb = (L >> 4) & 7;
    int b  = L >> 7;

    const u16* Q  = Qg + (long)b * qbz + h * 64;
    const u16* Kp = Kg + (long)b * kbz + h * 64;
    const u16* Vp = Vg + (long)b * 1048576 + (long)h * 65536;
    u16* outp = outg + (long)b * 1048576 + (long)tb * 131072 + h * 64;

    int tid = threadIdx.x, lane = tid & 63, wave = tid >> 6;
    int wm = wave >> 1, wn = wave & 1;
    int r16 = lane & 15, quad = lane >> 4, l8 = lane >> 3;
    int gsw = ((lane & 7) ^ l8) * 8;
    long t0 = (long)tb * 128;

    // prologue: Q (4 loads/thread) + K/V chunk 0 (4 loads/thread)
    #pragma unroll
    for (int s = wave; s < 16; s += 4)
        gl_lds16(&Q[(t0 + s * 8 + l8) * ldq + gsw], &Qs[s * 512]);
    #pragma unroll
    for (int s = wave; s < 8; s += 4) {
        gl_lds16(&Kp[(long)(s * 8 + l8) * ldk + gsw], &Ks[0][s * 512]);
        gl_lds16(&Vp[(long)(s * 8 + l8) * 1024 + gsw], &Vs[0][s * 512]);
    }

    f32x4 acc[4][2];
    #pragma unroll
    for (int i = 0; i < 4; ++i)
        #pragma unroll
        for (int j = 0; j < 2; ++j) {
            acc[i][j][0] = 0.f; acc[i][j][1] = 0.f;
            acc[i][j][2] = 0.f; acc[i][j][3] = 0.f;
        }

    for (int sc = 0; sc < 16; ++sc) {
        const u16* Ksc = Ks[sc & 1];
        const u16* Vsc = Vs[sc & 1];
        if (sc < 15) {
            int nc = sc + 1;
            u16* Kn = Ks[nc & 1];
            u16* Vn = Vs[nc & 1];
            #pragma unroll
            for (int s = wave; s < 8; s += 4) {
                gl_lds16(&Kp[(long)(nc * 64 + s * 8 + l8) * ldk + gsw], &Kn[s * 512]);
                gl_lds16(&Vp[(long)(s * 8 + l8) * 1024 + nc * 64 + gsw], &Vn[s * 512]);
            }
            asm volatile("s_waitcnt vmcnt(4)" ::: "memory");   // chunk sc (and Q) landed
        } else {
            asm volatile("s_waitcnt vmcnt(0)" ::: "memory");   // last chunk landed
        }
        bar_raw();                            // all waves' chunk-sc loads visible

        // E-chunk = Q x K^T (128x64, contraction 64)
        f32x4 e[4][2];
        #pragma unroll
        for (int i = 0; i < 4; ++i)
            #pragma unroll
            for (int j = 0; j < 2; ++j) {
                e[i][j][0] = 0.f; e[i][j][1] = 0.f;
                e[i][j][2] = 0.f; e[i][j][3] = 0.f;
            }
        #pragma unroll
        for (int kk = 0; kk < 64; kk += 32) {
            int cb = (kk >> 3) + quad;
            bf16x8 av[4], bv[2];
            #pragma unroll
            for (int i = 0; i < 4; ++i) {
                int r = wm * 64 + i * 16 + r16;
                av[i] = *reinterpret_cast<const bf16x8*>(&Qs[r * 64 + ((cb ^ (r & 7)) * 8)]);
            }
            #pragma unroll
            for (int j = 0; j < 2; ++j) {
                int r = wn * 32 + j * 16 + r16;
                bv[j] = *reinterpret_cast<const bf16x8*>(&Ksc[r * 64 + ((cb ^ (r & 7)) * 8)]);
            }
            #pragma unroll
            for (int i = 0; i < 4; ++i)
                #pragma unroll
                for (int j = 0; j < 2; ++j)
                    e[i][j] = __builtin_amdgcn_mfma_f32_16x16x32_bf16(av[i], bv[j], e[i][j], 0, 0, 0);
        }
        // exp + write to Es (C-frag: row=quad*4+r, col=r16; XOR-swizzled rows)
        #pragma unroll
        for (int i = 0; i < 4; ++i)
            #pragma unroll
            for (int j = 0; j < 2; ++j) {
                int lcol = wn * 32 + j * 16 + r16;
                #pragma unroll
                for (int r = 0; r < 4; ++r) {
                    int lrow = wm * 64 + i * 16 + quad * 4 + r;
                    float v = __expf(e[i][j][r] * 0.125f);
                    Es[lrow * 64 + (((lcol >> 3) ^ (lrow & 7)) * 8) + (lcol & 7)] = f2bf(v);
                }
            }
        asm volatile("s_waitcnt lgkmcnt(0)" ::: "memory");
        bar_raw();

        // acc += E-chunk x Vs^T (contraction over s-chunk)
        #pragma unroll
        for (int kk = 0; kk < 64; kk += 32) {
            int cb = (kk >> 3) + quad;
            bf16x8 av[4], bv[2];
            #pragma unroll
            for (int i = 0; i < 4; ++i) {
                int r = wm * 64 + i * 16 + r16;
                av[i] = *reinterpret_cast<const bf16x8*>(&Es[r * 64 + ((cb ^ (r & 7)) * 8)]);
            }
            #pragma unroll
            for (int j = 0; j < 2; ++j) {
                int r = wn * 32 + j * 16 + r16;
                bv[j] = *reinterpret_cast<const bf16x8*>(&Vsc[r * 64 + ((cb ^ (r & 7)) * 8)]);
            }
            #pragma unroll
            for (int i = 0; i < 4; ++i)
                #pragma unroll
                for (int j = 0; j < 2; ++j)
                    acc[i][j] = __builtin_amdgcn_mfma_f32_16x16x32_bf16(av[i], bv[j], acc[i][j], 0, 0, 0);
        }
        bar_raw();                 // all waves done reading buf[sc&1] K/V + Es
    }

    #pragma unroll
    for (int i = 0; i < 4; ++i)
        #pragma unroll
        for (int j = 0; j < 2; ++j) {
            int lcol = wn * 32 + j * 16 + r16;
            #pragma unroll
            for (int r = 0; r < 4; ++r) {
                int lrow = wm * 64 + i * 16 + quad * 4 + r;
                outp[(long)lrow * 1024 + lcol] = f2bf(acc[i][j][r]);
            }
        }
}

// ---------------- fused sub_norm chain: all 3 layers in one dispatch ----------------
// t1 = sn(yf + g0); t2 = sn(t1 + g1); out = sn(t2 + f01[0]+f01[s]+f23[0]+f23[s] + b).
// sm[8] reuse is race-free: every slot's readers finish before the barrier that
// precedes its overwrite (reads sm[0..3] precede sync2; reads sm[4..7] precede
// the next step's sync1).
__global__ __launch_bounds__(256) void addsn_fuse_k(
    const float* __restrict__ g0, const float* __restrict__ g1,
    const float* __restrict__ f01, const float* __restrict__ f23, long fstride,
    const float* __restrict__ yf, const float* __restrict__ b_out,
    float* __restrict__ out)
{
    __shared__ float sm[8];
    long row = blockIdx.x;
    int tid = threadIdx.x;
    int lane = tid & 63, w = tid >> 6;

    auto subnorm = [&](float4& x) {
        float s = x.x + x.y + x.z + x.w;
        for (int o = 32; o > 0; o >>= 1) s += __shfl_down(s, o, 64);
        if (lane == 0) sm[w] = s;
        __syncthreads();
        float mean = (sm[0] + sm[1] + sm[2] + sm[3]) * (1.f / 1024.f);
        float d0 = x.x - mean, d1 = x.y - mean, d2 = x.z - mean, d3 = x.w - mean;
        float q = d0 * d0 + d1 * d1 + d2 * d2 + d3 * d3;
        for (int o = 32; o > 0; o >>= 1) q += __shfl_down(q, o, 64);
        if (lane == 0) sm[w + 4] = q;
        __syncthreads();
        float sd = sqrtf((sm[4] + sm[5] + sm[6] + sm[7]) * (1.f / 1023.f));
        x.x = d0 - sd; x.y = d1 - sd; x.z = d2 - sd; x.w = d3 - sd;
    };

    float4 x = reinterpret_cast<const float4*>(yf + row * 1024)[tid];
    float4 a = reinterpret_cast<const float4*>(g0 + row * 1024)[tid];
    x.x += a.x; x.y += a.y; x.z += a.z; x.w += a.w;
    subnorm(x);                                         // t1 = out1

    a = reinterpret_cast<const float4*>(g1 + row * 1024)[tid];
    x.x += a.x; x.y += a.y; x.z += a.z; x.w += a.w;
    subnorm(x);                                         // t2 = out2

    float4 f0 = reinterpret_cast<const float4*>(f01 + row * 1024)[tid];
    float4 f1 = reinterpret_cast<const float4*>(f01 + fstride + row * 1024)[tid];
    float4 f2 = reinterpret_cast<const float4*>(f23 + row * 1024)[tid];
    float4 f3 = reinterpret_cast<const float4*>(f23 + fstride + row * 1024)[tid];
    float4 bb = reinterpret_cast<const float4*>(b_out)[tid];
    x.x += f0.x + f1.x + f2.x + f3.x + bb.x;
    x.y += f0.y + f1.y + f2.y + f3.y + bb.y;
    x.z += f0.z + f1.z + f2.z + f3.z + bb.z;
    x.w += f0.w + f1.w + f2.w + f3.w + bb.w;
    subnorm(x);                                         // final

    reinterpret_cast<float4*>(out + row * 1024)[tid] = x;
}

// ---------------- launcher ----------------

extern "C" void kernel_launch(void* const* d_in, const int* in_sizes, int n_in,
                              void* d_out, int out_size, void* d_ws, size_t ws_size,
                              hipStream_t stream) {
    (void)in_sizes; (void)n_in; (void)out_size; (void)ws_size;
    const float* xf   = (const float*)d_in[0];
    const float* yf   = (const float*)d_in[1];
    const float* Wq1  = (const float*)d_in[2];
    const float* Wk1  = (const float*)d_in[3];
    const float* Wv1  = (const float*)d_in[4];
    const float* Wo1  = (const float*)d_in[5];
    const float* Wq2  = (const float*)d_in[6];
    const float* Wk2  = (const float*)d_in[7];
    const float* Wv2  = (const float*)d_in[8];
    const float* Wo2  = (const float*)d_in[9];
    const float* W_in = (const float*)d_in[10];
    const float* b_in = (const float*)d_in[11];
    const float* W_out= (const float*)d_in[12];
    const float* b_out= (const float*)d_in[13];

    // workspace layout (176 MB with aliases; lifetimes in header comment)
    char* p = (char*)d_ws;
    auto alloc = [&](size_t bytes) { char* r = p; p += bytes; return r; };
    u16*   yb    = (u16*)alloc(8388608);    // dead after SPLITN
    u16*   xb    = (u16*)alloc(8388608);    // dead after KV2 gemm
    u16*   W1cat = (u16*)alloc(8388608);    // dead after SPLITN
    u16*   Winb  = (u16*)alloc(8388608);    // dead after SPLITN (contiguous with W1cat)
    u16*   Wkv2t = (u16*)alloc(4194304);
    u16*   Wo1t  = (u16*)alloc(2097152);
    u16*   Wo2t  = (u16*)alloc(2097152);    // contiguous after Wo1t (b_zout=1048576)
    u16*   Woutb = (u16*)alloc(8388608);
    u16*   QKV   = (u16*)alloc(33554432);   // [Q1|K1|V1|Q2]; FFN-out fp32 slabs 0,1 after attn
    u16*   KV2   = (u16*)alloc(16777216);   // [K2|V2]
    u16*   Pb    = (u16*)alloc(33554432);   // FFN hidden
    u16*   part  = (u16*)alloc(16777216);   // attn partials [2 mha][4096][1024] bf16
    float* gout  = (float*)alloc(33554432); // Wo fp32 outputs, 2 slabs of 16 MB
    // aliases:
    u16*   Vt    = yb;                      // [2 mha][1024 hv][1024 s] (16 MB over yb+xb)
    float* csum  = gout;                    // [2 mha][4][16][1024] (512 KB, dead before Wo)
    float* ffnC2 = (float*)yb;              // FFN-out slabs 2,3 (32 MB over yb..Winb; Vt dead)

    // 1. all converts + weight packs + csum zero
    mega_pack_k<<<18560, 256, 0, stream>>>(
        yf, yb, xf, xb, W_in, Winb, W_out, Woutb,
        Wq1, Wk1, Wv1, Wq2, W1cat, Wk2, Wv2, Wkv2t,
        Wo1, Wo1t, Wo2, Wo2t, csum);

    // 2. QKV1+Q2 AND FFN-in in one dispatch (A=yb; B=[W1cat|Winb] contiguous)
    gemm8_k<32,1,0,1,1><<<512, 512, 0, stream>>>(
        yb, 1024L, W1cat, 1024L, (void*)QKV, (void*)Pb, 4096L, 1024, 1.0f, b_in, 0L);

    // 3. K2/V2 from x, N=2048 — legacy 128^2 tiles, grid (16,32)=512 blocks
    //    (full machine; the gemm8 grid-128 version left half the CUs idle)
    gemm_k<128,128,64,2,2,1,0,0,1,0><<<dim3(16, 32, 1), 256, 0, stream>>>(
        xb, 1024L, 0L, 0L, Wkv2t, 1024L, 0L, 0L,
        (void*)KV2, 2048L, 0L, 0L, 1, 1024, 1.0f, nullptr, nullptr,
        nullptr, 0L, nullptr, 0L, 0L, nullptr);

    // 4. l-pass BOTH MHAs: grid (8,8,128); z<64 MHA1 (Q1 x K1), z>=64 MHA2
    //    (Q2 x K2). zin=16: zi=h (stride 64), zo=b.
    gemm_k<128,128,64,2,2,1,4,0,1,1><<<dim3(8, 8, 128), 256, 0, stream>>>(
        QKV, 4096L, 64L, 4194304L,            // A1 = Q1
        QKV + 1024, 4096L, 64L, 4194304L,     // B1 = K1
        (void*)Pb, 1024L, 0L, 0L, 16, 64, 0.125f, nullptr, csum,
        QKV + 3072, 4096L,                    // A2 = Q2
        KV2, 2048L, 2097152L,                 // B2 = K2
        csum + 65536);

    // 5. V-transpose + 1/l scale, both MHAs (Vt slabs 0,1 = dead yb/xb region)
    tscale2_k<<<dim3(16, 16, 8), 256, 0, stream>>>(
        QKV + 2048, 4096L, 4194304L,          // V1
        KV2 + 1024, 2048L, 2097152L,          // V2
        Vt, csum);

    // 6. attention PV, both MHAs (part slabs 0,1)
    attn_pv_k<1><<<1024, 256, 0, stream>>>(
        QKV, 4096L, 4194304L, QKV + 1024, 4096L, 4194304L, Vt, part,
        QKV + 3072, KV2, 2048L, 2097152L, Vt + 4194304, part + 4194304);

    // 7. Wo both MHAs, full-K: grid 2*512. z: A += z*4194304 (part slab),
    //    B += z*1048576 (Wo1t->Wo2t), C += z*4194304 floats (gout slab).
    gemm_k<128,64,64,2,2,0,0,4,2,0><<<1024, 256, 0, stream>>>(
        part, 1024L, 0L, 4194304L, Wo1t, 1024L, 0L, 1048576L,
        (void*)gout, 1024L, 0L, 4194304L, 1, 1024, 1.0f, nullptr, nullptr,
        nullptr, 0L, nullptr, 0L, 0L, nullptr);

    // 8. FFN-out: split-K 4; slabs 0,1 -> QKV (dead), slabs 2,3 -> yb region
    //    (dead; Vt dead after step 6). gout holds live Wo results - untouched.
    gemm8_k<4,4,0,0,0><<<256, 512, 0, stream>>>(
        Pb, 4096L, Woutb, 4096L, (void*)QKV, (void*)ffnC2, 1024L, 1024, 1.0f, nullptr, 4194304L);

    // 9. fused sub_norm chain (replaces 3 addsn dispatches)
    addsn_fuse_k<<<4096, 256, 0, stream>>>(
        gout, gout + 4194304, (const float*)QKV, ffnC2, 4194304L,
        yf, b_out, (float*)d_out);
}

// Round 11
// 448.822 us; speedup vs baseline: 1.3548x; 1.0487x over previous
//
#include <hip/hip_runtime.h>

// DecoderStack: B=4,T=1024,D=1024,H=16,DK=DV=64,FF=4096
// Softmax over QUERY axis: l_s = sum_t exp(S) via store-free l-pass (EPI=4),
// 1/l_s folded into the V-transpose, then attn_pv_k recomputes E per tile in
// LDS and multiplies by V — E never touches HBM.
// sub_norm(o) = o - mean - std (ddof=1).
// gemm8_k: R1 schedule (best measured), frozen.
// R11 = R10 resubmitted unchanged (R10 bench was an infra double-failure, no
// pytest verdict; swapped-QK audit clean — see session journal):
// attn_pv QK computes S^T = mfma(K, Q). C-fragment holds 4 CONSECUTIVE s per
// thread (row=quad*4+rr = s, col=r16 = t), so the Es spill is 8x
// ds_write_b64 (ushort4) instead of 32x ds_write_b16 per thread per chunk.
// Write swizzle matches PV's read swizzle: Es[t*64 + ((g^(t&7))*8) + (s&7)],
// g=s>>3. PV/staging/barriers unchanged.

typedef unsigned short u16;
typedef __bf16 bf16x8 __attribute__((ext_vector_type(8)));
typedef float f32x4 __attribute__((ext_vector_type(4)));

__device__ __forceinline__ u16 f2bf(float f) {
    unsigned int u = __float_as_uint(f);
    u += 0x7fffu + ((u >> 16) & 1u);   // RNE; inputs are finite
    return (u16)(u >> 16);
}
__device__ __forceinline__ float bf2f(u16 b) {
    return __uint_as_float(((unsigned int)b) << 16);
}

typedef __attribute__((address_space(1))) const void* as1cv;
typedef __attribute__((address_space(3))) void* as3v;
__device__ __forceinline__ void gl_lds16(const void* g, void* l) {
    __builtin_amdgcn_global_load_lds((as1cv)g, (as3v)l, 16, 0, 0);
}

// ---------------- fused converts + packs + csum-zero: ONE dispatch ----------------
// Blocks 0..16383: float4->bf16x4 converts (job = id>>12: yf,xf,W_in,W_out).
// Blocks 16384..18431: pack_perm jobs (8 x 256 blocks).
// Blocks 18432..18559: zero csum[2] (131072 floats).
__global__ __launch_bounds__(256) void mega_pack_k(
    const float* __restrict__ yf, u16* __restrict__ yb,
    const float* __restrict__ xf, u16* __restrict__ xb,
    const float* __restrict__ W_in, u16* __restrict__ Winb,
    const float* __restrict__ W_out, u16* __restrict__ Woutb,
    const float* __restrict__ Wq1, const float* __restrict__ Wk1,
    const float* __restrict__ Wv1, const float* __restrict__ Wq2,
    u16* __restrict__ W1cat,
    const float* __restrict__ Wk2, const float* __restrict__ Wv2,
    u16* __restrict__ Wkv2t,
    const float* __restrict__ Wo1, u16* __restrict__ Wo1t,
    const float* __restrict__ Wo2, u16* __restrict__ Wo2t,
    float* __restrict__ csumz)
{
    __shared__ float tile[64][65];
    int id = blockIdx.x;
    if (id >= 18432) {
        long i = (long)(id - 18432) * 256 + threadIdx.x;
        float4 zz; zz.x = 0.f; zz.y = 0.f; zz.z = 0.f; zz.w = 0.f;
        reinterpret_cast<float4*>(csumz)[i] = zz;
        return;
    }
    if (id < 16384) {
        int j = id >> 12, local = id & 4095;
        const float* in; u16* out;
        switch (j) {
            case 0:  in = yf;    out = yb;    break;
            case 1:  in = xf;    out = xb;    break;
            case 2:  in = W_in;  out = Winb;  break;
            default: in = W_out; out = Woutb; break;
        }
        long i = (long)local * 256 + threadIdx.x;
        float4 v = reinterpret_cast<const float4*>(in)[i];
        ushort4 o;
        o.x = f2bf(v.x); o.y = f2bf(v.y); o.z = f2bf(v.z); o.w = f2bf(v.w);
        reinterpret_cast<ushort4*>(out)[i] = o;
        return;
    }
    int t = id - 16384;
    int pj = t >> 8, local = t & 255;
    const float* in; u16* out;
    int Q, R, bx, by, bz;
    if (pj < 6) {
        switch (pj) {
            case 0:  in = Wq1; out = W1cat;           break;
            case 1:  in = Wk1; out = W1cat + 1048576; break;
            case 2:  in = Wv1; out = W1cat + 2097152; break;
            case 3:  in = Wq2; out = W1cat + 3145728; break;
            case 4:  in = Wk2; out = Wkv2t;           break;
            default: in = Wv2; out = Wkv2t + 1048576; break;
        }
        Q = 1024; R = 64; bx = 0; by = local & 15; bz = local >> 4;
    } else {
        in = (pj == 6) ? Wo1 : Wo2; out = (pj == 6) ? Wo1t : Wo2t;
        Q = 1024; R = 1024; bx = local & 15; by = local >> 4; bz = 0;
    }
    int r0 = bx * 64, q0 = by * 64;
    int tx = threadIdx.x & 63, ty = threadIdx.x >> 6;
    const float* inp = in + ((long)bz * Q + q0) * R + r0;
    #pragma unroll
    for (int i = 0; i < 64; i += 4)
        tile[ty + i][tx] = inp[(long)(ty + i) * R + tx];
    __syncthreads();
    u16* outp = out + ((long)bz * R + r0) * Q + q0;
    #pragma unroll
    for (int i = 0; i < 64; i += 4)
        outp[(long)(ty + i) * Q + tx] = f2bf(tile[tx][ty + i]);
}

// Merged V-transpose + 1/l scale for BOTH MHAs. grid (16,16,8): z<4 -> MHA1
// (in1/ld1/zs1, Vt slab 0, csum half 0), z>=4 -> MHA2. out[c][r]=in[r][c]/l.
__global__ __launch_bounds__(256) void tscale2_k(
    const u16* __restrict__ in1, long ld1, long zs1,
    const u16* __restrict__ in2, long ld2, long zs2,
    u16* __restrict__ Vt, const float* __restrict__ csum) {
    __shared__ u16 tile[64][66];
    int z = blockIdx.z;
    int m = z >> 2, zb = z & 3;
    const u16* in; long ld, zs;
    if (m) { in = in2; ld = ld2; zs = zs2; } else { in = in1; ld = ld1; zs = zs1; }
    const u16* inz = in + (long)zb * zs;
    u16* outz = Vt + (long)m * 4194304 + (long)zb * 1048576;
    const float* cs = csum + m * 65536 + (long)zb * 16384;
    int r0 = blockIdx.y * 64;
    int c0 = blockIdx.x * 64;
    int tx = threadIdx.x & 63, ty = threadIdx.x >> 6;
    #pragma unroll
    for (int i = 0; i < 64; i += 4)
        tile[ty + i][tx] = inz[(long)(r0 + ty + i) * ld + c0 + tx];
    __syncthreads();
    #pragma unroll
    for (int i = 0; i < 64; i += 4) {
        int orow = c0 + ty + i;
        float f = bf2f(tile[tx][ty + i]) / cs[(orow >> 6) * 1024 + r0 + tx];
        outz[(long)orow * 1024 + r0 + tx] = f2bf(f);
    }
}

// ---------------- legacy GEMM (l-pass merged, Wo full-K merged, KV2 128^2) ----------------
// MRG=1 (SWZ=0 path): blockIdx.z in [0,128); z>=64 switches to the second
// pointer set (A2/lda2/B2/ldb2/b_zout2/csum2) with z &= 63.
template<int BM, int BN, int BK, int WM, int WN, int OUT_BF16, int EPI, int SWZ, int KS, int MRG>
__global__ __launch_bounds__(256) void gemm_k(
    const u16* __restrict__ A, long lda, long a_zin, long a_zout,
    const u16* __restrict__ B, long ldb, long b_zin, long b_zout,
    void* __restrict__ Cv, long ldc, long c_zin, long c_zout,
    int zin, int K, float alpha, const float* __restrict__ bias,
    float* __restrict__ csum,
    const u16* __restrict__ A2, long lda2,
    const u16* __restrict__ B2, long ldb2, long b_zout2,
    float* __restrict__ csum2)
{
    static_assert(BK == 64, "staging assumes BK=64");
    constexpr int WTM = BM / WM;
    constexpr int WTN = BN / WN;
    constexpr int TM = WTM / 16;
    constexpr int TN = WTN / 16;
    __shared__ __align__(16) u16 smem[(BM + BN) * BK];
    u16* As = smem;
    u16* Bs = smem + BM * BK;

    int bx, by, z;
    if (SWZ == 4) {
        int L = blockIdx.x;
        if (KS > 1) { z = L >> 9; L &= 511; } else { z = 0; }
        by = (L & 7) * 4 + ((L >> 3) & 3);
        bx = L >> 5;
    } else {
        bx = blockIdx.x; by = blockIdx.y; z = blockIdx.z;
    }
    if (MRG) {
        int m2 = z >> 6; z &= 63;
        if (m2) { A = A2; lda = lda2; B = B2; ldb = ldb2; b_zout = b_zout2; csum = csum2; }
    }
    int zi = z % zin, zo = z / zin;
    A += (long)zi * a_zin + (long)zo * a_zout;
    B += (long)zi * b_zin + (long)zo * b_zout;
    long coff = (long)zi * c_zin + (long)zo * c_zout;

    int tid = threadIdx.x;
    int lane = tid & 63;
    int wave = tid >> 6;
    int wm = wave / WN, wn = wave % WN;
    long bm0 = (long)by * BM, bn0 = (long)bx * BN;

    f32x4 acc[TM][TN];
    #pragma unroll
    for (int i = 0; i < TM; ++i)
        #pragma unroll
        for (int j = 0; j < TN; ++j) {
            acc[i][j][0] = 0.f; acc[i][j][1] = 0.f;
            acc[i][j][2] = 0.f; acc[i][j][3] = 0.f;
        }

    int r16 = lane & 15;
    int quad = lane >> 4;
    int l8 = lane >> 3;                    // stripe row
    int gsw = ((lane & 7) ^ l8) * 8;       // swizzled global col (elements)

    constexpr int ASTR = BM / 8;
    constexpr int BSTR = BN / 8;

    for (int k0 = 0; k0 < K; k0 += BK) {
        #pragma unroll
        for (int s = wave; s < ASTR; s += 4)
            gl_lds16(&A[(bm0 + s * 8 + l8) * lda + k0 + gsw], &As[s * 512]);
        #pragma unroll
        for (int s = wave; s < BSTR; s += 4)
            gl_lds16(&B[(bn0 + s * 8 + l8) * ldb + k0 + gsw], &Bs[s * 512]);
        __syncthreads();
        #pragma unroll
        for (int kk = 0; kk < BK; kk += 32) {
            int cb = (kk >> 3) + quad;
            bf16x8 av[TM], bv[TN];
            #pragma unroll
            for (int i = 0; i < TM; ++i) {
                int r = wm * WTM + i * 16 + r16;
                av[i] = *reinterpret_cast<const bf16x8*>(&As[r * 64 + ((cb ^ (r & 7)) * 8)]);
            }
            #pragma unroll
            for (int j = 0; j < TN; ++j) {
                int r = wn * WTN + j * 16 + r16;
                bv[j] = *reinterpret_cast<const bf16x8*>(&Bs[r * 64 + ((cb ^ (r & 7)) * 8)]);
            }
            #pragma unroll
            for (int i = 0; i < TM; ++i)
                #pragma unroll
                for (int j = 0; j < TN; ++j)
                    acc[i][j] = __builtin_amdgcn_mfma_f32_16x16x32_bf16(av[i], bv[j], acc[i][j], 0, 0, 0);
        }
        __syncthreads();
    }

    int rb = quad * 4;

    if (EPI == 4) {
        // exp + column sums only; no C store. csum layout [z][1024].
        float csl[TN];
        #pragma unroll
        for (int j = 0; j < TN; ++j) csl[j] = 0.f;
        #pragma unroll
        for (int i = 0; i < TM; ++i)
            #pragma unroll
            for (int j = 0; j < TN; ++j)
                #pragma unroll
                for (int r = 0; r < 4; ++r)
                    csl[j] += __expf(acc[i][j][r] * alpha);
        #pragma unroll
        for (int j = 0; j < TN; ++j) {
            float cs = csl[j];
            cs += __shfl_xor(cs, 16, 64);
            cs += __shfl_xor(cs, 32, 64);
            if (quad == 0) {
                long col = bn0 + wn * WTN + j * 16 + r16;
                atomicAdd(&csum[((long)zo * zin + zi) * 1024 + col], cs);
            }
        }
        return;
    }

    // ---- LDS-staged store epilogue ----
    constexpr int EB = OUT_BF16 ? 2 : 4;
    constexpr int CH = 16 / EB;
    constexpr int STRIDE = BN + CH;
    constexpr int LDSB = (BM + BN) * BK * 2;
    constexpr int EPASS = (BM * STRIDE * EB > LDSB) ? 2 : 1;
    constexpr int RPP = BM / EPASS;
    static_assert(RPP * STRIDE * EB <= LDSB, "epilogue tile overflows LDS");
    static_assert(EPASS == 1 || (WM == 2 && WTM == RPP), "pass/wave row alignment");
    constexpr int CPR = BN / CH;
    constexpr int NCH = RPP * CPR / 256;
    static_assert(RPP * CPR % 256 == 0, "store mapping");

    float* Ef = reinterpret_cast<float*>(smem);
    char* Cb = reinterpret_cast<char*>(Cv);

    for (int pass = 0; pass < EPASS; ++pass) {
        int p0 = pass * RPP;
        __syncthreads();
        #pragma unroll
        for (int i = 0; i < TM; ++i) {
            #pragma unroll
            for (int j = 0; j < TN; ++j) {
                int lcol = wn * WTN + j * 16 + r16;
                float bsv = (EPI == 1 || EPI == 2) ? bias[bn0 + lcol] : 0.f;
                #pragma unroll
                for (int r = 0; r < 4; ++r) {
                    int lrow = wm * WTM + i * 16 + rb + r;
                    if ((unsigned)(lrow - p0) < (unsigned)RPP) {
                        float v = acc[i][j][r] * alpha;
                        if (EPI == 1) { v += bsv; v = v > 0.f ? v : 0.f; }
                        else if (EPI == 2) { v += bsv; }
                        if (OUT_BF16) smem[(lrow - p0) * STRIDE + lcol] = f2bf(v);
                        else          Ef[(lrow - p0) * STRIDE + lcol] = v;
                    }
                }
            }
        }
        __syncthreads();
        #pragma unroll
        for (int c = 0; c < NCH; ++c) {
            int cid = tid + c * 256;
            int row = cid / CPR, ch = cid - row * CPR;
            int4 v = *reinterpret_cast<const int4*>(
                reinterpret_cast<const char*>(smem) + (row * STRIDE + ch * CH) * EB);
            long gidx = coff + (bm0 + p0 + row) * ldc + bn0 + ch * CH;
            *reinterpret_cast<int4*>(Cb + gidx * EB) = v;
        }
    }
}

// ---------------- 8-phase 256x256 GEMM (R1 schedule, frozen) ----------------
// Per K-tile t, 4 phases = (ih,jh) quadrants x K=64, 2 raw barriers each:
//   ph1: read av(ih0),bv(jh0) | stage (t+1).A-half1 | vmcnt(10)
//   ph2: read bv(jh1)         | stage (t+2).A-half0 | vmcnt(10)
//   ph3: read av(ih1)         | stage (t+2).B-half0 |
//   ph4:                      | stage (t+2).B-half1 | vmcnt(10)
// SPLITN=1: first NT/2 bx-tiles -> Cv (no epi); second NT/2 -> Cv2 with
// bias+relu, column base rebased (QKV1 + FFN-in fused dispatch).

__device__ __forceinline__ void bar_raw() {
    asm volatile("" ::: "memory");
    __builtin_amdgcn_s_barrier();
    asm volatile("" ::: "memory");
}

template<int N> __device__ __forceinline__ void vmw() {
    if constexpr (N == 10) asm volatile("s_waitcnt vmcnt(10)" ::: "memory");
    else if constexpr (N == 8) asm volatile("s_waitcnt vmcnt(8)" ::: "memory");
    else if constexpr (N == 4) asm volatile("s_waitcnt vmcnt(4)" ::: "memory");
    else if constexpr (N == 2) asm volatile("s_waitcnt vmcnt(2)" ::: "memory");
    else if constexpr (N == 0) asm volatile("s_waitcnt vmcnt(0)" ::: "memory");
}

// stage one half-tile (16 stripes of 8 rows x 64 cols) = 2 gl_lds per thread
__device__ __forceinline__ void stage_half(const u16* __restrict__ base, long ld, int kt,
                                           u16* __restrict__ lds, int half, int wave) {
    const u16* src = base + (long)kt * 64;
    #pragma unroll
    for (int u = 0; u < 2; ++u) {
        int s = half * 16 + u * 8 + wave;
        gl_lds16(src + (long)(s * 8) * ld, lds + s * 512);
    }
}

template<int IH>
__device__ __forceinline__ void read_a8(bf16x8 (&av)[4][2], const u16* __restrict__ As,
                                        int wm, int r16, int quad) {
    #pragma unroll
    for (int ii = 0; ii < 4; ++ii) {
        int r = IH * 128 + wm * 64 + ii * 16 + r16;
        #pragma unroll
        for (int kx = 0; kx < 2; ++kx)
            av[ii][kx] = *reinterpret_cast<const bf16x8*>(&As[r * 64 + (((kx * 4 + quad) ^ (r & 7)) * 8)]);
    }
}

template<int JH>
__device__ __forceinline__ void read_b8(bf16x8 (&bv)[2][2], const u16* __restrict__ Bs,
                                        int wn, int r16, int quad) {
    #pragma unroll
    for (int j = 0; j < 2; ++j) {
        int r = JH * 128 + wn * 32 + j * 16 + r16;
        #pragma unroll
        for (int kx = 0; kx < 2; ++kx)
            bv[j][kx] = *reinterpret_cast<const bf16x8*>(&Bs[r * 64 + (((kx * 4 + quad) ^ (r & 7)) * 8)]);
    }
}

template<int IH, int JH>
__device__ __forceinline__ void mfma_q(f32x4 (&acc)[2][4][2][2],
                                       const bf16x8 (&av)[4][2], const bf16x8 (&bv)[2][2]) {
    #pragma unroll
    for (int kx = 0; kx < 2; ++kx)
        #pragma unroll
        for (int ii = 0; ii < 4; ++ii)
            #pragma unroll
            for (int j = 0; j < 2; ++j)
                acc[IH][ii][JH][j] = __builtin_amdgcn_mfma_f32_16x16x32_bf16(
                    av[ii][kx], bv[j][kx], acc[IH][ii][JH][j], 0, 0, 0);
}

// MODE 0: steady; 1: t=T-2 (only (t+1).A1 staged); 2: t=T-1 (no staging)
template<int MODE>
__device__ __forceinline__ void tile_iter(
    int t, f32x4 (&acc)[2][4][2][2], bf16x8 (&av)[4][2], bf16x8 (&bvh)[2][2][2],
    u16* __restrict__ smem, const u16* __restrict__ Ab, long lda,
    const u16* __restrict__ Bb, long ldb, int wave, int wm, int wn, int r16, int quad)
{
    u16* As0 = smem + (t & 1) * 32768;          // buf for tile t (also target of t+2 stages)
    u16* Bs0 = As0 + 16384;
    u16* As1 = smem + ((t + 1) & 1) * 32768;    // buf for tile t+1
    // ---- ph1 (ih0,jh0)
    read_a8<0>(av, As0, wm, r16, quad);
    read_b8<0>(bvh[0], Bs0, wn, r16, quad);
    if (MODE < 2) stage_half(Ab, lda, t + 1, As1, 1, wave);
    vmw<MODE == 0 ? 10 : (MODE == 1 ? 10 : 2)>();
    bar_raw(); __builtin_amdgcn_sched_barrier(0);
    __builtin_amdgcn_s_setprio(1);
    mfma_q<0, 0>(acc, av, bvh[0]);
    __builtin_amdgcn_s_setprio(0);
    __builtin_amdgcn_sched_barrier(0);
    bar_raw();
    // ---- ph2 (ih0,jh1)
    read_b8<1>(bvh[1], Bs0, wn, r16, quad);
    if (MODE == 0) stage_half(Ab, lda, t + 2, As0, 0, wave);
    vmw<MODE == 0 ? 10 : (MODE == 1 ? 8 : 0)>();
    bar_raw(); __builtin_amdgcn_sched_barrier(0);
    __builtin_amdgcn_s_setprio(1);
    mfma_q<0, 1>(acc, av, bvh[1]);
    __builtin_amdgcn_s_setprio(0);
    __builtin_amdgcn_sched_barrier(0);
    bar_raw();
    // ---- ph3 (ih1,jh0)
    read_a8<1>(av, As0, wm, r16, quad);
    if (MODE == 0) stage_half(Bb, ldb, t + 2, Bs0, 0, wave);
    bar_raw(); __builtin_amdgcn_sched_barrier(0);
    __builtin_amdgcn_s_setprio(1);
    mfma_q<1, 0>(acc, av, bvh[0]);
    __builtin_amdgcn_s_setprio(0);
    __builtin_amdgcn_sched_barrier(0);
    bar_raw();
    // ---- ph4 (ih1,jh1)
    if (MODE == 0) stage_half(Bb, ldb, t + 2, Bs0, 1, wave);
    if (MODE < 2) vmw<MODE == 0 ? 10 : 4>();
    bar_raw(); __builtin_amdgcn_sched_barrier(0);
    __builtin_amdgcn_s_setprio(1);
    mfma_q<1, 1>(acc, av, bvh[1]);
    __builtin_amdgcn_s_setprio(0);
    __builtin_amdgcn_sched_barrier(0);
    bar_raw();
}

// grid = 16*NT*KS blocks of 512. EPI: 0 none, 1 bias+relu. KS>1: z picks K-chunk,
// output slab z: z<2 -> Cv + (z&1)*czs, z>=2 -> Cv2 + (z&1)*czs (fp32).
// SPLITN=1 (KS must be 1): bx>=NT/2 -> Cv2, bias+relu, columns rebased.
template<int NT, int KS, int EPI, int OUT_BF16, int SPLITN>
__global__ __launch_bounds__(512, 2) void gemm8_k(
    const u16* __restrict__ A, long lda,
    const u16* __restrict__ B, long ldb,
    void* __restrict__ Cv, void* __restrict__ Cv2, long ldc,
    int K, float alpha, const float* __restrict__ bias, long czs)
{
    __shared__ __align__(16) u16 smem[65536];   // 128 KiB

    int L = blockIdx.x;
    int z = 0;
    if (KS > 1) { z = L / (16 * NT); L -= z * 16 * NT; }
    int by = (L & 7) * 2 + ((L >> 3) & 1);      // XCD-contiguous M-rows
    int bx = L >> 4;
    if (KS > 1) { A += (long)z * K; B += (long)z * K; }

    int tid = threadIdx.x;
    int lane = tid & 63, wave = tid >> 6;
    int wm = wave >> 2, wn = wave & 3;
    int r16 = lane & 15, quad = lane >> 4, l8 = lane >> 3;
    int gsw = ((lane & 7) ^ l8) * 8;
    long bm0 = (long)by * 256, bn0 = (long)bx * 256;
    const u16* Ab = A + (bm0 + l8) * lda + gsw;
    const u16* Bb = B + (bn0 + l8) * ldb + gsw;

    f32x4 acc[2][4][2][2];
    #pragma unroll
    for (int a0 = 0; a0 < 2; ++a0)
        #pragma unroll
        for (int a1 = 0; a1 < 4; ++a1)
            #pragma unroll
            for (int a2 = 0; a2 < 2; ++a2)
                #pragma unroll
                for (int a3 = 0; a3 < 2; ++a3) {
                    acc[a0][a1][a2][a3][0] = 0.f; acc[a0][a1][a2][a3][1] = 0.f;
                    acc[a0][a1][a2][a3][2] = 0.f; acc[a0][a1][a2][a3][3] = 0.f;
                }
    bf16x8 av[4][2];
    bf16x8 bvh[2][2][2];

    int T = K >> 6;   // >= 3

    // prologue issue stream: [0.A0, 0.B0, 0.B1, 0.A1, 1.A0, 1.B0, 1.B1]
    stage_half(Ab, lda, 0, smem,         0, wave);
    stage_half(Bb, ldb, 0, smem + 16384, 0, wave);
    stage_half(Bb, ldb, 0, smem + 16384, 1, wave);
    stage_half(Ab, lda, 0, smem,         1, wave);
    stage_half(Ab, lda, 1, smem + 32768, 0, wave);
    stage_half(Bb, ldb, 1, smem + 49152, 0, wave);
    stage_half(Bb, ldb, 1, smem + 49152, 1, wave);
    vmw<10>();          // 14 issued -> oldest 4 (0.A0,0.B0) landed
    bar_raw();

    for (int t = 0; t < T - 2; ++t)
        tile_iter<0>(t, acc, av, bvh, smem, Ab, lda, Bb, ldb, wave, wm, wn, r16, quad);
    tile_iter<1>(T - 2, acc, av, bvh, smem, Ab, lda, Bb, ldb, wave, wm, wn, r16, quad);
    tile_iter<2>(T - 1, acc, av, bvh, smem, Ab, lda, Bb, ldb, wave, wm, wn, r16, quad);

    // ---- epilogue: stage to LDS (row-XOR-swizzled), coalesced int4 stores
    constexpr int EB = OUT_BF16 ? 2 : 4;
    constexpr int EPASS = OUT_BF16 ? 1 : 2;   // f32 = 2 passes of 128 rows (ih=pass)
    bool sec = SPLITN && (bx >= NT / 2);
    char* Cb;
    long bnc = bn0;
    if (SPLITN) {
        Cb = reinterpret_cast<char*>(sec ? Cv2 : Cv);
        if (sec) bnc = bn0 - (long)(NT / 2) * 256;
    } else {
        Cb = reinterpret_cast<char*>((KS > 1 && z >= 2) ? Cv2 : Cv);
        if (KS > 1) Cb += (long)(z & 1) * czs * EB;
    }
    bool do_bias = (EPI == 1) || sec;
    float bsv[2][2];
    if (do_bias) {
        #pragma unroll
        for (int jh = 0; jh < 2; ++jh)
            #pragma unroll
            for (int j = 0; j < 2; ++j)
                bsv[jh][j] = bias[bnc + jh * 128 + wn * 32 + j * 16 + r16];
    }
    u16* sm16 = smem;
    float* smf = reinterpret_cast<float*>(smem);
    #pragma unroll
    for (int pass = 0; pass < EPASS; ++pass) {
        bar_raw();
        #pragma unroll
        for (int ih = 0; ih < 2; ++ih) {
            if (EPASS == 2 && ih != pass) continue;
            #pragma unroll
            for (int ii = 0; ii < 4; ++ii)
                #pragma unroll
                for (int jh = 0; jh < 2; ++jh)
                    #pragma unroll
                    for (int j = 0; j < 2; ++j)
                        #pragma unroll
                        for (int r = 0; r < 4; ++r) {
                            int lrow = (EPASS == 2 ? 0 : ih * 128) + wm * 64 + ii * 16 + quad * 4 + r;
                            int lcol = jh * 128 + wn * 32 + j * 16 + r16;
                            float v = acc[ih][ii][jh][j][r] * alpha;
                            if (do_bias) { v += bsv[jh][j]; v = v > 0.f ? v : 0.f; }
                            int scol = lcol ^ ((lrow & 7) * 8);
                            if (OUT_BF16) sm16[lrow * 256 + scol] = f2bf(v);
                            else          smf[lrow * 256 + scol] = v;
                        }
        }
        bar_raw();
        constexpr int CH = 16 / EB;
        constexpr int CPR = 256 / CH;
        constexpr int NCH = (OUT_BF16 ? 256 : 128) * CPR / 512;
        #pragma unroll
        for (int c = 0; c < NCH; ++c) {
            int cid = tid + c * 512;
            int row = cid / CPR, ch = cid - row * CPR;
            int col = (ch * CH) ^ ((row & 7) * 8);
            int4 v = *reinterpret_cast<const int4*>(
                reinterpret_cast<const char*>(smem) + ((long)row * 256 + col) * EB);
            long grow = bm0 + pass * 128 + row;
            *reinterpret_cast<int4*>(Cb + (grow * ldc + bnc + ch * CH) * EB) = v;
        }
    }
}

// ---------------- fused attention PV (both MHAs in one dispatch) ----------------
// MRG=1: grid 1024; L>=512 switches to second pointer set (MHA2).
// Per block: out[128 t][64 v] = sum_s exp(0.125*Q K^T) * Vt_scaled.
// K/V double-buffered; stage(c+1) issued BEFORE chunk c compute; counted
// vmcnt(4) + barrier; mid-chunk lgkmcnt(0)+barrier.
// QK computes S^T = mfma(K, Q) — C-fragment holds s=quad*4+rr (4 CONSECUTIVE
// s) at col t=r16, so Es spill is 8x ushort4 (b64) per thread instead of
// 32x b16. Write addr Es[t*64 + ((g^(t&7))*8) + (s&7)], g=s>>3, matches PV's
// read swizzle exactly. Wave roles: wm = t-half, wn = s-half.
template<int MRG>
__global__ __launch_bounds__(256) void attn_pv_k(
    const u16* __restrict__ Qg, long ldq, long qbz,
    const u16* __restrict__ Kg, long ldk, long kbz,
    const u16* __restrict__ Vg, u16* __restrict__ outg,
    const u16* __restrict__ Qg2,
    const u16* __restrict__ Kg2, long ldk2, long kbz2,
    const u16* __restrict__ Vg2, u16* __restrict__ outg2)
{
    __shared__ __align__(16) u16 Qs[128 * 64];
    __shared__ __align__(16) u16 Ks[2][64 * 64];
    __shared__ __align__(16) u16 Vs[2][64 * 64];
    __shared__ __align__(16) u16 Es[128 * 64];

    int L = blockIdx.x;
    if (MRG) {
        int m = L >> 9; L &= 511;
        if (m) { Qg = Qg2; Kg = Kg2; ldk = ldk2; kbz = kbz2; Vg = Vg2; outg = outg2; }
    }
    int h  = (L & 7) * 2 + ((L >> 3) & 1);
    int tb = (L >> 4) & 7;
    int b  = L >> 7;

    const u16* Q  = Qg + (long)b * qbz + h * 64;
    const u16* Kp = Kg + (long)b * kbz + h * 64;
    const u16* Vp = Vg + (long)b * 1048576 + (long)h * 65536;
    u16* outp = outg + (long)b * 1048576 + (long)tb * 131072 + h * 64;

    int tid = threadIdx.x, lane = tid & 63, wave = tid >> 6;
    int wm = wave >> 1, wn = wave & 1;
    int r16 = lane & 15, quad = lane >> 4, l8 = lane >> 3;
    int gsw = ((lane & 7) ^ l8) * 8;
    long t0 = (long)tb * 128;

    // prologue: Q (4 loads/thread) + K/V chunk 0 (4 loads/thread)
    #pragma unroll
    for (int s = wave; s < 16; s += 4)
        gl_lds16(&Q[(t0 + s * 8 + l8) * ldq + gsw], &Qs[s * 512]);
    #pragma unroll
    for (int s = wave; s < 8; s += 4) {
        gl_lds16(&Kp[(long)(s * 8 + l8) * ldk + gsw], &Ks[0][s * 512]);
        gl_lds16(&Vp[(long)(s * 8 + l8) * 1024 + gsw], &Vs[0][s * 512]);
    }

    f32x4 acc[4][2];
    #pragma unroll
    for (int i = 0; i < 4; ++i)
        #pragma unroll
        for (int j = 0; j < 2; ++j) {
            acc[i][j][0] = 0.f; acc[i][j][1] = 0.f;
            acc[i][j][2] = 0.f; acc[i][j][3] = 0.f;
        }

    for (int sc = 0; sc < 16; ++sc) {
        const u16* Ksc = Ks[sc & 1];
        const u16* Vsc = Vs[sc & 1];
        if (sc < 15) {
            int nc = sc + 1;
            u16* Kn = Ks[nc & 1];
            u16* Vn = Vs[nc & 1];
            #pragma unroll
            for (int s = wave; s < 8; s += 4) {
                gl_lds16(&Kp[(long)(nc * 64 + s * 8 + l8) * ldk + gsw], &Kn[s * 512]);
                gl_lds16(&Vp[(long)(s * 8 + l8) * 1024 + nc * 64 + gsw], &Vn[s * 512]);
            }
            asm volatile("s_waitcnt vmcnt(4)" ::: "memory");   // chunk sc (and Q) landed
        } else {
            asm volatile("s_waitcnt vmcnt(0)" ::: "memory");   // last chunk landed
        }
        bar_raw();                            // all waves' chunk-sc loads visible

        // E^T-chunk = K x Q^T (64 s x 128 t, contraction 64). e[i=s-blk][j=t-blk]:
        // C row = s (from K-fragment), C col = t (from Q-fragment).
        f32x4 e[2][4];
        #pragma unroll
        for (int i = 0; i < 2; ++i)
            #pragma unroll
            for (int j = 0; j < 4; ++j) {
                e[i][j][0] = 0.f; e[i][j][1] = 0.f;
                e[i][j][2] = 0.f; e[i][j][3] = 0.f;
            }
        #pragma unroll
        for (int kk = 0; kk < 64; kk += 32) {
            int cb = (kk >> 3) + quad;
            bf16x8 kv[2], qv[4];
            #pragma unroll
            for (int i = 0; i < 2; ++i) {
                int r = wn * 32 + i * 16 + r16;
                kv[i] = *reinterpret_cast<const bf16x8*>(&Ksc[r * 64 + ((cb ^ (r & 7)) * 8)]);
            }
            #pragma unroll
            for (int j = 0; j < 4; ++j) {
                int r = wm * 64 + j * 16 + r16;
                qv[j] = *reinterpret_cast<const bf16x8*>(&Qs[r * 64 + ((cb ^ (r & 7)) * 8)]);
            }
            #pragma unroll
            for (int i = 0; i < 2; ++i)
                #pragma unroll
                for (int j = 0; j < 4; ++j)
                    e[i][j] = __builtin_amdgcn_mfma_f32_16x16x32_bf16(kv[i], qv[j], e[i][j], 0, 0, 0);
        }
        // exp + vectorized write to Es[t][s]: thread holds s = wn*32+i*16+quad*4+rr
        // (rr=0..3 contiguous) at t = wm*64+j*16+r16. One ushort4 per fragment.
        #pragma unroll
        for (int i = 0; i < 2; ++i) {
            int g = wn * 4 + i * 2 + (quad >> 1);      // s>>3 group
            int sl = (quad & 1) * 4;                   // s&7 base
            #pragma unroll
            for (int j = 0; j < 4; ++j) {
                int t = wm * 64 + j * 16 + r16;
                ushort4 w;
                w.x = f2bf(__expf(e[i][j][0] * 0.125f));
                w.y = f2bf(__expf(e[i][j][1] * 0.125f));
                w.z = f2bf(__expf(e[i][j][2] * 0.125f));
                w.w = f2bf(__expf(e[i][j][3] * 0.125f));
                *reinterpret_cast<ushort4*>(&Es[t * 64 + ((g ^ (t & 7)) * 8) + sl]) = w;
            }
        }
        asm volatile("s_waitcnt lgkmcnt(0)" ::: "memory");
        bar_raw();

        // acc += E-chunk x Vs^T (contraction over s-chunk)
        #pragma unroll
        for (int kk = 0; kk < 64; kk += 32) {
            int cb = (kk >> 3) + quad;
            bf16x8 av[4], bv[2];
            #pragma unroll
            for (int i = 0; i < 4; ++i) {
                int r = wm * 64 + i * 16 + r16;
                av[i] = *reinterpret_cast<const bf16x8*>(&Es[r * 64 + ((cb ^ (r & 7)) * 8)]);
            }
            #pragma unroll
            for (int j = 0; j < 2; ++j) {
                int r = wn * 32 + j * 16 + r16;
                bv[j] = *reinterpret_cast<const bf16x8*>(&Vsc[r * 64 + ((cb ^ (r & 7)) * 8)]);
            }
            #pragma unroll
            for (int i = 0; i < 4; ++i)
                #pragma unroll
                for (int j = 0; j < 2; ++j)
                    acc[i][j] = __builtin_amdgcn_mfma_f32_16x16x32_bf16(av[i], bv[j], acc[i][j], 0, 0, 0);
        }
        bar_raw();                 // all waves done reading buf[sc&1] K/V + Es
    }

    #pragma unroll
    for (int i = 0; i < 4; ++i)
        #pragma unroll
        for (int j = 0; j < 2; ++j) {
            int lcol = wn * 32 + j * 16 + r16;
            #pragma unroll
            for (int r = 0; r < 4; ++r) {
                int lrow = wm * 64 + i * 16 + quad * 4 + r;
                outp[(long)lrow * 1024 + lcol] = f2bf(acc[i][j][r]);
            }
        }
}

// ---------------- fused sub_norm chain: all 3 layers in one dispatch ----------------
// t1 = sn(yf + g0); t2 = sn(t1 + g1); out = sn(t2 + f01[0]+f01[s]+f23[0]+f23[s] + b).
// sm[8] reuse is race-free: every slot's readers finish before the barrier that
// precedes its overwrite.
__global__ __launch_bounds__(256) void addsn_fuse_k(
    const float* __restrict__ g0, const float* __restrict__ g1,
    const float* __restrict__ f01, const float* __restrict__ f23, long fstride,
    const float* __restrict__ yf, const float* __restrict__ b_out,
    float* __restrict__ out)
{
    __shared__ float sm[8];
    long row = blockIdx.x;
    int tid = threadIdx.x;
    int lane = tid & 63, w = tid >> 6;

    auto subnorm = [&](float4& x) {
        float s = x.x + x.y + x.z + x.w;
        for (int o = 32; o > 0; o >>= 1) s += __shfl_down(s, o, 64);
        if (lane == 0) sm[w] = s;
        __syncthreads();
        float mean = (sm[0] + sm[1] + sm[2] + sm[3]) * (1.f / 1024.f);
        float d0 = x.x - mean, d1 = x.y - mean, d2 = x.z - mean, d3 = x.w - mean;
        float q = d0 * d0 + d1 * d1 + d2 * d2 + d3 * d3;
        for (int o = 32; o > 0; o >>= 1) q += __shfl_down(q, o, 64);
        if (lane == 0) sm[w + 4] = q;
        __syncthreads();
        float sd = sqrtf((sm[4] + sm[5] + sm[6] + sm[7]) * (1.f / 1023.f));
        x.x = d0 - sd; x.y = d1 - sd; x.z = d2 - sd; x.w = d3 - sd;
    };

    float4 x = reinterpret_cast<const float4*>(yf + row * 1024)[tid];
    float4 a = reinterpret_cast<const float4*>(g0 + row * 1024)[tid];
    x.x += a.x; x.y += a.y; x.z += a.z; x.w += a.w;
    subnorm(x);                                         // t1 = out1

    a = reinterpret_cast<const float4*>(g1 + row * 1024)[tid];
    x.x += a.x; x.y += a.y; x.z += a.z; x.w += a.w;
    subnorm(x);                                         // t2 = out2

    float4 f0 = reinterpret_cast<const float4*>(f01 + row * 1024)[tid];
    float4 f1 = reinterpret_cast<const float4*>(f01 + fstride + row * 1024)[tid];
    float4 f2 = reinterpret_cast<const float4*>(f23 + row * 1024)[tid];
    float4 f3 = reinterpret_cast<const float4*>(f23 + fstride + row * 1024)[tid];
    float4 bb = reinterpret_cast<const float4*>(b_out)[tid];
    x.x += f0.x + f1.x + f2.x + f3.x + bb.x;
    x.y += f0.y + f1.y + f2.y + f3.y + bb.y;
    x.z += f0.z + f1.z + f2.z + f3.z + bb.z;
    x.w += f0.w + f1.w + f2.w + f3.w + bb.w;
    subnorm(x);                                         // final

    reinterpret_cast<float4*>(out + row * 1024)[tid] = x;
}

// ---------------- launcher ----------------

extern "C" void kernel_launch(void* const* d_in, const int* in_sizes, int n_in,
                              void* d_out, int out_size, void* d_ws, size_t ws_size,
                              hipStream_t stream) {
    (void)in_sizes; (void)n_in; (void)out_size; (void)ws_size;
    const float* xf   = (const float*)d_in[0];
    const float* yf   = (const float*)d_in[1];
    const float* Wq1  = (const float*)d_in[2];
    const float* Wk1  = (const float*)d_in[3];
    const float* Wv1  = (const float*)d_in[4];
    const float* Wo1  = (const float*)d_in[5];
    const float* Wq2  = (const float*)d_in[6];
    const float* Wk2  = (const float*)d_in[7];
    const float* Wv2  = (const float*)d_in[8];
    const float* Wo2  = (const float*)d_in[9];
    const float* W_in = (const float*)d_in[10];
    const float* b_in = (const float*)d_in[11];
    const float* W_out= (const float*)d_in[12];
    const float* b_out= (const float*)d_in[13];

    // workspace layout (176 MB with aliases; lifetimes in header comment)
    char* p = (char*)d_ws;
    auto alloc = [&](size_t bytes) { char* r = p; p += bytes; return r; };
    u16*   yb    = (u16*)alloc(8388608);    // dead after SPLITN
    u16*   xb    = (u16*)alloc(8388608);    // dead after KV2 gemm
    u16*   W1cat = (u16*)alloc(8388608);    // dead after SPLITN
    u16*   Winb  = (u16*)alloc(8388608);    // dead after SPLITN (contiguous with W1cat)
    u16*   Wkv2t = (u16*)alloc(4194304);
    u16*   Wo1t  = (u16*)alloc(2097152);
    u16*   Wo2t  = (u16*)alloc(2097152);    // contiguous after Wo1t (b_zout=1048576)
    u16*   Woutb = (u16*)alloc(8388608);
    u16*   QKV   = (u16*)alloc(33554432);   // [Q1|K1|V1|Q2]; FFN-out fp32 slabs 0,1 after attn
    u16*   KV2   = (u16*)alloc(16777216);   // [K2|V2]
    u16*   Pb    = (u16*)alloc(33554432);   // FFN hidden
    u16*   part  = (u16*)alloc(16777216);   // attn partials [2 mha][4096][1024] bf16
    float* gout  = (float*)alloc(33554432); // Wo fp32 outputs, 2 slabs of 16 MB
    // aliases:
    u16*   Vt    = yb;                      // [2 mha][1024 hv][1024 s] (16 MB over yb+xb)
    float* csum  = gout;                    // [2 mha][4][16][1024] (512 KB, dead before Wo)
    float* ffnC2 = (float*)yb;              // FFN-out slabs 2,3 (32 MB over yb..Winb; Vt dead)

    // 1. all converts + weight packs + csum zero
    mega_pack_k<<<18560, 256, 0, stream>>>(
        yf, yb, xf, xb, W_in, Winb, W_out, Woutb,
        Wq1, Wk1, Wv1, Wq2, W1cat, Wk2, Wv2, Wkv2t,
        Wo1, Wo1t, Wo2, Wo2t, csum);

    // 2. QKV1+Q2 AND FFN-in in one dispatch (A=yb; B=[W1cat|Winb] contiguous)
    gemm8_k<32,1,0,1,1><<<512, 512, 0, stream>>>(
        yb, 1024L, W1cat, 1024L, (void*)QKV, (void*)Pb, 4096L, 1024, 1.0f, b_in, 0L);

    // 3. K2/V2 from x, N=2048 — legacy 128^2 tiles, grid (16,32)=512 blocks
    gemm_k<128,128,64,2,2,1,0,0,1,0><<<dim3(16, 32, 1), 256, 0, stream>>>(
        xb, 1024L, 0L, 0L, Wkv2t, 1024L, 0L, 0L,
        (void*)KV2, 2048L, 0L, 0L, 1, 1024, 1.0f, nullptr, nullptr,
        nullptr, 0L, nullptr, 0L, 0L, nullptr);

    // 4. l-pass BOTH MHAs: grid (8,8,128); z<64 MHA1 (Q1 x K1), z>=64 MHA2
    gemm_k<128,128,64,2,2,1,4,0,1,1><<<dim3(8, 8, 128), 256, 0, stream>>>(
        QKV, 4096L, 64L, 4194304L,            // A1 = Q1
        QKV + 1024, 4096L, 64L, 4194304L,     // B1 = K1
        (void*)Pb, 1024L, 0L, 0L, 16, 64, 0.125f, nullptr, csum,
        QKV + 3072, 4096L,                    // A2 = Q2
        KV2, 2048L, 2097152L,                 // B2 = K2
        csum + 65536);

    // 5. V-transpose + 1/l scale, both MHAs (Vt slabs 0,1 = dead yb/xb region)
    tscale2_k<<<dim3(16, 16, 8), 256, 0, stream>>>(
        QKV + 2048, 4096L, 4194304L,          // V1
        KV2 + 1024, 2048L, 2097152L,          // V2
        Vt, csum);

    // 6. attention PV, both MHAs (part slabs 0,1)
    attn_pv_k<1><<<1024, 256, 0, stream>>>(
        QKV, 4096L, 4194304L, QKV + 1024, 4096L, 4194304L, Vt, part,
        QKV + 3072, KV2, 2048L, 2097152L, Vt + 4194304, part + 4194304);

    // 7. Wo both MHAs, full-K: grid 2*512. z: A += z*4194304 (part slab),
    //    B += z*1048576 (Wo1t->Wo2t), C += z*4194304 floats (gout slab).
    gemm_k<128,64,64,2,2,0,0,4,2,0><<<1024, 256, 0, stream>>>(
        part, 1024L, 0L, 4194304L, Wo1t, 1024L, 0L, 1048576L,
        (void*)gout, 1024L, 0L, 4194304L, 1, 1024, 1.0f, nullptr, nullptr,
        nullptr, 0L, nullptr, 0L, 0L, nullptr);

    // 8. FFN-out: split-K 4; slabs 0,1 -> QKV (dead), slabs 2,3 -> yb region
    gemm8_k<4,4,0,0,0><<<256, 512, 0, stream>>>(
        Pb, 4096L, Woutb, 4096L, (void*)QKV, (void*)ffnC2, 1024L, 1024, 1.0f, nullptr, 4194304L);

    // 9. fused sub_norm chain
    addsn_fuse_k<<<4096, 256, 0, stream>>>(
        gout, gout + 4194304, (const float*)QKV, ffnC2, 4194304L,
        yf, b_out, (float*)d_out);
}